// Round 3
// baseline (242.850 us; speedup 1.0000x reference)
//
#include <hip/hip_runtime.h>
#include <cstddef>
#include <cstdint>

// Problem constants
#define B_SZ  2
#define T_SEQ 2048
#define S_SEQ 2048
#define C_EMB 1024
#define NH    16
#define HD    64
#define KDIM  1024   // inner dim of the three big GEMMs

typedef __attribute__((ext_vector_type(8))) short bf16x8;
typedef __attribute__((ext_vector_type(4))) float f32x4;

// ---------------------------------------------------------------------------
// Workspace layout (float units).
// ---------------------------------------------------------------------------
#define OFF_XH    ((size_t)0)           // [4096,1024] ushort
#define OFF_XL    ((size_t)2097152)
#define OFF_MEMH  ((size_t)4194304)     // [4096,1024] ushort
#define OFF_MEML  ((size_t)6291456)
#define OFF_QWH   ((size_t)8388608)     // [1024,1024] ushort (transposed [N,K])
#define OFF_QWL   ((size_t)8912896)
#define OFF_KVWH  ((size_t)9437184)     // [2048,1024] ushort
#define OFF_KVWL  ((size_t)10485760)
#define OFF_PWH   ((size_t)11534336)    // [1024,1024] ushort
#define OFF_PWL   ((size_t)12058624)
#define OFF_KSUM  ((size_t)12582912)    // [2,1024]      (zeroed by prep)
#define OFF_MT    ((size_t)12584960)    // [32,64,64]    (zeroed by prep)
#define OFF_TAB   ((size_t)12716032)    // [2048,32] float2
#define OFF_YH    ((size_t)12847104)    // [4096,1024] ushort
#define OFF_YL    ((size_t)14944256)
#define WS_FLOATS ((size_t)17041408)    // ~68.2 MB

__device__ __forceinline__ float elu1(float v) {
    return v > 0.0f ? v + 1.0f : __expf(v);
}
__device__ __forceinline__ unsigned short bf16_rne(float x) {
    union { float f; unsigned int u; } v; v.f = x;
    unsigned int u = v.u;
    return (unsigned short)((u + 0x7FFFu + ((u >> 16) & 1u)) >> 16);
}
__device__ __forceinline__ float bf16_to_f(unsigned short h) {
    union { unsigned int u; float f; } v; v.u = ((unsigned int)h) << 16;
    return v.f;
}

// ---------------------------------------------------------------------------
// Unified prep kernel (block-range dispatch), unchanged.
// ---------------------------------------------------------------------------
#define PREP_BLOCKS 13064

__device__ __forceinline__ void split4_body(
    const float4* __restrict__ in, ushort4* __restrict__ hi,
    ushort4* __restrict__ lo, int i)
{
    float4 v = in[i];
    ushort4 h, l;
    h.x = bf16_rne(v.x); l.x = bf16_rne(v.x - bf16_to_f(h.x));
    h.y = bf16_rne(v.y); l.y = bf16_rne(v.y - bf16_to_f(h.y));
    h.z = bf16_rne(v.z); l.z = bf16_rne(v.z - bf16_to_f(h.z));
    h.w = bf16_rne(v.w); l.w = bf16_rne(v.w - bf16_to_f(h.w));
    hi[i] = h; lo[i] = l;
}

__device__ __forceinline__ void transpose_body(
    const float* __restrict__ W, unsigned short* __restrict__ Wth,
    unsigned short* __restrict__ Wtl, int K, int N, int bx, int by,
    float (*tile)[33])
{
    const int k0 = by * 32, n0 = bx * 32;
    const int tx = threadIdx.x & 31, ty = threadIdx.x >> 5;
    #pragma unroll
    for (int j = 0; j < 4; ++j)
        tile[ty + j * 8][tx] = W[(size_t)(k0 + ty + j * 8) * N + n0 + tx];
    __syncthreads();
    #pragma unroll
    for (int j = 0; j < 4; ++j) {
        float x = tile[tx][ty + j * 8];
        unsigned short h = bf16_rne(x);
        unsigned short l = bf16_rne(x - bf16_to_f(h));
        size_t o = (size_t)(n0 + ty + j * 8) * K + k0 + tx;
        Wth[o] = h; Wtl[o] = l;
    }
}

__global__ __launch_bounds__(256) void prep_kernel(
    const float* __restrict__ x, const float* __restrict__ memory,
    const float* __restrict__ q_w, const float* __restrict__ kv_w,
    const float* __restrict__ proj_w,
    unsigned short* __restrict__ xh, unsigned short* __restrict__ xl,
    unsigned short* __restrict__ mh, unsigned short* __restrict__ ml,
    unsigned short* __restrict__ qwh, unsigned short* __restrict__ qwl,
    unsigned short* __restrict__ kvwh, unsigned short* __restrict__ kvwl,
    unsigned short* __restrict__ pwh, unsigned short* __restrict__ pwl,
    float2* __restrict__ tab, float* __restrict__ zero_base)
{
    __shared__ float tile[32][33];
    const int bid = blockIdx.x;
    const int tid = threadIdx.x;
    if (bid < 4096) {
        split4_body((const float4*)x, (ushort4*)xh, (ushort4*)xl, bid * 256 + tid);
    } else if (bid < 8192) {
        split4_body((const float4*)memory, (ushort4*)mh, (ushort4*)ml, (bid - 4096) * 256 + tid);
    } else if (bid < 9216) {
        int i = bid - 8192;
        transpose_body(q_w, qwh, qwl, 1024, 1024, i & 31, i >> 5, tile);
    } else if (bid < 11264) {
        int i = bid - 9216;
        transpose_body(kv_w, kvwh, kvwl, 1024, 2048, i & 63, i >> 6, tile);
    } else if (bid < 12288) {
        int i = bid - 11264;
        transpose_body(proj_w, pwh, pwl, 1024, 1024, i & 31, i >> 5, tile);
    } else if (bid < 12544) {
        int idx = (bid - 12288) * 256 + tid;    // pos*32 + i
        int pos = idx >> 5, i = idx & 31;
        double invf = exp(-(double)i * (9.210340371976184 / 32.0));  // 10000^(-i/32)
        float arg = (float)((double)pos * invf);
        float sn, cs;
        sincosf(arg, &sn, &cs);
        tab[idx] = make_float2(cs, sn);
    } else {
        int idx = (bid - 12544) * 256 + tid;
        if (idx < 2048 + 131072) zero_base[idx] = 0.0f;   // Ksum + Mt
    }
}

#define WAITCNT_VM(N)   asm volatile("s_waitcnt vmcnt(" #N ")" ::: "memory")
#define WAITCNT_LGKM(N) asm volatile("s_waitcnt lgkmcnt(" #N ")" ::: "memory")
#define CBAR()          asm volatile("" ::: "memory")

// ---------------------------------------------------------------------------
// Bijective XCD swizzles (id%8 assumed = XCD).
// 16x16 grid: XCD x owns by in {2x,2x+1}, all 16 bx.
// 16x32 grid: XCD x owns by in {4x..4x+3}, all 16 bx.
// ---------------------------------------------------------------------------
__device__ __forceinline__ void xcd_swz16(int& bx, int& by) {
    int id = (int)(blockIdx.x + (blockIdx.y << 4));
    int x = id & 7, k = id >> 3;
    bx = k >> 1;
    by = x * 2 + (k & 1);
}
__device__ __forceinline__ void xcd_swz32(int& bx, int& by) {
    int id = (int)(blockIdx.x + (blockIdx.y << 4));   // 0..511
    int x = id & 7, k = id >> 3;                      // k 0..63
    bx = k >> 2;                                      // 0..15
    by = x * 4 + (k & 3);                             // 0..31
}

// ---------------------------------------------------------------------------
// KV GEMM: 256(M)x128(N) head-paired tile. Register-double-buffered main
// loop: per tile {vmcnt(0); lgkm(0); barrier; STAGE(t+2); ds_read frags(t+1)
// -> other reg set; 48 MFMA on current set (NO waits)}. 2-buffer LDS ring.
// 512 threads (8 waves, wr x wc = 4x2, per-wave 64x64). 1 barrier/tile.
// Fused elu/Ksum/rope + Mt accumulate epilogue (unchanged).
// Epilogue LDS: K_hi[64][264] @0, K_lo @16896, V_hi @33792, V_lo @50688.
// ---------------------------------------------------------------------------
__global__ __launch_bounds__(512, 2) void gemm_kv(
    const unsigned short* __restrict__ Ah, const unsigned short* __restrict__ Al,
    const unsigned short* __restrict__ Bth, const unsigned short* __restrict__ Btl,
    const float* __restrict__ bias, const float2* __restrict__ tab,
    float* __restrict__ Ksum, float* __restrict__ Mt)
{
    __shared__ alignas(16) unsigned short smem[67584];   // 132 KiB
    const int tid = threadIdx.x;
    const int w = tid >> 6, lane = tid & 63;
    const int wr = w >> 1, wc = w & 1;
    const int quad = lane >> 4, lrow = lane & 15;
    int h, mt;
    xcd_swz16(h, mt);
    const int m0 = mt * 256;
    const int n0 = h * 64;
    const int b  = m0 >> 11;
    const int tbase = (m0 & 2047) + wr * 64;
    const int bh_idx = b * NH + h;

    // ---- staging setup (each wave stages 6 x 16-row granule groups)
    const int sr = tid >> 2;                          // 0..127
    const int g  = (tid & 3) ^ ((tid >> 3) & 3);      // pre-swizzled granule
    const unsigned short* gA0 = Ah + (size_t)(m0 + sr) * KDIM + g * 8;
    const unsigned short* gA1 = Ah + (size_t)(m0 + 128 + sr) * KDIM + g * 8;
    const unsigned short* gA2 = Al + (size_t)(m0 + sr) * KDIM + g * 8;
    const unsigned short* gA3 = Al + (size_t)(m0 + 128 + sr) * KDIM + g * 8;
    const size_t brow = (size_t)(n0 + sr) + (sr >= 64 ? (size_t)960 : 0);
    const unsigned short* gB0 = Bth + brow * KDIM + g * 8;
    const unsigned short* gB1 = Btl + brow * KDIM + g * 8;
    const int lA0 = w * 512;                 // A hi rows 0-127
    const int lA1 = 4096 + w * 512;          // A hi rows 128-255
    const int lA2 = 8192 + w * 512;          // A lo rows 0-127
    const int lA3 = 12288 + w * 512;         // A lo rows 128-255
    const int lB0 = 16384 + w * 512;         // B hi [128][32]
    const int lB1 = 20480 + w * 512;         // B lo

    auto STAGE = [&](unsigned short* buf, int k0) {
        __builtin_amdgcn_global_load_lds(
            (const __attribute__((address_space(1))) unsigned int*)(gA0 + k0),
            (__attribute__((address_space(3))) unsigned int*)(buf + lA0), 16, 0, 0);
        __builtin_amdgcn_global_load_lds(
            (const __attribute__((address_space(1))) unsigned int*)(gA1 + k0),
            (__attribute__((address_space(3))) unsigned int*)(buf + lA1), 16, 0, 0);
        __builtin_amdgcn_global_load_lds(
            (const __attribute__((address_space(1))) unsigned int*)(gA2 + k0),
            (__attribute__((address_space(3))) unsigned int*)(buf + lA2), 16, 0, 0);
        __builtin_amdgcn_global_load_lds(
            (const __attribute__((address_space(1))) unsigned int*)(gA3 + k0),
            (__attribute__((address_space(3))) unsigned int*)(buf + lA3), 16, 0, 0);
        __builtin_amdgcn_global_load_lds(
            (const __attribute__((address_space(1))) unsigned int*)(gB0 + k0),
            (__attribute__((address_space(3))) unsigned int*)(buf + lB0), 16, 0, 0);
        __builtin_amdgcn_global_load_lds(
            (const __attribute__((address_space(1))) unsigned int*)(gB1 + k0),
            (__attribute__((address_space(3))) unsigned int*)(buf + lB1), 16, 0, 0);
    };

    // ---- fragment geometry
    const int rowbase = wr * 64, colbase = wc * 64;
    const int sw = ((quad ^ ((lrow >> 1) & 3)) << 3); // swizzled read granule

    f32x4 acc[4][4] = {};
    bf16x8 ahA[4], alA[4], bhA[4], blA[4];
    bf16x8 ahB[4], alB[4], bhB[4], blB[4];

    auto KV_READ = [&](bf16x8 (&AH)[4], bf16x8 (&AL)[4],
                       bf16x8 (&BH)[4], bf16x8 (&BL)[4],
                       const unsigned short* _b) {
        #pragma unroll
        for (int it = 0; it < 4; ++it) {
            int off = (rowbase + it * 16 + lrow) * 32 + sw;
            AH[it] = *(const bf16x8*)&_b[off];
            AL[it] = *(const bf16x8*)&_b[8192 + off];
        }
        #pragma unroll
        for (int jt = 0; jt < 4; ++jt) {
            int boff = (colbase + jt * 16 + lrow) * 32 + sw;
            BH[jt] = *(const bf16x8*)&_b[16384 + boff];
            BL[jt] = *(const bf16x8*)&_b[20480 + boff];
        }
    };
    auto KV_MFMA = [&](bf16x8 (&AH)[4], bf16x8 (&AL)[4],
                       bf16x8 (&BH)[4], bf16x8 (&BL)[4]) {
        #pragma unroll
        for (int it = 0; it < 4; ++it)
            #pragma unroll
            for (int jt = 0; jt < 4; ++jt)
                acc[it][jt] = __builtin_amdgcn_mfma_f32_16x16x32_bf16(AH[it], BH[jt], acc[it][jt], 0, 0, 0);
        #pragma unroll
        for (int it = 0; it < 4; ++it)
            #pragma unroll
            for (int jt = 0; jt < 4; ++jt)
                acc[it][jt] = __builtin_amdgcn_mfma_f32_16x16x32_bf16(AH[it], BL[jt], acc[it][jt], 0, 0, 0);
        #pragma unroll
        for (int it = 0; it < 4; ++it)
            #pragma unroll
            for (int jt = 0; jt < 4; ++jt)
                acc[it][jt] = __builtin_amdgcn_mfma_f32_16x16x32_bf16(AL[it], BH[jt], acc[it][jt], 0, 0, 0);
    };

    unsigned short* buf0 = smem;
    unsigned short* buf1 = smem + 24576;

    STAGE(buf0, 0);
    STAGE(buf1, 32);
    WAITCNT_VM(6);                       // own STAGE(tile0) complete
    __builtin_amdgcn_s_barrier();        // all waves' tile0 resident
    KV_READ(ahA, alA, bhA, blA, buf0);   // tile 0 -> set A

    #pragma unroll 1
    for (int t = 0; t < 32; t += 2) {
        // ---- even: MFMA set A (tile t); read set B (tile t+1); stage t+2
        WAITCNT_VM(0);                   // prev STAGE complete (own)
        WAITCNT_LGKM(0);                 // prev frag reads drained (own)
        __builtin_amdgcn_sched_barrier(0);
        __builtin_amdgcn_s_barrier();
        __builtin_amdgcn_sched_barrier(0);
        if (t + 2 < 32) STAGE(buf0, (t + 2) * 32);
        KV_READ(ahB, alB, bhB, blB, buf1);
        __builtin_amdgcn_s_setprio(1);
        KV_MFMA(ahA, alA, bhA, blA);
        __builtin_amdgcn_s_setprio(0);

        // ---- odd: MFMA set B (tile t+1); read set A (tile t+2); stage t+3
        WAITCNT_VM(0);
        WAITCNT_LGKM(0);
        __builtin_amdgcn_sched_barrier(0);
        __builtin_amdgcn_s_barrier();
        __builtin_amdgcn_sched_barrier(0);
        if (t + 3 < 32) STAGE(buf1, (t + 3) * 32);
        if (t + 2 < 32) KV_READ(ahA, alA, bhA, blA, buf0);
        __builtin_amdgcn_s_setprio(1);
        KV_MFMA(ahB, alB, bhB, blB);
        __builtin_amdgcn_s_setprio(0);
    }
    __syncthreads();   // drain before LDS reuse by epilogue

    // ---------------- epilogue (unchanged) ----------------
    const bool isK = (wc == 0);
    const int colg = (isK ? 0 : C_EMB) + h * 64;
    float bb[4];
    #pragma unroll
    for (int jt = 0; jt < 4; ++jt) bb[jt] = bias[colg + jt * 16 + lrow];
    #pragma unroll
    for (int it = 0; it < 4; ++it)
        #pragma unroll
        for (int jt = 0; jt < 4; ++jt)
            #pragma unroll
            for (int r = 0; r < 4; ++r) {
                float v = acc[it][jt][r] + bb[jt];
                acc[it][jt][r] = isK ? elu1(v) : v;
            }

    if (isK) {
        #pragma unroll
        for (int jt = 0; jt < 4; ++jt) {
            float p = 0.0f;
            #pragma unroll
            for (int it = 0; it < 4; ++it)
                #pragma unroll
                for (int r = 0; r < 4; ++r) p += acc[it][jt][r];
            p += __shfl_xor(p, 16);
            p += __shfl_xor(p, 32);
            if (quad == 0)
                atomicAdd(&Ksum[b * C_EMB + h * 64 + jt * 16 + lrow], p);
        }
        #pragma unroll
        for (int it = 0; it < 4; ++it)
            #pragma unroll
            for (int r = 0; r < 4; ++r) {
                int s = tbase + it * 16 + quad * 4 + r;
                float2 c0 = tab[s * 32 + lrow];
                float2 c1 = tab[s * 32 + 16 + lrow];
                float a0 = acc[it][0][r], a1 = acc[it][1][r];
                float a2 = acc[it][2][r], a3 = acc[it][3][r];
                acc[it][0][r] = a0 * c0.x - a2 * c0.y;
                acc[it][2][r] = a2 * c0.x + a0 * c0.y;
                acc[it][1][r] = a1 * c1.x - a3 * c1.y;
                acc[it][3][r] = a3 * c1.x + a1 * c1.y;
            }
    }

    // transposed LDS: [64 d][264 t] hi/lo per K and V
    unsigned short* Hd = smem + (isK ? 0 : 33792);
    unsigned short* Ld = Hd + 16896;
    #pragma unroll
    for (int jt = 0; jt < 4; ++jt) {
        int d = jt * 16 + lrow;
        #pragma unroll
        for (int it = 0; it < 4; ++it) {
            int t0loc = wr * 64 + it * 16 + quad * 4;
            ushort4 h4, l4;
            float v0 = acc[it][jt][0], v1 = acc[it][jt][1];
            float v2 = acc[it][jt][2], v3 = acc[it][jt][3];
            h4.x = bf16_rne(v0); l4.x = bf16_rne(v0 - bf16_to_f(h4.x));
            h4.y = bf16_rne(v1); l4.y = bf16_rne(v1 - bf16_to_f(h4.y));
            h4.z = bf16_rne(v2); l4.z = bf16_rne(v2 - bf16_to_f(h4.z));
            h4.w = bf16_rne(v3); l4.w = bf16_rne(v3 - bf16_to_f(h4.w));
            *(ushort4*)&Hd[d * 264 + t0loc] = h4;
            *(ushort4*)&Ld[d * 264 + t0loc] = l4;
        }
    }
    __syncthreads();

    {
        const unsigned short* KH = smem;
        const unsigned short* KL = smem + 16896;
        const unsigned short* VH = smem + 33792;
        const unsigned short* VL = smem + 50688;
        const int mrow = (w & 3) * 16 + lrow;   // V feature row
        const int thalf = w >> 2;               // t-half 0/1 (128 each)
        f32x4 macc[4] = {};
        #pragma unroll
        for (int ks = 0; ks < 4; ++ks) {
            int kof = thalf * 128 + ks * 32 + quad * 8;
            bf16x8 vah = *(const bf16x8*)&VH[mrow * 264 + kof];
            bf16x8 val = *(const bf16x8*)&VL[mrow * 264 + kof];
            #pragma unroll
            for (int jt = 0; jt < 4; ++jt) {
                int nrow = jt * 16 + lrow;
                bf16x8 kbh = *(const bf16x8*)&KH[nrow * 264 + kof];
                bf16x8 kbl = *(const bf16x8*)&KL[nrow * 264 + kof];
                macc[jt] = __builtin_amdgcn_mfma_f32_16x16x32_bf16(vah, kbh, macc[jt], 0, 0, 0);
                macc[jt] = __builtin_amdgcn_mfma_f32_16x16x32_bf16(vah, kbl, macc[jt], 0, 0, 0);
                macc[jt] = __builtin_amdgcn_mfma_f32_16x16x32_bf16(val, kbh, macc[jt], 0, 0, 0);
            }
        }
        #pragma unroll
        for (int jt = 0; jt < 4; ++jt)
            #pragma unroll
            for (int r = 0; r < 4; ++r)
                atomicAdd(&Mt[((size_t)bh_idx * 64 + (w & 3) * 16 + quad * 4 + r) * 64 + jt * 16 + lrow],
                          macc[jt][r]);
    }
}

// ---------------------------------------------------------------------------
// 128(M)x64(N) main loop for Q / out. 256 threads (4 waves, per-wave 32x64).
// 2-buffer LDS ring (24576 B each; 48 KiB total -> 3 blocks/CU), distance-1
// staging, 1 barrier/tile, counted lgkm split, product-major MFMA.
// Buffer layout (ushorts): A_hi[128][32] @0, A_lo @4096, B_hi[64][32] @8192,
// B_lo @10240.  BUFSZ = 12288.
// ---------------------------------------------------------------------------
__device__ __forceinline__ void gemm_main_128(
    const unsigned short* __restrict__ Ah, const unsigned short* __restrict__ Al,
    const unsigned short* __restrict__ Bth, const unsigned short* __restrict__ Btl,
    unsigned short* lds, int m0, int n0, f32x4 (&acc)[2][4])
{
    const int tid = threadIdx.x;
    const int w = tid >> 6, lane = tid & 63;
    const int quad = lane >> 4, lrow = lane & 15;
    const int srow = lane >> 2;                       // 0..15
    const int g  = (lane & 3) ^ ((lane >> 3) & 3);    // pre-swizzled granule
    const int sw = ((quad ^ ((lrow >> 1) & 3)) << 3); // swizzled read granule

    const unsigned short* gA0 = Ah + (size_t)(m0 + w * 16 + srow) * KDIM + g * 8;
    const unsigned short* gA1 = Ah + (size_t)(m0 + 64 + w * 16 + srow) * KDIM + g * 8;
    const unsigned short* gA2 = Al + (size_t)(m0 + w * 16 + srow) * KDIM + g * 8;
    const unsigned short* gA3 = Al + (size_t)(m0 + 64 + w * 16 + srow) * KDIM + g * 8;
    const unsigned short* gB0 = Bth + (size_t)(n0 + w * 16 + srow) * KDIM + g * 8;
    const unsigned short* gB1 = Btl + (size_t)(n0 + w * 16 + srow) * KDIM + g * 8;
    const int lA0 = w * 512, lA1 = 2048 + w * 512;
    const int lA2 = 4096 + w * 512, lA3 = 6144 + w * 512;
    const int lB0 = 8192 + w * 512, lB1 = 10240 + w * 512;

    auto STAGE = [&](unsigned short* buf, int k0) {
        __builtin_amdgcn_global_load_lds(
            (const __attribute__((address_space(1))) unsigned int*)(gA0 + k0),
            (__attribute__((address_space(3))) unsigned int*)(buf + lA0), 16, 0, 0);
        __builtin_amdgcn_global_load_lds(
            (const __attribute__((address_space(1))) unsigned int*)(gA1 + k0),
            (__attribute__((address_space(3))) unsigned int*)(buf + lA1), 16, 0, 0);
        __builtin_amdgcn_global_load_lds(
            (const __attribute__((address_space(1))) unsigned int*)(gA2 + k0),
            (__attribute__((address_space(3))) unsigned int*)(buf + lA2), 16, 0, 0);
        __builtin_amdgcn_global_load_lds(
            (const __attribute__((address_space(1))) unsigned int*)(gA3 + k0),
            (__attribute__((address_space(3))) unsigned int*)(buf + lA3), 16, 0, 0);
        __builtin_amdgcn_global_load_lds(
            (const __attribute__((address_space(1))) unsigned int*)(gB0 + k0),
            (__attribute__((address_space(3))) unsigned int*)(buf + lB0), 16, 0, 0);
        __builtin_amdgcn_global_load_lds(
            (const __attribute__((address_space(1))) unsigned int*)(gB1 + k0),
            (__attribute__((address_space(3))) unsigned int*)(buf + lB1), 16, 0, 0);
    };

    STAGE(lds, 0);

    #pragma unroll 1
    for (int t = 0; t < 32; ++t) {
        unsigned short* cur = lds + (t & 1) * 12288;
        unsigned short* nxt = lds + ((t + 1) & 1) * 12288;
        WAITCNT_VM(0);                    // own STAGE(t) complete
        __builtin_amdgcn_sched_barrier(0);
        __builtin_amdgcn_s_barrier();     // all waves: t resident; t-1 reads done
        __builtin_amdgcn_sched_barrier(0);

        bf16x8 ah[2], al[2], bh[4], bl[4];
        #pragma unroll
        for (int it = 0; it < 2; ++it) {
            int off = (w * 32 + it * 16 + lrow) * 32 + sw;
            ah[it] = *(const bf16x8*)&cur[off];
            al[it] = *(const bf16x8*)&cur[4096 + off];
        }
        #pragma unroll
        for (int jt = 0; jt < 2; ++jt) {
            int boff = (jt * 16 + lrow) * 32 + sw;
            bh[jt] = *(const bf16x8*)&cur[8192 + boff];
            bl[jt] = *(const bf16x8*)&cur[10240 + boff];
        }
        CBAR();   // pin group order: lgkm(4) counts exactly the 4 reads below
        #pragma unroll
        for (int jt = 2; jt < 4; ++jt) {
            int boff = (jt * 16 + lrow) * 32 + sw;
            bh[jt] = *(const bf16x8*)&cur[8192 + boff];
            bl[jt] = *(const bf16x8*)&cur[10240 + boff];
        }
        if (t + 1 < 32) STAGE(nxt, (t + 1) * 32);

        WAITCNT_LGKM(4);                  // group 1 (A + B jt01) resident
        __builtin_amdgcn_sched_barrier(0);
        __builtin_amdgcn_s_setprio(1);
        #pragma unroll
        for (int it = 0; it < 2; ++it)
            #pragma unroll
            for (int jt = 0; jt < 2; ++jt)
                acc[it][jt] = __builtin_amdgcn_mfma_f32_16x16x32_bf16(ah[it], bh[jt], acc[it][jt], 0, 0, 0);
        #pragma unroll
        for (int it = 0; it < 2; ++it)
            #pragma unroll
            for (int jt = 0; jt < 2; ++jt)
                acc[it][jt] = __builtin_amdgcn_mfma_f32_16x16x32_bf16(ah[it], bl[jt], acc[it][jt], 0, 0, 0);
        #pragma unroll
        for (int it = 0; it < 2; ++it)
            #pragma unroll
            for (int jt = 0; jt < 2; ++jt)
                acc[it][jt] = __builtin_amdgcn_mfma_f32_16x16x32_bf16(al[it], bh[jt], acc[it][jt], 0, 0, 0);

        WAITCNT_LGKM(0);                  // group 2 (B jt23) resident
        __builtin_amdgcn_sched_barrier(0);
        #pragma unroll
        for (int it = 0; it < 2; ++it)
            #pragma unroll
            for (int jt = 2; jt < 4; ++jt)
                acc[it][jt] = __builtin_amdgcn_mfma_f32_16x16x32_bf16(ah[it], bh[jt], acc[it][jt], 0, 0, 0);
        #pragma unroll
        for (int it = 0; it < 2; ++it)
            #pragma unroll
            for (int jt = 2; jt < 4; ++jt)
                acc[it][jt] = __builtin_amdgcn_mfma_f32_16x16x32_bf16(ah[it], bl[jt], acc[it][jt], 0, 0, 0);
        #pragma unroll
        for (int it = 0; it < 2; ++it)
            #pragma unroll
            for (int jt = 2; jt < 4; ++jt)
                acc[it][jt] = __builtin_amdgcn_mfma_f32_16x16x32_bf16(al[it], bh[jt], acc[it][jt], 0, 0, 0);
        __builtin_amdgcn_s_setprio(0);
    }
    __syncthreads();   // drain before LDS reuse by epilogues
}

// ---------------------------------------------------------------------------
// Q GEMM, 128x64 tile (one head per block), grid (16,32) x 256 thr.
// Epilogue: bias, elu+1, den in regs, RoPE, per-wave Qrot LDS,
// Y = (Qrot @ Mt^T)/den, bf16 hi/lo stores.
// ---------------------------------------------------------------------------
__global__ __launch_bounds__(256, 3) void gemm_q(
    const unsigned short* __restrict__ Ah, const unsigned short* __restrict__ Al,
    const unsigned short* __restrict__ Bth, const unsigned short* __restrict__ Btl,
    const float* __restrict__ bias, const float2* __restrict__ tab,
    const float* __restrict__ Ksum, const float* __restrict__ Mt,
    unsigned short* __restrict__ Yh, unsigned short* __restrict__ Yl)
{
    // main loop uses [0,24576); epilogue reuses [0,18432) as per-wave Qrot
    __shared__ alignas(16) unsigned short smem[24576];   // 48 KiB
    int h, mt;
    xcd_swz32(h, mt);
    const int m0 = mt * 128;
    f32x4 acc[2][4] = {};
    gemm_main_128(Ah, Al, Bth, Btl, smem, m0, h * 64, acc);

    const int tid = threadIdx.x;
    const int w = tid >> 6, lane = tid & 63;
    const int quad = lane >> 4, lrow = lane & 15;
    const int b = m0 >> 11;
    const int tbase = (m0 & 2047) + w * 32;
    const int bh = b * NH + h;

    float bb[4];
    #pragma unroll
    for (int jt = 0; jt < 4; ++jt) bb[jt] = bias[h * 64 + jt * 16 + lrow];
    #pragma unroll
    for (int it = 0; it < 2; ++it)
        #pragma unroll
        for (int jt = 0; jt < 4; ++jt)
            #pragma unroll
            for (int r = 0; r < 4; ++r)
                acc[it][jt][r] = elu1(acc[it][jt][r] + bb[jt]);

    // den (pre-rope), kept in registers
    float ks[4], den_reg[2][4];
    #pragma unroll
    for (int jt = 0; jt < 4; ++jt) ks[jt] = Ksum[b * C_EMB + h * 64 + jt * 16 + lrow];
    #pragma unroll
    for (int it = 0; it < 2; ++it)
        #pragma unroll
        for (int r = 0; r < 4; ++r) {
            float p = acc[it][0][r] * ks[0] + acc[it][1][r] * ks[1]
                    + acc[it][2][r] * ks[2] + acc[it][3][r] * ks[3];
            p += __shfl_xor(p, 1);
            p += __shfl_xor(p, 2);
            p += __shfl_xor(p, 4);
            p += __shfl_xor(p, 8);
            den_reg[it][r] = p;
        }

    // RoPE in registers (pairs jt, jt^2)
    #pragma unroll
    for (int it = 0; it < 2; ++it)
        #pragma unroll
        for (int r = 0; r < 4; ++r) {
            int s = tbase + it * 16 + quad * 4 + r;
            float2 c0 = tab[s * 32 + lrow];
            float2 c1 = tab[s * 32 + 16 + lrow];
            float a0 = acc[it][0][r], a1 = acc[it][1][r];
            float a2 = acc[it][2][r], a3 = acc[it][3][r];
            acc[it][0][r] = a0 * c0.x - a2 * c0.y;
            acc[it][2][r] = a2 * c0.x + a0 * c0.y;
            acc[it][1][r] = a1 * c1.x - a3 * c1.y;
            acc[it][3][r] = a3 * c1.x + a1 * c1.y;
        }

    // Qrot -> per-wave LDS ([32 rows][72], hi then lo). Wave-private region;
    // main loop's final __syncthreads drained cross-wave LDS reads.
    unsigned short* QH = smem + w * 4608;
    unsigned short* QL = QH + 2304;
    #pragma unroll
    for (int it = 0; it < 2; ++it)
        #pragma unroll
        for (int jt = 0; jt < 4; ++jt)
            #pragma unroll
            for (int r = 0; r < 4; ++r) {
                int tloc = it * 16 + quad * 4 + r;
                int d = jt * 16 + lrow;
                float v = acc[it][jt][r];
                unsigned short hh = bf16_rne(v);
                QH[tloc * 72 + d] = hh;
                QL[tloc * 72 + d] = bf16_rne(v - bf16_to_f(hh));
            }

    // Y = (Qrot @ Mt^T) / den
    f32x4 acc2[2][4] = {};
    #pragma unroll
    for (int kc = 0; kc < 2; ++kc) {
        bf16x8 mbh[4], mbl[4];
        #pragma unroll
        for (int jt2 = 0; jt2 < 4; ++jt2) {
            const float* mp = &Mt[((size_t)bh * 64 + jt2 * 16 + lrow) * 64 + kc * 32 + quad * 8];
            #pragma unroll
            for (int e = 0; e < 8; ++e) {
                float x = mp[e];
                unsigned short hh = bf16_rne(x);
                mbh[jt2][e] = (short)hh;
                mbl[jt2][e] = (short)bf16_rne(x - bf16_to_f(hh));
            }
        }
        #pragma unroll
        for (int it2 = 0; it2 < 2; ++it2) {
            int ro = (it2 * 16 + lrow) * 72 + kc * 32 + quad * 8;
            bf16x8 qh = *(const bf16x8*)&QH[ro];
            bf16x8 ql = *(const bf16x8*)&QL[ro];
            #pragma unroll
            for (int jt2 = 0; jt2 < 4; ++jt2) {
                acc2[it2][jt2] = __builtin_amdgcn_mfma_f32_16x16x32_bf16(qh, mbh[jt2], acc2[it2][jt2], 0, 0, 0);
                acc2[it2][jt2] = __builtin_amdgcn_mfma_f32_16x16x32_bf16(qh, mbl[jt2], acc2[it2][jt2], 0, 0, 0);
                acc2[it2][jt2] = __builtin_amdgcn_mfma_f32_16x16x32_bf16(ql, mbh[jt2], acc2[it2][jt2], 0, 0, 0);
            }
        }
    }

    // divide + bf16 hi/lo store
    #pragma unroll
    for (int it2 = 0; it2 < 2; ++it2)
        #pragma unroll
        for (int jt2 = 0; jt2 < 4; ++jt2)
            #pragma unroll
            for (int r = 0; r < 4; ++r) {
                float v = acc2[it2][jt2][r] / den_reg[it2][r];
                size_t o = ((size_t)(m0 + w * 32 + it2 * 16 + quad * 4 + r)) * C_EMB
                         + h * 64 + jt2 * 16 + lrow;
                unsigned short hh = bf16_rne(v);
                Yh[o] = hh;
                Yl[o] = bf16_rne(v - bf16_to_f(hh));
            }
}

// ---------------------------------------------------------------------------
// Output projection GEMM, 128x64 tile: out = Y @ proj_w + proj_b.
// grid (16 n-tiles, 32 m-tiles) x 256 thr.
// ---------------------------------------------------------------------------
__global__ __launch_bounds__(256, 3) void gemm_out(
    const unsigned short* __restrict__ Ah, const unsigned short* __restrict__ Al,
    const unsigned short* __restrict__ Bth, const unsigned short* __restrict__ Btl,
    const float* __restrict__ bias, float* __restrict__ out)
{
    __shared__ alignas(16) unsigned short smem[24576];
    int nt, mt;
    xcd_swz32(nt, mt);
    const int m0 = mt * 128, n0 = nt * 64;
    f32x4 acc[2][4] = {};
    gemm_main_128(Ah, Al, Bth, Btl, smem, m0, n0, acc);

    const int tid = threadIdx.x;
    const int w = tid >> 6, lane = tid & 63;
    const int quad = lane >> 4, lrow = lane & 15;

    #pragma unroll
    for (int jt = 0; jt < 4; ++jt) {
        int gc = n0 + jt * 16 + lrow;
        float bb = bias[gc];
        #pragma unroll
        for (int it = 0; it < 2; ++it) {
            int grb = m0 + w * 32 + it * 16 + quad * 4;
            #pragma unroll
            for (int r = 0; r < 4; ++r)
                out[(size_t)(grb + r) * C_EMB + gc] = acc[it][jt][r] + bb;
        }
    }
}

// ---------------------------------------------------------------------------
extern "C" void kernel_launch(void* const* d_in, const int* in_sizes, int n_in,
                              void* d_out, int out_size, void* d_ws, size_t ws_size,
                              hipStream_t stream)
{
    const float* x      = (const float*)d_in[0];
    const float* memory = (const float*)d_in[1];
    const float* q_w    = (const float*)d_in[2];
    const float* q_b    = (const float*)d_in[3];
    const float* kv_w   = (const float*)d_in[4];
    const float* kv_b   = (const float*)d_in[5];
    const float* proj_w = (const float*)d_in[6];
    const float* proj_b = (const float*)d_in[7];

    if (ws_size < WS_FLOATS * sizeof(float)) return;

    float* ws = (float*)d_ws;
    unsigned short* xh   = (unsigned short*)(ws + OFF_XH);
    unsigned short* xl   = (unsigned short*)(ws + OFF_XL);
    unsigned short* mh   = (unsigned short*)(ws + OFF_MEMH);
    unsigned short* ml   = (unsigned short*)(ws + OFF_MEML);
    unsigned short* qwh  = (unsigned short*)(ws + OFF_QWH);
    unsigned short* qwl  = (unsigned short*)(ws + OFF_QWL);
    unsigned short* kvwh = (unsigned short*)(ws + OFF_KVWH);
    unsigned short* kvwl = (unsigned short*)(ws + OFF_KVWL);
    unsigned short* pwh  = (unsigned short*)(ws + OFF_PWH);
    unsigned short* pwl  = (unsigned short*)(ws + OFF_PWL);
    unsigned short* Yh   = (unsigned short*)(ws + OFF_YH);
    unsigned short* Yl   = (unsigned short*)(ws + OFF_YL);
    float*  Ksum = ws + OFF_KSUM;
    float*  Mm   = ws + OFF_MT;
    float2* tab  = (float2*)(ws + OFF_TAB);

    // One prep dispatch: splits + weight transposes + rope table + zero Ksum/Mt
    prep_kernel<<<PREP_BLOCKS, 256, 0, stream>>>(
        x, memory, q_w, kv_w, proj_w,
        xh, xl, mh, ml, qwh, qwl, kvwh, kvwl, pwh, pwl,
        tab, Ksum /* zero_base: Ksum+Mt contiguous */);

    // KV GEMM (+elu/Ksum/rope + fused Mt accumulate). 256 blocks x 512 thr.
    gemm_kv<<<dim3(16, 16), 512, 0, stream>>>(mh, ml, kvwh, kvwl, kv_b, tab, Ksum, Mm);
    // Q GEMM (+elu/den/rope + fused Y = Qrot·Mt^T/den) -> Yh/Yl. 512 x 256.
    gemm_q<<<dim3(16, 32), 256, 0, stream>>>(xh, xl, qwh, qwl, q_b, tab, Ksum, Mm, Yh, Yl);
    // out = Y @ proj_w + proj_b. 512 x 256.
    gemm_out<<<dim3(16, 32), 256, 0, stream>>>(Yh, Yl, pwh, pwl, proj_b, (float*)d_out);
}

// Round 4
// 240.983 us; speedup vs baseline: 1.0078x; 1.0078x over previous
//
#include <hip/hip_runtime.h>
#include <cstddef>
#include <cstdint>

// Problem constants
#define B_SZ  2
#define T_SEQ 2048
#define S_SEQ 2048
#define C_EMB 1024
#define NH    16
#define HD    64
#define KDIM  1024   // inner dim of the three big GEMMs

typedef __attribute__((ext_vector_type(8))) short bf16x8;
typedef __attribute__((ext_vector_type(4))) float f32x4;

// ---------------------------------------------------------------------------
// Workspace layout (float units).
// ---------------------------------------------------------------------------
#define OFF_XH    ((size_t)0)           // [4096,1024] ushort
#define OFF_XL    ((size_t)2097152)
#define OFF_MEMH  ((size_t)4194304)     // [4096,1024] ushort
#define OFF_MEML  ((size_t)6291456)
#define OFF_QWH   ((size_t)8388608)     // [1024,1024] ushort (transposed [N,K])
#define OFF_QWL   ((size_t)8912896)
#define OFF_KVWH  ((size_t)9437184)     // [2048,1024] ushort
#define OFF_KVWL  ((size_t)10485760)
#define OFF_PWH   ((size_t)11534336)    // [1024,1024] ushort
#define OFF_PWL   ((size_t)12058624)
#define OFF_KSUM  ((size_t)12582912)    // [2,1024]      (zeroed by prep)
#define OFF_MT    ((size_t)12584960)    // [32,64,64]    (zeroed by prep)
#define OFF_TAB   ((size_t)12716032)    // [2048,32] float2
#define OFF_YH    ((size_t)12847104)    // [4096,1024] ushort
#define OFF_YL    ((size_t)14944256)
#define WS_FLOATS ((size_t)17041408)    // ~68.2 MB

__device__ __forceinline__ float elu1(float v) {
    return v > 0.0f ? v + 1.0f : __expf(v);
}
__device__ __forceinline__ unsigned short bf16_rne(float x) {
    union { float f; unsigned int u; } v; v.f = x;
    unsigned int u = v.u;
    return (unsigned short)((u + 0x7FFFu + ((u >> 16) & 1u)) >> 16);
}
__device__ __forceinline__ float bf16_to_f(unsigned short h) {
    union { unsigned int u; float f; } v; v.u = ((unsigned int)h) << 16;
    return v.f;
}

// ---------------------------------------------------------------------------
// Unified prep kernel (block-range dispatch), unchanged.
// ---------------------------------------------------------------------------
#define PREP_BLOCKS 13064

__device__ __forceinline__ void split4_body(
    const float4* __restrict__ in, ushort4* __restrict__ hi,
    ushort4* __restrict__ lo, int i)
{
    float4 v = in[i];
    ushort4 h, l;
    h.x = bf16_rne(v.x); l.x = bf16_rne(v.x - bf16_to_f(h.x));
    h.y = bf16_rne(v.y); l.y = bf16_rne(v.y - bf16_to_f(h.y));
    h.z = bf16_rne(v.z); l.z = bf16_rne(v.z - bf16_to_f(h.z));
    h.w = bf16_rne(v.w); l.w = bf16_rne(v.w - bf16_to_f(h.w));
    hi[i] = h; lo[i] = l;
}

__device__ __forceinline__ void transpose_body(
    const float* __restrict__ W, unsigned short* __restrict__ Wth,
    unsigned short* __restrict__ Wtl, int K, int N, int bx, int by,
    float (*tile)[33])
{
    const int k0 = by * 32, n0 = bx * 32;
    const int tx = threadIdx.x & 31, ty = threadIdx.x >> 5;
    #pragma unroll
    for (int j = 0; j < 4; ++j)
        tile[ty + j * 8][tx] = W[(size_t)(k0 + ty + j * 8) * N + n0 + tx];
    __syncthreads();
    #pragma unroll
    for (int j = 0; j < 4; ++j) {
        float x = tile[tx][ty + j * 8];
        unsigned short h = bf16_rne(x);
        unsigned short l = bf16_rne(x - bf16_to_f(h));
        size_t o = (size_t)(n0 + ty + j * 8) * K + k0 + tx;
        Wth[o] = h; Wtl[o] = l;
    }
}

__global__ __launch_bounds__(256) void prep_kernel(
    const float* __restrict__ x, const float* __restrict__ memory,
    const float* __restrict__ q_w, const float* __restrict__ kv_w,
    const float* __restrict__ proj_w,
    unsigned short* __restrict__ xh, unsigned short* __restrict__ xl,
    unsigned short* __restrict__ mh, unsigned short* __restrict__ ml,
    unsigned short* __restrict__ qwh, unsigned short* __restrict__ qwl,
    unsigned short* __restrict__ kvwh, unsigned short* __restrict__ kvwl,
    unsigned short* __restrict__ pwh, unsigned short* __restrict__ pwl,
    float2* __restrict__ tab, float* __restrict__ zero_base)
{
    __shared__ float tile[32][33];
    const int bid = blockIdx.x;
    const int tid = threadIdx.x;
    if (bid < 4096) {
        split4_body((const float4*)x, (ushort4*)xh, (ushort4*)xl, bid * 256 + tid);
    } else if (bid < 8192) {
        split4_body((const float4*)memory, (ushort4*)mh, (ushort4*)ml, (bid - 4096) * 256 + tid);
    } else if (bid < 9216) {
        int i = bid - 8192;
        transpose_body(q_w, qwh, qwl, 1024, 1024, i & 31, i >> 5, tile);
    } else if (bid < 11264) {
        int i = bid - 9216;
        transpose_body(kv_w, kvwh, kvwl, 1024, 2048, i & 63, i >> 6, tile);
    } else if (bid < 12288) {
        int i = bid - 11264;
        transpose_body(proj_w, pwh, pwl, 1024, 1024, i & 31, i >> 5, tile);
    } else if (bid < 12544) {
        int idx = (bid - 12288) * 256 + tid;    // pos*32 + i
        int pos = idx >> 5, i = idx & 31;
        double invf = exp(-(double)i * (9.210340371976184 / 32.0));  // 10000^(-i/32)
        float arg = (float)((double)pos * invf);
        float sn, cs;
        sincosf(arg, &sn, &cs);
        tab[idx] = make_float2(cs, sn);
    } else {
        int idx = (bid - 12544) * 256 + tid;
        if (idx < 2048 + 131072) zero_base[idx] = 0.0f;   // Ksum + Mt
    }
}

#define WAITCNT_VM(N)   asm volatile("s_waitcnt vmcnt(" #N ")" ::: "memory")
#define WAITCNT_LGKM(N) asm volatile("s_waitcnt lgkmcnt(" #N ")" ::: "memory")
#define CBAR()          asm volatile("" ::: "memory")

// ---------------------------------------------------------------------------
// Bijective XCD swizzles (id%8 assumed = XCD).
// 16x16 grid: XCD x owns by in {2x,2x+1}, all 16 bx.
// 16x32 grid: XCD x owns by in {4x..4x+3}, all 16 bx.
// ---------------------------------------------------------------------------
__device__ __forceinline__ void xcd_swz16(int& bx, int& by) {
    int id = (int)(blockIdx.x + (blockIdx.y << 4));
    int x = id & 7, k = id >> 3;
    bx = k >> 1;
    by = x * 2 + (k & 1);
}
__device__ __forceinline__ void xcd_swz32(int& bx, int& by) {
    int id = (int)(blockIdx.x + (blockIdx.y << 4));   // 0..511
    int x = id & 7, k = id >> 3;                      // k 0..63
    bx = k >> 2;                                      // 0..15
    by = x * 4 + (k & 3);                             // 0..31
}

// ---------------------------------------------------------------------------
// KV GEMM: 256(M)x128(N) head-paired tile. Register-double-buffered main
// loop, LAMBDA-FREE (round-3's lambdas with array-ref captures forced the
// fragment sets to scratch: VGPR 128 + WRITE_SIZE 23 MB). Per half-iter:
// {vmcnt(0); lgkm(0); barrier; STAGE(t+2); ds_read frags(t+1) -> other set;
// 48 MFMA on current set with NO intervening waits}. 2-buffer LDS ring.
// 512 threads (8 waves, wr x wc = 4x2, per-wave 64x64). 1 barrier/tile.
// Epilogue LDS: K_hi[64][264] @0, K_lo @16896, V_hi @33792, V_lo @50688.
// ---------------------------------------------------------------------------
#define KV_READ(S, BUF) do {                                                   \
    _Pragma("unroll")                                                          \
    for (int it = 0; it < 4; ++it) {                                           \
        int off = (rowbase + it * 16 + lrow) * 32 + sw;                        \
        ah##S[it] = *(const bf16x8*)&(BUF)[off];                               \
        al##S[it] = *(const bf16x8*)&(BUF)[8192 + off];                        \
    }                                                                          \
    _Pragma("unroll")                                                          \
    for (int jt = 0; jt < 4; ++jt) {                                           \
        int boff = (colbase + jt * 16 + lrow) * 32 + sw;                       \
        bh##S[jt] = *(const bf16x8*)&(BUF)[16384 + boff];                      \
        bl##S[jt] = *(const bf16x8*)&(BUF)[20480 + boff];                      \
    }                                                                          \
} while (0)

#define KV_MFMA(S) do {                                                        \
    _Pragma("unroll")                                                          \
    for (int it = 0; it < 4; ++it)                                             \
        _Pragma("unroll")                                                      \
        for (int jt = 0; jt < 4; ++jt)                                         \
            acc[it][jt] = __builtin_amdgcn_mfma_f32_16x16x32_bf16(             \
                ah##S[it], bh##S[jt], acc[it][jt], 0, 0, 0);                   \
    _Pragma("unroll")                                                          \
    for (int it = 0; it < 4; ++it)                                             \
        _Pragma("unroll")                                                      \
        for (int jt = 0; jt < 4; ++jt)                                         \
            acc[it][jt] = __builtin_amdgcn_mfma_f32_16x16x32_bf16(             \
                ah##S[it], bl##S[jt], acc[it][jt], 0, 0, 0);                   \
    _Pragma("unroll")                                                          \
    for (int it = 0; it < 4; ++it)                                             \
        _Pragma("unroll")                                                      \
        for (int jt = 0; jt < 4; ++jt)                                         \
            acc[it][jt] = __builtin_amdgcn_mfma_f32_16x16x32_bf16(             \
                al##S[it], bh##S[jt], acc[it][jt], 0, 0, 0);                   \
} while (0)

__global__ __launch_bounds__(512, 2) void gemm_kv(
    const unsigned short* __restrict__ Ah, const unsigned short* __restrict__ Al,
    const unsigned short* __restrict__ Bth, const unsigned short* __restrict__ Btl,
    const float* __restrict__ bias, const float2* __restrict__ tab,
    float* __restrict__ Ksum, float* __restrict__ Mt)
{
    __shared__ alignas(16) unsigned short smem[67584];   // 132 KiB
    const int tid = threadIdx.x;
    const int w = tid >> 6, lane = tid & 63;
    const int wr = w >> 1, wc = w & 1;
    const int quad = lane >> 4, lrow = lane & 15;
    int h, mt;
    xcd_swz16(h, mt);
    const int m0 = mt * 256;
    const int n0 = h * 64;
    const int b  = m0 >> 11;
    const int tbase = (m0 & 2047) + wr * 64;
    const int bh_idx = b * NH + h;

    // ---- staging setup (each wave stages 6 x 16-row granule groups)
    const int sr = tid >> 2;                          // 0..127
    const int g  = (tid & 3) ^ ((tid >> 3) & 3);      // pre-swizzled granule
    const unsigned short* gA0 = Ah + (size_t)(m0 + sr) * KDIM + g * 8;
    const unsigned short* gA1 = Ah + (size_t)(m0 + 128 + sr) * KDIM + g * 8;
    const unsigned short* gA2 = Al + (size_t)(m0 + sr) * KDIM + g * 8;
    const unsigned short* gA3 = Al + (size_t)(m0 + 128 + sr) * KDIM + g * 8;
    const size_t brow = (size_t)(n0 + sr) + (sr >= 64 ? (size_t)960 : 0);
    const unsigned short* gB0 = Bth + brow * KDIM + g * 8;
    const unsigned short* gB1 = Btl + brow * KDIM + g * 8;
    const int lA0 = w * 512;                 // A hi rows 0-127
    const int lA1 = 4096 + w * 512;          // A hi rows 128-255
    const int lA2 = 8192 + w * 512;          // A lo rows 0-127
    const int lA3 = 12288 + w * 512;         // A lo rows 128-255
    const int lB0 = 16384 + w * 512;         // B hi [128][32]
    const int lB1 = 20480 + w * 512;         // B lo

    auto STAGE = [&](unsigned short* buf, int k0) {
        __builtin_amdgcn_global_load_lds(
            (const __attribute__((address_space(1))) unsigned int*)(gA0 + k0),
            (__attribute__((address_space(3))) unsigned int*)(buf + lA0), 16, 0, 0);
        __builtin_amdgcn_global_load_lds(
            (const __attribute__((address_space(1))) unsigned int*)(gA1 + k0),
            (__attribute__((address_space(3))) unsigned int*)(buf + lA1), 16, 0, 0);
        __builtin_amdgcn_global_load_lds(
            (const __attribute__((address_space(1))) unsigned int*)(gA2 + k0),
            (__attribute__((address_space(3))) unsigned int*)(buf + lA2), 16, 0, 0);
        __builtin_amdgcn_global_load_lds(
            (const __attribute__((address_space(1))) unsigned int*)(gA3 + k0),
            (__attribute__((address_space(3))) unsigned int*)(buf + lA3), 16, 0, 0);
        __builtin_amdgcn_global_load_lds(
            (const __attribute__((address_space(1))) unsigned int*)(gB0 + k0),
            (__attribute__((address_space(3))) unsigned int*)(buf + lB0), 16, 0, 0);
        __builtin_amdgcn_global_load_lds(
            (const __attribute__((address_space(1))) unsigned int*)(gB1 + k0),
            (__attribute__((address_space(3))) unsigned int*)(buf + lB1), 16, 0, 0);
    };

    // ---- fragment geometry
    const int rowbase = wr * 64, colbase = wc * 64;
    const int sw = ((quad ^ ((lrow >> 1) & 3)) << 3); // swizzled read granule

    f32x4 acc[4][4] = {};
    bf16x8 ahA[4], alA[4], bhA[4], blA[4];
    bf16x8 ahB[4], alB[4], bhB[4], blB[4];

    unsigned short* buf0 = smem;
    unsigned short* buf1 = smem + 24576;

    STAGE(buf0, 0);
    STAGE(buf1, 32);
    WAITCNT_VM(6);                       // own STAGE(tile0) complete
    __builtin_amdgcn_s_barrier();        // all waves' tile0 resident
    KV_READ(A, buf0);                    // tile 0 -> set A

    #pragma unroll 1
    for (int t = 0; t < 32; t += 2) {
        // ---- even: MFMA set A (tile t); read set B (tile t+1); stage t+2
        WAITCNT_VM(0);                   // prev STAGE complete (own)
        WAITCNT_LGKM(0);                 // prev frag reads drained (own)
        __builtin_amdgcn_sched_barrier(0);
        __builtin_amdgcn_s_barrier();
        __builtin_amdgcn_sched_barrier(0);
        if (t + 2 < 32) STAGE(buf0, (t + 2) * 32);
        KV_READ(B, buf1);
        __builtin_amdgcn_s_setprio(1);
        KV_MFMA(A);
        __builtin_amdgcn_s_setprio(0);

        // ---- odd: MFMA set B (tile t+1); read set A (tile t+2); stage t+3
        WAITCNT_VM(0);
        WAITCNT_LGKM(0);
        __builtin_amdgcn_sched_barrier(0);
        __builtin_amdgcn_s_barrier();
        __builtin_amdgcn_sched_barrier(0);
        if (t + 3 < 32) STAGE(buf1, (t + 3) * 32);
        if (t + 2 < 32) KV_READ(A, buf0);
        __builtin_amdgcn_s_setprio(1);
        KV_MFMA(B);
        __builtin_amdgcn_s_setprio(0);
    }
    __syncthreads();   // drain before LDS reuse by epilogue

    // ---------------- epilogue (unchanged, verified) ----------------
    const bool isK = (wc == 0);
    const int colg = (isK ? 0 : C_EMB) + h * 64;
    float bb[4];
    #pragma unroll
    for (int jt = 0; jt < 4; ++jt) bb[jt] = bias[colg + jt * 16 + lrow];
    #pragma unroll
    for (int it = 0; it < 4; ++it)
        #pragma unroll
        for (int jt = 0; jt < 4; ++jt)
            #pragma unroll
            for (int r = 0; r < 4; ++r) {
                float v = acc[it][jt][r] + bb[jt];
                acc[it][jt][r] = isK ? elu1(v) : v;
            }

    if (isK) {
        #pragma unroll
        for (int jt = 0; jt < 4; ++jt) {
            float p = 0.0f;
            #pragma unroll
            for (int it = 0; it < 4; ++it)
                #pragma unroll
                for (int r = 0; r < 4; ++r) p += acc[it][jt][r];
            p += __shfl_xor(p, 16);
            p += __shfl_xor(p, 32);
            if (quad == 0)
                atomicAdd(&Ksum[b * C_EMB + h * 64 + jt * 16 + lrow], p);
        }
        #pragma unroll
        for (int it = 0; it < 4; ++it)
            #pragma unroll
            for (int r = 0; r < 4; ++r) {
                int s = tbase + it * 16 + quad * 4 + r;
                float2 c0 = tab[s * 32 + lrow];
                float2 c1 = tab[s * 32 + 16 + lrow];
                float a0 = acc[it][0][r], a1 = acc[it][1][r];
                float a2 = acc[it][2][r], a3 = acc[it][3][r];
                acc[it][0][r] = a0 * c0.x - a2 * c0.y;
                acc[it][2][r] = a2 * c0.x + a0 * c0.y;
                acc[it][1][r] = a1 * c1.x - a3 * c1.y;
                acc[it][3][r] = a3 * c1.x + a1 * c1.y;
            }
    }

    // transposed LDS: [64 d][264 t] hi/lo per K and V
    unsigned short* Hd = smem + (isK ? 0 : 33792);
    unsigned short* Ld = Hd + 16896;
    #pragma unroll
    for (int jt = 0; jt < 4; ++jt) {
        int d = jt * 16 + lrow;
        #pragma unroll
        for (int it = 0; it < 4; ++it) {
            int t0loc = wr * 64 + it * 16 + quad * 4;
            ushort4 h4, l4;
            float v0 = acc[it][jt][0], v1 = acc[it][jt][1];
            float v2 = acc[it][jt][2], v3 = acc[it][jt][3];
            h4.x = bf16_rne(v0); l4.x = bf16_rne(v0 - bf16_to_f(h4.x));
            h4.y = bf16_rne(v1); l4.y = bf16_rne(v1 - bf16_to_f(h4.y));
            h4.z = bf16_rne(v2); l4.z = bf16_rne(v2 - bf16_to_f(h4.z));
            h4.w = bf16_rne(v3); l4.w = bf16_rne(v3 - bf16_to_f(h4.w));
            *(ushort4*)&Hd[d * 264 + t0loc] = h4;
            *(ushort4*)&Ld[d * 264 + t0loc] = l4;
        }
    }
    __syncthreads();

    {
        const unsigned short* KH = smem;
        const unsigned short* KL = smem + 16896;
        const unsigned short* VH = smem + 33792;
        const unsigned short* VL = smem + 50688;
        const int mrow = (w & 3) * 16 + lrow;   // V feature row
        const int thalf = w >> 2;               // t-half 0/1 (128 each)
        f32x4 macc[4] = {};
        #pragma unroll
        for (int ks = 0; ks < 4; ++ks) {
            int kof = thalf * 128 + ks * 32 + quad * 8;
            bf16x8 vah = *(const bf16x8*)&VH[mrow * 264 + kof];
            bf16x8 val = *(const bf16x8*)&VL[mrow * 264 + kof];
            #pragma unroll
            for (int jt = 0; jt < 4; ++jt) {
                int nrow = jt * 16 + lrow;
                bf16x8 kbh = *(const bf16x8*)&KH[nrow * 264 + kof];
                bf16x8 kbl = *(const bf16x8*)&KL[nrow * 264 + kof];
                macc[jt] = __builtin_amdgcn_mfma_f32_16x16x32_bf16(vah, kbh, macc[jt], 0, 0, 0);
                macc[jt] = __builtin_amdgcn_mfma_f32_16x16x32_bf16(vah, kbl, macc[jt], 0, 0, 0);
                macc[jt] = __builtin_amdgcn_mfma_f32_16x16x32_bf16(val, kbh, macc[jt], 0, 0, 0);
            }
        }
        #pragma unroll
        for (int jt = 0; jt < 4; ++jt)
            #pragma unroll
            for (int r = 0; r < 4; ++r)
                atomicAdd(&Mt[((size_t)bh_idx * 64 + (w & 3) * 16 + quad * 4 + r) * 64 + jt * 16 + lrow],
                          macc[jt][r]);
    }
}

// ---------------------------------------------------------------------------
// 128(M)x64(N) main loop for Q / out. 256 threads (4 waves, per-wave 32x64).
// 2-buffer LDS ring (48 KiB total -> 3 blocks/CU), distance-1 staging,
// 1 barrier/tile, counted lgkm split, product-major MFMA. (round-3 version)
// ---------------------------------------------------------------------------
__device__ __forceinline__ void gemm_main_128(
    const unsigned short* __restrict__ Ah, const unsigned short* __restrict__ Al,
    const unsigned short* __restrict__ Bth, const unsigned short* __restrict__ Btl,
    unsigned short* lds, int m0, int n0, f32x4 (&acc)[2][4])
{
    const int tid = threadIdx.x;
    const int w = tid >> 6, lane = tid & 63;
    const int quad = lane >> 4, lrow = lane & 15;
    const int srow = lane >> 2;                       // 0..15
    const int g  = (lane & 3) ^ ((lane >> 3) & 3);    // pre-swizzled granule
    const int sw = ((quad ^ ((lrow >> 1) & 3)) << 3); // swizzled read granule

    const unsigned short* gA0 = Ah + (size_t)(m0 + w * 16 + srow) * KDIM + g * 8;
    const unsigned short* gA1 = Ah + (size_t)(m0 + 64 + w * 16 + srow) * KDIM + g * 8;
    const unsigned short* gA2 = Al + (size_t)(m0 + w * 16 + srow) * KDIM + g * 8;
    const unsigned short* gA3 = Al + (size_t)(m0 + 64 + w * 16 + srow) * KDIM + g * 8;
    const unsigned short* gB0 = Bth + (size_t)(n0 + w * 16 + srow) * KDIM + g * 8;
    const unsigned short* gB1 = Btl + (size_t)(n0 + w * 16 + srow) * KDIM + g * 8;
    const int lA0 = w * 512, lA1 = 2048 + w * 512;
    const int lA2 = 4096 + w * 512, lA3 = 6144 + w * 512;
    const int lB0 = 8192 + w * 512, lB1 = 10240 + w * 512;

    auto STAGE = [&](unsigned short* buf, int k0) {
        __builtin_amdgcn_global_load_lds(
            (const __attribute__((address_space(1))) unsigned int*)(gA0 + k0),
            (__attribute__((address_space(3))) unsigned int*)(buf + lA0), 16, 0, 0);
        __builtin_amdgcn_global_load_lds(
            (const __attribute__((address_space(1))) unsigned int*)(gA1 + k0),
            (__attribute__((address_space(3))) unsigned int*)(buf + lA1), 16, 0, 0);
        __builtin_amdgcn_global_load_lds(
            (const __attribute__((address_space(1))) unsigned int*)(gA2 + k0),
            (__attribute__((address_space(3))) unsigned int*)(buf + lA2), 16, 0, 0);
        __builtin_amdgcn_global_load_lds(
            (const __attribute__((address_space(1))) unsigned int*)(gA3 + k0),
            (__attribute__((address_space(3))) unsigned int*)(buf + lA3), 16, 0, 0);
        __builtin_amdgcn_global_load_lds(
            (const __attribute__((address_space(1))) unsigned int*)(gB0 + k0),
            (__attribute__((address_space(3))) unsigned int*)(buf + lB0), 16, 0, 0);
        __builtin_amdgcn_global_load_lds(
            (const __attribute__((address_space(1))) unsigned int*)(gB1 + k0),
            (__attribute__((address_space(3))) unsigned int*)(buf + lB1), 16, 0, 0);
    };

    STAGE(lds, 0);

    #pragma unroll 1
    for (int t = 0; t < 32; ++t) {
        unsigned short* cur = lds + (t & 1) * 12288;
        unsigned short* nxt = lds + ((t + 1) & 1) * 12288;
        WAITCNT_VM(0);                    // own STAGE(t) complete
        __builtin_amdgcn_sched_barrier(0);
        __builtin_amdgcn_s_barrier();     // all waves: t resident; t-1 reads done
        __builtin_amdgcn_sched_barrier(0);

        bf16x8 ah[2], al[2], bh[4], bl[4];
        #pragma unroll
        for (int it = 0; it < 2; ++it) {
            int off = (w * 32 + it * 16 + lrow) * 32 + sw;
            ah[it] = *(const bf16x8*)&cur[off];
            al[it] = *(const bf16x8*)&cur[4096 + off];
        }
        #pragma unroll
        for (int jt = 0; jt < 2; ++jt) {
            int boff = (jt * 16 + lrow) * 32 + sw;
            bh[jt] = *(const bf16x8*)&cur[8192 + boff];
            bl[jt] = *(const bf16x8*)&cur[10240 + boff];
        }
        CBAR();   // pin group order: lgkm(4) counts exactly the 4 reads below
        #pragma unroll
        for (int jt = 2; jt < 4; ++jt) {
            int boff = (jt * 16 + lrow) * 32 + sw;
            bh[jt] = *(const bf16x8*)&cur[8192 + boff];
            bl[jt] = *(const bf16x8*)&cur[10240 + boff];
        }
        if (t + 1 < 32) STAGE(nxt, (t + 1) * 32);

        WAITCNT_LGKM(4);                  // group 1 (A + B jt01) resident
        __builtin_amdgcn_sched_barrier(0);
        __builtin_amdgcn_s_setprio(1);
        #pragma unroll
        for (int it = 0; it < 2; ++it)
            #pragma unroll
            for (int jt = 0; jt < 2; ++jt)
                acc[it][jt] = __builtin_amdgcn_mfma_f32_16x16x32_bf16(ah[it], bh[jt], acc[it][jt], 0, 0, 0);
        #pragma unroll
        for (int it = 0; it < 2; ++it)
            #pragma unroll
            for (int jt = 0; jt < 2; ++jt)
                acc[it][jt] = __builtin_amdgcn_mfma_f32_16x16x32_bf16(ah[it], bl[jt], acc[it][jt], 0, 0, 0);
        #pragma unroll
        for (int it = 0; it < 2; ++it)
            #pragma unroll
            for (int jt = 0; jt < 2; ++jt)
                acc[it][jt] = __builtin_amdgcn_mfma_f32_16x16x32_bf16(al[it], bh[jt], acc[it][jt], 0, 0, 0);

        WAITCNT_LGKM(0);                  // group 2 (B jt23) resident
        __builtin_amdgcn_sched_barrier(0);
        #pragma unroll
        for (int it = 0; it < 2; ++it)
            #pragma unroll
            for (int jt = 2; jt < 4; ++jt)
                acc[it][jt] = __builtin_amdgcn_mfma_f32_16x16x32_bf16(ah[it], bh[jt], acc[it][jt], 0, 0, 0);
        #pragma unroll
        for (int it = 0; it < 2; ++it)
            #pragma unroll
            for (int jt = 2; jt < 4; ++jt)
                acc[it][jt] = __builtin_amdgcn_mfma_f32_16x16x32_bf16(ah[it], bl[jt], acc[it][jt], 0, 0, 0);
        #pragma unroll
        for (int it = 0; it < 2; ++it)
            #pragma unroll
            for (int jt = 2; jt < 4; ++jt)
                acc[it][jt] = __builtin_amdgcn_mfma_f32_16x16x32_bf16(al[it], bh[jt], acc[it][jt], 0, 0, 0);
        __builtin_amdgcn_s_setprio(0);
    }
    __syncthreads();   // drain before LDS reuse by epilogues
}

// ---------------------------------------------------------------------------
// Q GEMM, 128x64 tile (one head per block), grid (16,32) x 256 thr.
// Epilogue: bias, elu+1, den in regs, RoPE, per-wave Qrot LDS,
// Y = (Qrot @ Mt^T)/den, bf16 hi/lo stores.
// ---------------------------------------------------------------------------
__global__ __launch_bounds__(256, 3) void gemm_q(
    const unsigned short* __restrict__ Ah, const unsigned short* __restrict__ Al,
    const unsigned short* __restrict__ Bth, const unsigned short* __restrict__ Btl,
    const float* __restrict__ bias, const float2* __restrict__ tab,
    const float* __restrict__ Ksum, const float* __restrict__ Mt,
    unsigned short* __restrict__ Yh, unsigned short* __restrict__ Yl)
{
    // main loop uses [0,24576); epilogue reuses [0,18432) as per-wave Qrot
    __shared__ alignas(16) unsigned short smem[24576];   // 48 KiB
    int h, mt;
    xcd_swz32(h, mt);
    const int m0 = mt * 128;
    f32x4 acc[2][4] = {};
    gemm_main_128(Ah, Al, Bth, Btl, smem, m0, h * 64, acc);

    const int tid = threadIdx.x;
    const int w = tid >> 6, lane = tid & 63;
    const int quad = lane >> 4, lrow = lane & 15;
    const int b = m0 >> 11;
    const int tbase = (m0 & 2047) + w * 32;
    const int bh = b * NH + h;

    float bb[4];
    #pragma unroll
    for (int jt = 0; jt < 4; ++jt) bb[jt] = bias[h * 64 + jt * 16 + lrow];
    #pragma unroll
    for (int it = 0; it < 2; ++it)
        #pragma unroll
        for (int jt = 0; jt < 4; ++jt)
            #pragma unroll
            for (int r = 0; r < 4; ++r)
                acc[it][jt][r] = elu1(acc[it][jt][r] + bb[jt]);

    // den (pre-rope), kept in registers
    float ks[4], den_reg[2][4];
    #pragma unroll
    for (int jt = 0; jt < 4; ++jt) ks[jt] = Ksum[b * C_EMB + h * 64 + jt * 16 + lrow];
    #pragma unroll
    for (int it = 0; it < 2; ++it)
        #pragma unroll
        for (int r = 0; r < 4; ++r) {
            float p = acc[it][0][r] * ks[0] + acc[it][1][r] * ks[1]
                    + acc[it][2][r] * ks[2] + acc[it][3][r] * ks[3];
            p += __shfl_xor(p, 1);
            p += __shfl_xor(p, 2);
            p += __shfl_xor(p, 4);
            p += __shfl_xor(p, 8);
            den_reg[it][r] = p;
        }

    // RoPE in registers (pairs jt, jt^2)
    #pragma unroll
    for (int it = 0; it < 2; ++it)
        #pragma unroll
        for (int r = 0; r < 4; ++r) {
            int s = tbase + it * 16 + quad * 4 + r;
            float2 c0 = tab[s * 32 + lrow];
            float2 c1 = tab[s * 32 + 16 + lrow];
            float a0 = acc[it][0][r], a1 = acc[it][1][r];
            float a2 = acc[it][2][r], a3 = acc[it][3][r];
            acc[it][0][r] = a0 * c0.x - a2 * c0.y;
            acc[it][2][r] = a2 * c0.x + a0 * c0.y;
            acc[it][1][r] = a1 * c1.x - a3 * c1.y;
            acc[it][3][r] = a3 * c1.x + a1 * c1.y;
        }

    // Qrot -> per-wave LDS ([32 rows][72], hi then lo). Wave-private region;
    // main loop's final __syncthreads drained cross-wave LDS reads.
    unsigned short* QH = smem + w * 4608;
    unsigned short* QL = QH + 2304;
    #pragma unroll
    for (int it = 0; it < 2; ++it)
        #pragma unroll
        for (int jt = 0; jt < 4; ++jt)
            #pragma unroll
            for (int r = 0; r < 4; ++r) {
                int tloc = it * 16 + quad * 4 + r;
                int d = jt * 16 + lrow;
                float v = acc[it][jt][r];
                unsigned short hh = bf16_rne(v);
                QH[tloc * 72 + d] = hh;
                QL[tloc * 72 + d] = bf16_rne(v - bf16_to_f(hh));
            }

    // Y = (Qrot @ Mt^T) / den
    f32x4 acc2[2][4] = {};
    #pragma unroll
    for (int kc = 0; kc < 2; ++kc) {
        bf16x8 mbh[4], mbl[4];
        #pragma unroll
        for (int jt2 = 0; jt2 < 4; ++jt2) {
            const float* mp = &Mt[((size_t)bh * 64 + jt2 * 16 + lrow) * 64 + kc * 32 + quad * 8];
            #pragma unroll
            for (int e = 0; e < 8; ++e) {
                float x = mp[e];
                unsigned short hh = bf16_rne(x);
                mbh[jt2][e] = (short)hh;
                mbl[jt2][e] = (short)bf16_rne(x - bf16_to_f(hh));
            }
        }
        #pragma unroll
        for (int it2 = 0; it2 < 2; ++it2) {
            int ro = (it2 * 16 + lrow) * 72 + kc * 32 + quad * 8;
            bf16x8 qh = *(const bf16x8*)&QH[ro];
            bf16x8 ql = *(const bf16x8*)&QL[ro];
            #pragma unroll
            for (int jt2 = 0; jt2 < 4; ++jt2) {
                acc2[it2][jt2] = __builtin_amdgcn_mfma_f32_16x16x32_bf16(qh, mbh[jt2], acc2[it2][jt2], 0, 0, 0);
                acc2[it2][jt2] = __builtin_amdgcn_mfma_f32_16x16x32_bf16(qh, mbl[jt2], acc2[it2][jt2], 0, 0, 0);
                acc2[it2][jt2] = __builtin_amdgcn_mfma_f32_16x16x32_bf16(ql, mbh[jt2], acc2[it2][jt2], 0, 0, 0);
            }
        }
    }

    // divide + bf16 hi/lo store
    #pragma unroll
    for (int it2 = 0; it2 < 2; ++it2)
        #pragma unroll
        for (int jt2 = 0; jt2 < 4; ++jt2)
            #pragma unroll
            for (int r = 0; r < 4; ++r) {
                float v = acc2[it2][jt2][r] / den_reg[it2][r];
                size_t o = ((size_t)(m0 + w * 32 + it2 * 16 + quad * 4 + r)) * C_EMB
                         + h * 64 + jt2 * 16 + lrow;
                unsigned short hh = bf16_rne(v);
                Yh[o] = hh;
                Yl[o] = bf16_rne(v - bf16_to_f(hh));
            }
}

// ---------------------------------------------------------------------------
// Output projection GEMM, 128x64 tile: out = Y @ proj_w + proj_b.
// grid (16 n-tiles, 32 m-tiles) x 256 thr.
// ---------------------------------------------------------------------------
__global__ __launch_bounds__(256, 3) void gemm_out(
    const unsigned short* __restrict__ Ah, const unsigned short* __restrict__ Al,
    const unsigned short* __restrict__ Bth, const unsigned short* __restrict__ Btl,
    const float* __restrict__ bias, float* __restrict__ out)
{
    __shared__ alignas(16) unsigned short smem[24576];
    int nt, mt;
    xcd_swz32(nt, mt);
    const int m0 = mt * 128, n0 = nt * 64;
    f32x4 acc[2][4] = {};
    gemm_main_128(Ah, Al, Bth, Btl, smem, m0, n0, acc);

    const int tid = threadIdx.x;
    const int w = tid >> 6, lane = tid & 63;
    const int quad = lane >> 4, lrow = lane & 15;

    #pragma unroll
    for (int jt = 0; jt < 4; ++jt) {
        int gc = n0 + jt * 16 + lrow;
        float bb = bias[gc];
        #pragma unroll
        for (int it = 0; it < 2; ++it) {
            int grb = m0 + w * 32 + it * 16 + quad * 4;
            #pragma unroll
            for (int r = 0; r < 4; ++r)
                out[(size_t)(grb + r) * C_EMB + gc] = acc[it][jt][r] + bb;
        }
    }
}

// ---------------------------------------------------------------------------
extern "C" void kernel_launch(void* const* d_in, const int* in_sizes, int n_in,
                              void* d_out, int out_size, void* d_ws, size_t ws_size,
                              hipStream_t stream)
{
    const float* x      = (const float*)d_in[0];
    const float* memory = (const float*)d_in[1];
    const float* q_w    = (const float*)d_in[2];
    const float* q_b    = (const float*)d_in[3];
    const float* kv_w   = (const float*)d_in[4];
    const float* kv_b   = (const float*)d_in[5];
    const float* proj_w = (const float*)d_in[6];
    const float* proj_b = (const float*)d_in[7];

    if (ws_size < WS_FLOATS * sizeof(float)) return;

    float* ws = (float*)d_ws;
    unsigned short* xh   = (unsigned short*)(ws + OFF_XH);
    unsigned short* xl   = (unsigned short*)(ws + OFF_XL);
    unsigned short* mh   = (unsigned short*)(ws + OFF_MEMH);
    unsigned short* ml   = (unsigned short*)(ws + OFF_MEML);
    unsigned short* qwh  = (unsigned short*)(ws + OFF_QWH);
    unsigned short* qwl  = (unsigned short*)(ws + OFF_QWL);
    unsigned short* kvwh = (unsigned short*)(ws + OFF_KVWH);
    unsigned short* kvwl = (unsigned short*)(ws + OFF_KVWL);
    unsigned short* pwh  = (unsigned short*)(ws + OFF_PWH);
    unsigned short* pwl  = (unsigned short*)(ws + OFF_PWL);
    unsigned short* Yh   = (unsigned short*)(ws + OFF_YH);
    unsigned short* Yl   = (unsigned short*)(ws + OFF_YL);
    float*  Ksum = ws + OFF_KSUM;
    float*  Mm   = ws + OFF_MT;
    float2* tab  = (float2*)(ws + OFF_TAB);

    // One prep dispatch: splits + weight transposes + rope table + zero Ksum/Mt
    prep_kernel<<<PREP_BLOCKS, 256, 0, stream>>>(
        x, memory, q_w, kv_w, proj_w,
        xh, xl, mh, ml, qwh, qwl, kvwh, kvwl, pwh, pwl,
        tab, Ksum /* zero_base: Ksum+Mt contiguous */);

    // KV GEMM (+elu/Ksum/rope + fused Mt accumulate). 256 blocks x 512 thr.
    gemm_kv<<<dim3(16, 16), 512, 0, stream>>>(mh, ml, kvwh, kvwl, kv_b, tab, Ksum, Mm);
    // Q GEMM (+elu/den/rope + fused Y = Qrot·Mt^T/den) -> Yh/Yl. 512 x 256.
    gemm_q<<<dim3(16, 32), 256, 0, stream>>>(xh, xl, qwh, qwl, q_b, tab, Ksum, Mm, Yh, Yl);
    // out = Y @ proj_w + proj_b. 512 x 256.
    gemm_out<<<dim3(16, 32), 256, 0, stream>>>(Yh, Yl, pwh, pwl, proj_b, (float*)d_out);
}

// Round 5
// 234.102 us; speedup vs baseline: 1.0374x; 1.0294x over previous
//
#include <hip/hip_runtime.h>
#include <cstddef>
#include <cstdint>

// Problem constants
#define B_SZ  2
#define T_SEQ 2048
#define S_SEQ 2048
#define C_EMB 1024
#define NH    16
#define HD    64
#define KDIM  1024   // inner dim of the three big GEMMs

typedef __attribute__((ext_vector_type(8))) short bf16x8;
typedef __attribute__((ext_vector_type(4))) float f32x4;

// ---------------------------------------------------------------------------
// Workspace layout (float units).
// ---------------------------------------------------------------------------
#define OFF_XH    ((size_t)0)           // [4096,1024] ushort
#define OFF_XL    ((size_t)2097152)
#define OFF_MEMH  ((size_t)4194304)     // [4096,1024] ushort
#define OFF_MEML  ((size_t)6291456)
#define OFF_QWH   ((size_t)8388608)     // [1024,1024] ushort (transposed [N,K])
#define OFF_QWL   ((size_t)8912896)
#define OFF_KVWH  ((size_t)9437184)     // [2048,1024] ushort
#define OFF_KVWL  ((size_t)10485760)
#define OFF_PWH   ((size_t)11534336)    // [1024,1024] ushort
#define OFF_PWL   ((size_t)12058624)
#define OFF_KSUM  ((size_t)12582912)    // [2,1024]      (zeroed by prep)
#define OFF_MT    ((size_t)12584960)    // [32,64,64]    (zeroed by prep)
#define OFF_TAB   ((size_t)12716032)    // [2048,32] float2
#define OFF_YH    ((size_t)12847104)    // [4096,1024] ushort
#define OFF_YL    ((size_t)14944256)
#define WS_FLOATS ((size_t)17041408)    // ~68.2 MB

__device__ __forceinline__ float elu1(float v) {
    return v > 0.0f ? v + 1.0f : __expf(v);
}
__device__ __forceinline__ unsigned short bf16_rne(float x) {
    union { float f; unsigned int u; } v; v.f = x;
    unsigned int u = v.u;
    return (unsigned short)((u + 0x7FFFu + ((u >> 16) & 1u)) >> 16);
}
__device__ __forceinline__ float bf16_to_f(unsigned short h) {
    union { unsigned int u; float f; } v; v.u = ((unsigned int)h) << 16;
    return v.f;
}

// ---------------------------------------------------------------------------
// Unified prep kernel (block-range dispatch), unchanged.
// ---------------------------------------------------------------------------
#define PREP_BLOCKS 13064

__device__ __forceinline__ void split4_body(
    const float4* __restrict__ in, ushort4* __restrict__ hi,
    ushort4* __restrict__ lo, int i)
{
    float4 v = in[i];
    ushort4 h, l;
    h.x = bf16_rne(v.x); l.x = bf16_rne(v.x - bf16_to_f(h.x));
    h.y = bf16_rne(v.y); l.y = bf16_rne(v.y - bf16_to_f(h.y));
    h.z = bf16_rne(v.z); l.z = bf16_rne(v.z - bf16_to_f(h.z));
    h.w = bf16_rne(v.w); l.w = bf16_rne(v.w - bf16_to_f(h.w));
    hi[i] = h; lo[i] = l;
}

__device__ __forceinline__ void transpose_body(
    const float* __restrict__ W, unsigned short* __restrict__ Wth,
    unsigned short* __restrict__ Wtl, int K, int N, int bx, int by,
    float (*tile)[33])
{
    const int k0 = by * 32, n0 = bx * 32;
    const int tx = threadIdx.x & 31, ty = threadIdx.x >> 5;
    #pragma unroll
    for (int j = 0; j < 4; ++j)
        tile[ty + j * 8][tx] = W[(size_t)(k0 + ty + j * 8) * N + n0 + tx];
    __syncthreads();
    #pragma unroll
    for (int j = 0; j < 4; ++j) {
        float x = tile[tx][ty + j * 8];
        unsigned short h = bf16_rne(x);
        unsigned short l = bf16_rne(x - bf16_to_f(h));
        size_t o = (size_t)(n0 + ty + j * 8) * K + k0 + tx;
        Wth[o] = h; Wtl[o] = l;
    }
}

__global__ __launch_bounds__(256) void prep_kernel(
    const float* __restrict__ x, const float* __restrict__ memory,
    const float* __restrict__ q_w, const float* __restrict__ kv_w,
    const float* __restrict__ proj_w,
    unsigned short* __restrict__ xh, unsigned short* __restrict__ xl,
    unsigned short* __restrict__ mh, unsigned short* __restrict__ ml,
    unsigned short* __restrict__ qwh, unsigned short* __restrict__ qwl,
    unsigned short* __restrict__ kvwh, unsigned short* __restrict__ kvwl,
    unsigned short* __restrict__ pwh, unsigned short* __restrict__ pwl,
    float2* __restrict__ tab, float* __restrict__ zero_base)
{
    __shared__ float tile[32][33];
    const int bid = blockIdx.x;
    const int tid = threadIdx.x;
    if (bid < 4096) {
        split4_body((const float4*)x, (ushort4*)xh, (ushort4*)xl, bid * 256 + tid);
    } else if (bid < 8192) {
        split4_body((const float4*)memory, (ushort4*)mh, (ushort4*)ml, (bid - 4096) * 256 + tid);
    } else if (bid < 9216) {
        int i = bid - 8192;
        transpose_body(q_w, qwh, qwl, 1024, 1024, i & 31, i >> 5, tile);
    } else if (bid < 11264) {
        int i = bid - 9216;
        transpose_body(kv_w, kvwh, kvwl, 1024, 2048, i & 63, i >> 6, tile);
    } else if (bid < 12288) {
        int i = bid - 11264;
        transpose_body(proj_w, pwh, pwl, 1024, 1024, i & 31, i >> 5, tile);
    } else if (bid < 12544) {
        int idx = (bid - 12288) * 256 + tid;    // pos*32 + i
        int pos = idx >> 5, i = idx & 31;
        double invf = exp(-(double)i * (9.210340371976184 / 32.0));  // 10000^(-i/32)
        float arg = (float)((double)pos * invf);
        float sn, cs;
        sincosf(arg, &sn, &cs);
        tab[idx] = make_float2(cs, sn);
    } else {
        int idx = (bid - 12544) * 256 + tid;
        if (idx < 2048 + 131072) zero_base[idx] = 0.0f;   // Ksum + Mt
    }
}

#define WAITCNT_VM(N)   asm volatile("s_waitcnt vmcnt(" #N ")" ::: "memory")
#define WAITCNT_LGKM(N) asm volatile("s_waitcnt lgkmcnt(" #N ")" ::: "memory")
#define CBAR()          asm volatile("" ::: "memory")

// ---------------------------------------------------------------------------
// Bijective XCD swizzle for 16x32 grids (id%8 assumed = XCD):
// XCD x owns by in {4x..4x+3}, all 16 bx.
// ---------------------------------------------------------------------------
__device__ __forceinline__ void xcd_swz32(int& bx, int& by) {
    int id = (int)(blockIdx.x + (blockIdx.y << 4));   // 0..511
    int x = id & 7, k = id >> 3;                      // k 0..63
    bx = k >> 2;                                      // 0..15
    by = x * 4 + (k & 3);                             // 0..31
}

// ---------------------------------------------------------------------------
// KV GEMM: 128(M)x128(N) head-paired tile, 512 threads (8 waves, wr4 x wc2,
// per-wave 32x64, acc[2][4]). Single fragment set, 1 barrier/tile,
// distance-1 staging (4 global_load_lds per wave), counted lgkm split,
// product-major MFMA. 2-deep ring = 64 KB; epilogue transposed K/V
// [64][136] x4 = 68 KB -> LDS 69632 B -> 2 blocks/CU (4 waves/SIMD TLP).
// Epilogue: bias, elu+Ksum+RoPE (K), transposed LDS, Mt = V^T K accumulate
// (t split across wave halves). grid (16 heads, 32 mtiles).
// Buffer layout (ushorts): A_hi[128][32] @0, A_lo @4096, B_hi[128][32]
// @8192 (rows 0-63 K, 64-127 V), B_lo @12288. BUFSZ = 16384 ush.
// ---------------------------------------------------------------------------
__global__ __launch_bounds__(512, 4) void gemm_kv(
    const unsigned short* __restrict__ Ah, const unsigned short* __restrict__ Al,
    const unsigned short* __restrict__ Bth, const unsigned short* __restrict__ Btl,
    const float* __restrict__ bias, const float2* __restrict__ tab,
    float* __restrict__ Ksum, float* __restrict__ Mt)
{
    __shared__ alignas(16) unsigned short smem[34816];   // 68 KiB
    const int tid = threadIdx.x;
    const int w = tid >> 6, lane = tid & 63;
    const int wr = w >> 1, wc = w & 1;
    const int quad = lane >> 4, lrow = lane & 15;
    int h, mt;
    xcd_swz32(h, mt);
    const int m0 = mt * 128;
    const int n0 = h * 64;
    const int b  = m0 >> 11;
    const int tbase = (m0 & 2047) + wr * 32;
    const int bh_idx = b * NH + h;

    // staging: wave w stages rows [w*16, w*16+16) of A_hi/A_lo/B_hi/B_lo
    const int sr = lane >> 2;                        // 0..15
    const int g  = (lane & 3) ^ ((lane >> 3) & 3);   // pre-swizzled granule
    const int arow = w * 16 + sr;                    // 0..127
    const unsigned short* gAh = Ah + (size_t)(m0 + arow) * KDIM + g * 8;
    const unsigned short* gAl = Al + (size_t)(m0 + arow) * KDIM + g * 8;
    const size_t brow = (size_t)(n0 + arow) + ((w >= 4) ? (size_t)960 : 0);
    const unsigned short* gBh = Bth + brow * KDIM + g * 8;
    const unsigned short* gBl = Btl + brow * KDIM + g * 8;
    const int lAh = w * 512;
    const int lAl = 4096 + w * 512;
    const int lBh = 8192 + w * 512;
    const int lBl = 12288 + w * 512;

    auto STAGE = [&](unsigned short* buf, int k0) {
        __builtin_amdgcn_global_load_lds(
            (const __attribute__((address_space(1))) unsigned int*)(gAh + k0),
            (__attribute__((address_space(3))) unsigned int*)(buf + lAh), 16, 0, 0);
        __builtin_amdgcn_global_load_lds(
            (const __attribute__((address_space(1))) unsigned int*)(gAl + k0),
            (__attribute__((address_space(3))) unsigned int*)(buf + lAl), 16, 0, 0);
        __builtin_amdgcn_global_load_lds(
            (const __attribute__((address_space(1))) unsigned int*)(gBh + k0),
            (__attribute__((address_space(3))) unsigned int*)(buf + lBh), 16, 0, 0);
        __builtin_amdgcn_global_load_lds(
            (const __attribute__((address_space(1))) unsigned int*)(gBl + k0),
            (__attribute__((address_space(3))) unsigned int*)(buf + lBl), 16, 0, 0);
    };

    const int rowbase = wr * 32, colbase = wc * 64;
    const int sw = ((quad ^ ((lrow >> 1) & 3)) << 3);  // swizzled read granule

    f32x4 acc[2][4] = {};

    STAGE(smem, 0);

    #pragma unroll 1
    for (int t = 0; t < 32; ++t) {
        unsigned short* cur = smem + (t & 1) * 16384;
        unsigned short* nxt = smem + ((t + 1) & 1) * 16384;
        WAITCNT_VM(0);                    // own STAGE(t) complete
        __builtin_amdgcn_sched_barrier(0);
        __builtin_amdgcn_s_barrier();     // all waves: t resident; t-1 reads done
        __builtin_amdgcn_sched_barrier(0);

        bf16x8 ah[2], al[2], bh[4], bl[4];
        #pragma unroll
        for (int it = 0; it < 2; ++it) {
            int off = (rowbase + it * 16 + lrow) * 32 + sw;
            ah[it] = *(const bf16x8*)&cur[off];
            al[it] = *(const bf16x8*)&cur[4096 + off];
        }
        #pragma unroll
        for (int jt = 0; jt < 2; ++jt) {
            int boff = (colbase + jt * 16 + lrow) * 32 + sw;
            bh[jt] = *(const bf16x8*)&cur[8192 + boff];
            bl[jt] = *(const bf16x8*)&cur[12288 + boff];
        }
        CBAR();   // pin group order: lgkm(4) counts exactly the 4 reads below
        #pragma unroll
        for (int jt = 2; jt < 4; ++jt) {
            int boff = (colbase + jt * 16 + lrow) * 32 + sw;
            bh[jt] = *(const bf16x8*)&cur[8192 + boff];
            bl[jt] = *(const bf16x8*)&cur[12288 + boff];
        }
        if (t + 1 < 32) STAGE(nxt, (t + 1) * 32);

        WAITCNT_LGKM(4);                  // group 1 (A + B jt01) resident
        __builtin_amdgcn_sched_barrier(0);
        __builtin_amdgcn_s_setprio(1);
        #pragma unroll
        for (int it = 0; it < 2; ++it)
            #pragma unroll
            for (int jt = 0; jt < 2; ++jt)
                acc[it][jt] = __builtin_amdgcn_mfma_f32_16x16x32_bf16(ah[it], bh[jt], acc[it][jt], 0, 0, 0);
        #pragma unroll
        for (int it = 0; it < 2; ++it)
            #pragma unroll
            for (int jt = 0; jt < 2; ++jt)
                acc[it][jt] = __builtin_amdgcn_mfma_f32_16x16x32_bf16(ah[it], bl[jt], acc[it][jt], 0, 0, 0);
        #pragma unroll
        for (int it = 0; it < 2; ++it)
            #pragma unroll
            for (int jt = 0; jt < 2; ++jt)
                acc[it][jt] = __builtin_amdgcn_mfma_f32_16x16x32_bf16(al[it], bh[jt], acc[it][jt], 0, 0, 0);

        WAITCNT_LGKM(0);                  // group 2 (B jt23) resident
        __builtin_amdgcn_sched_barrier(0);
        #pragma unroll
        for (int it = 0; it < 2; ++it)
            #pragma unroll
            for (int jt = 2; jt < 4; ++jt)
                acc[it][jt] = __builtin_amdgcn_mfma_f32_16x16x32_bf16(ah[it], bh[jt], acc[it][jt], 0, 0, 0);
        #pragma unroll
        for (int it = 0; it < 2; ++it)
            #pragma unroll
            for (int jt = 2; jt < 4; ++jt)
                acc[it][jt] = __builtin_amdgcn_mfma_f32_16x16x32_bf16(ah[it], bl[jt], acc[it][jt], 0, 0, 0);
        #pragma unroll
        for (int it = 0; it < 2; ++it)
            #pragma unroll
            for (int jt = 2; jt < 4; ++jt)
                acc[it][jt] = __builtin_amdgcn_mfma_f32_16x16x32_bf16(al[it], bh[jt], acc[it][jt], 0, 0, 0);
        __builtin_amdgcn_s_setprio(0);
    }
    __syncthreads();   // drain before LDS reuse by epilogue

    // ---------------- epilogue (round-0 geometry, 8-wave decomposition) ----
    const bool isK = (wc == 0);
    const int colg = (isK ? 0 : C_EMB) + h * 64;
    float bb[4];
    #pragma unroll
    for (int jt = 0; jt < 4; ++jt) bb[jt] = bias[colg + jt * 16 + lrow];
    #pragma unroll
    for (int it = 0; it < 2; ++it)
        #pragma unroll
        for (int jt = 0; jt < 4; ++jt)
            #pragma unroll
            for (int r = 0; r < 4; ++r) {
                float v = acc[it][jt][r] + bb[jt];
                acc[it][jt][r] = isK ? elu1(v) : v;
            }

    if (isK) {
        #pragma unroll
        for (int jt = 0; jt < 4; ++jt) {
            float p = 0.0f;
            #pragma unroll
            for (int it = 0; it < 2; ++it)
                #pragma unroll
                for (int r = 0; r < 4; ++r) p += acc[it][jt][r];
            p += __shfl_xor(p, 16);
            p += __shfl_xor(p, 32);
            if (quad == 0)
                atomicAdd(&Ksum[b * C_EMB + h * 64 + jt * 16 + lrow], p);
        }
        #pragma unroll
        for (int it = 0; it < 2; ++it)
            #pragma unroll
            for (int r = 0; r < 4; ++r) {
                int s = tbase + it * 16 + quad * 4 + r;
                float2 c0 = tab[s * 32 + lrow];
                float2 c1 = tab[s * 32 + 16 + lrow];
                float a0 = acc[it][0][r], a1 = acc[it][1][r];
                float a2 = acc[it][2][r], a3 = acc[it][3][r];
                acc[it][0][r] = a0 * c0.x - a2 * c0.y;
                acc[it][2][r] = a2 * c0.x + a0 * c0.y;
                acc[it][1][r] = a1 * c1.x - a3 * c1.y;
                acc[it][3][r] = a3 * c1.x + a1 * c1.y;
            }
    }

    // transposed LDS: K_hi[64][136] @0, K_lo @8704, V_hi @17408, V_lo @26112
    unsigned short* Hd = smem + (isK ? 0 : 17408);
    unsigned short* Ld = Hd + 8704;
    #pragma unroll
    for (int jt = 0; jt < 4; ++jt) {
        int d = jt * 16 + lrow;
        #pragma unroll
        for (int it = 0; it < 2; ++it) {
            int t0loc = wr * 32 + it * 16 + quad * 4;
            ushort4 h4, l4;
            float v0 = acc[it][jt][0], v1 = acc[it][jt][1];
            float v2 = acc[it][jt][2], v3 = acc[it][jt][3];
            h4.x = bf16_rne(v0); l4.x = bf16_rne(v0 - bf16_to_f(h4.x));
            h4.y = bf16_rne(v1); l4.y = bf16_rne(v1 - bf16_to_f(h4.y));
            h4.z = bf16_rne(v2); l4.z = bf16_rne(v2 - bf16_to_f(h4.z));
            h4.w = bf16_rne(v3); l4.w = bf16_rne(v3 - bf16_to_f(h4.w));
            *(ushort4*)&Hd[d * 136 + t0loc] = h4;
            *(ushort4*)&Ld[d * 136 + t0loc] = l4;
        }
    }
    __syncthreads();

    {
        const unsigned short* KH = smem;
        const unsigned short* KL = smem + 8704;
        const unsigned short* VH = smem + 17408;
        const unsigned short* VL = smem + 26112;
        const int mrow = (w & 3) * 16 + lrow;   // V feature row (dv)
        const int thalf = w >> 2;               // t-half 0/1 (64 each)
        f32x4 macc[4] = {};
        #pragma unroll
        for (int ks = 0; ks < 2; ++ks) {
            int kof = thalf * 64 + ks * 32 + quad * 8;
            bf16x8 vah = *(const bf16x8*)&VH[mrow * 136 + kof];
            bf16x8 val = *(const bf16x8*)&VL[mrow * 136 + kof];
            #pragma unroll
            for (int jt = 0; jt < 4; ++jt) {
                int nrow = jt * 16 + lrow;      // K feature row (dk)
                bf16x8 kbh = *(const bf16x8*)&KH[nrow * 136 + kof];
                bf16x8 kbl = *(const bf16x8*)&KL[nrow * 136 + kof];
                macc[jt] = __builtin_amdgcn_mfma_f32_16x16x32_bf16(vah, kbh, macc[jt], 0, 0, 0);
                macc[jt] = __builtin_amdgcn_mfma_f32_16x16x32_bf16(vah, kbl, macc[jt], 0, 0, 0);
                macc[jt] = __builtin_amdgcn_mfma_f32_16x16x32_bf16(val, kbh, macc[jt], 0, 0, 0);
            }
        }
        #pragma unroll
        for (int jt = 0; jt < 4; ++jt)
            #pragma unroll
            for (int r = 0; r < 4; ++r)
                atomicAdd(&Mt[((size_t)bh_idx * 64 + (w & 3) * 16 + quad * 4 + r) * 64 + jt * 16 + lrow],
                          macc[jt][r]);
    }
}

// ---------------------------------------------------------------------------
// 128(M)x64(N) main loop for Q / out. 256 threads (4 waves, per-wave 32x64).
// 2-buffer LDS ring (48 KiB total -> 3 blocks/CU), distance-1 staging,
// 1 barrier/tile, counted lgkm split, product-major MFMA. (round-3 version)
// ---------------------------------------------------------------------------
__device__ __forceinline__ void gemm_main_128(
    const unsigned short* __restrict__ Ah, const unsigned short* __restrict__ Al,
    const unsigned short* __restrict__ Bth, const unsigned short* __restrict__ Btl,
    unsigned short* lds, int m0, int n0, f32x4 (&acc)[2][4])
{
    const int tid = threadIdx.x;
    const int w = tid >> 6, lane = tid & 63;
    const int quad = lane >> 4, lrow = lane & 15;
    const int srow = lane >> 2;                       // 0..15
    const int g  = (lane & 3) ^ ((lane >> 3) & 3);    // pre-swizzled granule
    const int sw = ((quad ^ ((lrow >> 1) & 3)) << 3); // swizzled read granule

    const unsigned short* gA0 = Ah + (size_t)(m0 + w * 16 + srow) * KDIM + g * 8;
    const unsigned short* gA1 = Ah + (size_t)(m0 + 64 + w * 16 + srow) * KDIM + g * 8;
    const unsigned short* gA2 = Al + (size_t)(m0 + w * 16 + srow) * KDIM + g * 8;
    const unsigned short* gA3 = Al + (size_t)(m0 + 64 + w * 16 + srow) * KDIM + g * 8;
    const unsigned short* gB0 = Bth + (size_t)(n0 + w * 16 + srow) * KDIM + g * 8;
    const unsigned short* gB1 = Btl + (size_t)(n0 + w * 16 + srow) * KDIM + g * 8;
    const int lA0 = w * 512, lA1 = 2048 + w * 512;
    const int lA2 = 4096 + w * 512, lA3 = 6144 + w * 512;
    const int lB0 = 8192 + w * 512, lB1 = 10240 + w * 512;

    auto STAGE = [&](unsigned short* buf, int k0) {
        __builtin_amdgcn_global_load_lds(
            (const __attribute__((address_space(1))) unsigned int*)(gA0 + k0),
            (__attribute__((address_space(3))) unsigned int*)(buf + lA0), 16, 0, 0);
        __builtin_amdgcn_global_load_lds(
            (const __attribute__((address_space(1))) unsigned int*)(gA1 + k0),
            (__attribute__((address_space(3))) unsigned int*)(buf + lA1), 16, 0, 0);
        __builtin_amdgcn_global_load_lds(
            (const __attribute__((address_space(1))) unsigned int*)(gA2 + k0),
            (__attribute__((address_space(3))) unsigned int*)(buf + lA2), 16, 0, 0);
        __builtin_amdgcn_global_load_lds(
            (const __attribute__((address_space(1))) unsigned int*)(gA3 + k0),
            (__attribute__((address_space(3))) unsigned int*)(buf + lA3), 16, 0, 0);
        __builtin_amdgcn_global_load_lds(
            (const __attribute__((address_space(1))) unsigned int*)(gB0 + k0),
            (__attribute__((address_space(3))) unsigned int*)(buf + lB0), 16, 0, 0);
        __builtin_amdgcn_global_load_lds(
            (const __attribute__((address_space(1))) unsigned int*)(gB1 + k0),
            (__attribute__((address_space(3))) unsigned int*)(buf + lB1), 16, 0, 0);
    };

    STAGE(lds, 0);

    #pragma unroll 1
    for (int t = 0; t < 32; ++t) {
        unsigned short* cur = lds + (t & 1) * 12288;
        unsigned short* nxt = lds + ((t + 1) & 1) * 12288;
        WAITCNT_VM(0);                    // own STAGE(t) complete
        __builtin_amdgcn_sched_barrier(0);
        __builtin_amdgcn_s_barrier();     // all waves: t resident; t-1 reads done
        __builtin_amdgcn_sched_barrier(0);

        bf16x8 ah[2], al[2], bh[4], bl[4];
        #pragma unroll
        for (int it = 0; it < 2; ++it) {
            int off = (w * 32 + it * 16 + lrow) * 32 + sw;
            ah[it] = *(const bf16x8*)&cur[off];
            al[it] = *(const bf16x8*)&cur[4096 + off];
        }
        #pragma unroll
        for (int jt = 0; jt < 2; ++jt) {
            int boff = (jt * 16 + lrow) * 32 + sw;
            bh[jt] = *(const bf16x8*)&cur[8192 + boff];
            bl[jt] = *(const bf16x8*)&cur[10240 + boff];
        }
        CBAR();   // pin group order: lgkm(4) counts exactly the 4 reads below
        #pragma unroll
        for (int jt = 2; jt < 4; ++jt) {
            int boff = (jt * 16 + lrow) * 32 + sw;
            bh[jt] = *(const bf16x8*)&cur[8192 + boff];
            bl[jt] = *(const bf16x8*)&cur[10240 + boff];
        }
        if (t + 1 < 32) STAGE(nxt, (t + 1) * 32);

        WAITCNT_LGKM(4);                  // group 1 (A + B jt01) resident
        __builtin_amdgcn_sched_barrier(0);
        __builtin_amdgcn_s_setprio(1);
        #pragma unroll
        for (int it = 0; it < 2; ++it)
            #pragma unroll
            for (int jt = 0; jt < 2; ++jt)
                acc[it][jt] = __builtin_amdgcn_mfma_f32_16x16x32_bf16(ah[it], bh[jt], acc[it][jt], 0, 0, 0);
        #pragma unroll
        for (int it = 0; it < 2; ++it)
            #pragma unroll
            for (int jt = 0; jt < 2; ++jt)
                acc[it][jt] = __builtin_amdgcn_mfma_f32_16x16x32_bf16(ah[it], bl[jt], acc[it][jt], 0, 0, 0);
        #pragma unroll
        for (int it = 0; it < 2; ++it)
            #pragma unroll
            for (int jt = 0; jt < 2; ++jt)
                acc[it][jt] = __builtin_amdgcn_mfma_f32_16x16x32_bf16(al[it], bh[jt], acc[it][jt], 0, 0, 0);

        WAITCNT_LGKM(0);                  // group 2 (B jt23) resident
        __builtin_amdgcn_sched_barrier(0);
        #pragma unroll
        for (int it = 0; it < 2; ++it)
            #pragma unroll
            for (int jt = 2; jt < 4; ++jt)
                acc[it][jt] = __builtin_amdgcn_mfma_f32_16x16x32_bf16(ah[it], bh[jt], acc[it][jt], 0, 0, 0);
        #pragma unroll
        for (int it = 0; it < 2; ++it)
            #pragma unroll
            for (int jt = 2; jt < 4; ++jt)
                acc[it][jt] = __builtin_amdgcn_mfma_f32_16x16x32_bf16(ah[it], bl[jt], acc[it][jt], 0, 0, 0);
        #pragma unroll
        for (int it = 0; it < 2; ++it)
            #pragma unroll
            for (int jt = 2; jt < 4; ++jt)
                acc[it][jt] = __builtin_amdgcn_mfma_f32_16x16x32_bf16(al[it], bh[jt], acc[it][jt], 0, 0, 0);
        __builtin_amdgcn_s_setprio(0);
    }
    __syncthreads();   // drain before LDS reuse by epilogues
}

// ---------------------------------------------------------------------------
// Q GEMM, 128x64 tile (one head per block), grid (16,32) x 256 thr.
// Epilogue: bias, elu+1, den in regs, RoPE, per-wave Qrot LDS,
// Y = (Qrot @ Mt^T)/den, bf16 hi/lo stores.
// ---------------------------------------------------------------------------
__global__ __launch_bounds__(256, 3) void gemm_q(
    const unsigned short* __restrict__ Ah, const unsigned short* __restrict__ Al,
    const unsigned short* __restrict__ Bth, const unsigned short* __restrict__ Btl,
    const float* __restrict__ bias, const float2* __restrict__ tab,
    const float* __restrict__ Ksum, const float* __restrict__ Mt,
    unsigned short* __restrict__ Yh, unsigned short* __restrict__ Yl)
{
    // main loop uses [0,24576); epilogue reuses [0,18432) as per-wave Qrot
    __shared__ alignas(16) unsigned short smem[24576];   // 48 KiB
    int h, mt;
    xcd_swz32(h, mt);
    const int m0 = mt * 128;
    f32x4 acc[2][4] = {};
    gemm_main_128(Ah, Al, Bth, Btl, smem, m0, h * 64, acc);

    const int tid = threadIdx.x;
    const int w = tid >> 6, lane = tid & 63;
    const int quad = lane >> 4, lrow = lane & 15;
    const int b = m0 >> 11;
    const int tbase = (m0 & 2047) + w * 32;
    const int bh = b * NH + h;

    float bb[4];
    #pragma unroll
    for (int jt = 0; jt < 4; ++jt) bb[jt] = bias[h * 64 + jt * 16 + lrow];
    #pragma unroll
    for (int it = 0; it < 2; ++it)
        #pragma unroll
        for (int jt = 0; jt < 4; ++jt)
            #pragma unroll
            for (int r = 0; r < 4; ++r)
                acc[it][jt][r] = elu1(acc[it][jt][r] + bb[jt]);

    // den (pre-rope), kept in registers
    float ks[4], den_reg[2][4];
    #pragma unroll
    for (int jt = 0; jt < 4; ++jt) ks[jt] = Ksum[b * C_EMB + h * 64 + jt * 16 + lrow];
    #pragma unroll
    for (int it = 0; it < 2; ++it)
        #pragma unroll
        for (int r = 0; r < 4; ++r) {
            float p = acc[it][0][r] * ks[0] + acc[it][1][r] * ks[1]
                    + acc[it][2][r] * ks[2] + acc[it][3][r] * ks[3];
            p += __shfl_xor(p, 1);
            p += __shfl_xor(p, 2);
            p += __shfl_xor(p, 4);
            p += __shfl_xor(p, 8);
            den_reg[it][r] = p;
        }

    // RoPE in registers (pairs jt, jt^2)
    #pragma unroll
    for (int it = 0; it < 2; ++it)
        #pragma unroll
        for (int r = 0; r < 4; ++r) {
            int s = tbase + it * 16 + quad * 4 + r;
            float2 c0 = tab[s * 32 + lrow];
            float2 c1 = tab[s * 32 + 16 + lrow];
            float a0 = acc[it][0][r], a1 = acc[it][1][r];
            float a2 = acc[it][2][r], a3 = acc[it][3][r];
            acc[it][0][r] = a0 * c0.x - a2 * c0.y;
            acc[it][2][r] = a2 * c0.x + a0 * c0.y;
            acc[it][1][r] = a1 * c1.x - a3 * c1.y;
            acc[it][3][r] = a3 * c1.x + a1 * c1.y;
        }

    // Qrot -> per-wave LDS ([32 rows][72], hi then lo). Wave-private region;
    // main loop's final __syncthreads drained cross-wave LDS reads.
    unsigned short* QH = smem + w * 4608;
    unsigned short* QL = QH + 2304;
    #pragma unroll
    for (int it = 0; it < 2; ++it)
        #pragma unroll
        for (int jt = 0; jt < 4; ++jt)
            #pragma unroll
            for (int r = 0; r < 4; ++r) {
                int tloc = it * 16 + quad * 4 + r;
                int d = jt * 16 + lrow;
                float v = acc[it][jt][r];
                unsigned short hh = bf16_rne(v);
                QH[tloc * 72 + d] = hh;
                QL[tloc * 72 + d] = bf16_rne(v - bf16_to_f(hh));
            }

    // Y = (Qrot @ Mt^T) / den
    f32x4 acc2[2][4] = {};
    #pragma unroll
    for (int kc = 0; kc < 2; ++kc) {
        bf16x8 mbh[4], mbl[4];
        #pragma unroll
        for (int jt2 = 0; jt2 < 4; ++jt2) {
            const float* mp = &Mt[((size_t)bh * 64 + jt2 * 16 + lrow) * 64 + kc * 32 + quad * 8];
            #pragma unroll
            for (int e = 0; e < 8; ++e) {
                float x = mp[e];
                unsigned short hh = bf16_rne(x);
                mbh[jt2][e] = (short)hh;
                mbl[jt2][e] = (short)bf16_rne(x - bf16_to_f(hh));
            }
        }
        #pragma unroll
        for (int it2 = 0; it2 < 2; ++it2) {
            int ro = (it2 * 16 + lrow) * 72 + kc * 32 + quad * 8;
            bf16x8 qh = *(const bf16x8*)&QH[ro];
            bf16x8 ql = *(const bf16x8*)&QL[ro];
            #pragma unroll
            for (int jt2 = 0; jt2 < 4; ++jt2) {
                acc2[it2][jt2] = __builtin_amdgcn_mfma_f32_16x16x32_bf16(qh, mbh[jt2], acc2[it2][jt2], 0, 0, 0);
                acc2[it2][jt2] = __builtin_amdgcn_mfma_f32_16x16x32_bf16(qh, mbl[jt2], acc2[it2][jt2], 0, 0, 0);
                acc2[it2][jt2] = __builtin_amdgcn_mfma_f32_16x16x32_bf16(ql, mbh[jt2], acc2[it2][jt2], 0, 0, 0);
            }
        }
    }

    // divide + bf16 hi/lo store
    #pragma unroll
    for (int it2 = 0; it2 < 2; ++it2)
        #pragma unroll
        for (int jt2 = 0; jt2 < 4; ++jt2)
            #pragma unroll
            for (int r = 0; r < 4; ++r) {
                float v = acc2[it2][jt2][r] / den_reg[it2][r];
                size_t o = ((size_t)(m0 + w * 32 + it2 * 16 + quad * 4 + r)) * C_EMB
                         + h * 64 + jt2 * 16 + lrow;
                unsigned short hh = bf16_rne(v);
                Yh[o] = hh;
                Yl[o] = bf16_rne(v - bf16_to_f(hh));
            }
}

// ---------------------------------------------------------------------------
// Output projection GEMM, 128x64 tile: out = Y @ proj_w + proj_b.
// grid (16 n-tiles, 32 m-tiles) x 256 thr.
// ---------------------------------------------------------------------------
__global__ __launch_bounds__(256, 3) void gemm_out(
    const unsigned short* __restrict__ Ah, const unsigned short* __restrict__ Al,
    const unsigned short* __restrict__ Bth, const unsigned short* __restrict__ Btl,
    const float* __restrict__ bias, float* __restrict__ out)
{
    __shared__ alignas(16) unsigned short smem[24576];
    int nt, mt;
    xcd_swz32(nt, mt);
    const int m0 = mt * 128, n0 = nt * 64;
    f32x4 acc[2][4] = {};
    gemm_main_128(Ah, Al, Bth, Btl, smem, m0, n0, acc);

    const int tid = threadIdx.x;
    const int w = tid >> 6, lane = tid & 63;
    const int quad = lane >> 4, lrow = lane & 15;

    #pragma unroll
    for (int jt = 0; jt < 4; ++jt) {
        int gc = n0 + jt * 16 + lrow;
        float bb = bias[gc];
        #pragma unroll
        for (int it = 0; it < 2; ++it) {
            int grb = m0 + w * 32 + it * 16 + quad * 4;
            #pragma unroll
            for (int r = 0; r < 4; ++r)
                out[(size_t)(grb + r) * C_EMB + gc] = acc[it][jt][r] + bb;
        }
    }
}

// ---------------------------------------------------------------------------
extern "C" void kernel_launch(void* const* d_in, const int* in_sizes, int n_in,
                              void* d_out, int out_size, void* d_ws, size_t ws_size,
                              hipStream_t stream)
{
    const float* x      = (const float*)d_in[0];
    const float* memory = (const float*)d_in[1];
    const float* q_w    = (const float*)d_in[2];
    const float* q_b    = (const float*)d_in[3];
    const float* kv_w   = (const float*)d_in[4];
    const float* kv_b   = (const float*)d_in[5];
    const float* proj_w = (const float*)d_in[6];
    const float* proj_b = (const float*)d_in[7];

    if (ws_size < WS_FLOATS * sizeof(float)) return;

    float* ws = (float*)d_ws;
    unsigned short* xh   = (unsigned short*)(ws + OFF_XH);
    unsigned short* xl   = (unsigned short*)(ws + OFF_XL);
    unsigned short* mh   = (unsigned short*)(ws + OFF_MEMH);
    unsigned short* ml   = (unsigned short*)(ws + OFF_MEML);
    unsigned short* qwh  = (unsigned short*)(ws + OFF_QWH);
    unsigned short* qwl  = (unsigned short*)(ws + OFF_QWL);
    unsigned short* kvwh = (unsigned short*)(ws + OFF_KVWH);
    unsigned short* kvwl = (unsigned short*)(ws + OFF_KVWL);
    unsigned short* pwh  = (unsigned short*)(ws + OFF_PWH);
    unsigned short* pwl  = (unsigned short*)(ws + OFF_PWL);
    unsigned short* Yh   = (unsigned short*)(ws + OFF_YH);
    unsigned short* Yl   = (unsigned short*)(ws + OFF_YL);
    float*  Ksum = ws + OFF_KSUM;
    float*  Mm   = ws + OFF_MT;
    float2* tab  = (float2*)(ws + OFF_TAB);

    // One prep dispatch: splits + weight transposes + rope table + zero Ksum/Mt
    prep_kernel<<<PREP_BLOCKS, 256, 0, stream>>>(
        x, memory, q_w, kv_w, proj_w,
        xh, xl, mh, ml, qwh, qwl, kvwh, kvwl, pwh, pwl,
        tab, Ksum /* zero_base: Ksum+Mt contiguous */);

    // KV GEMM (+elu/Ksum/rope + fused Mt accumulate). 512 blocks x 512 thr.
    gemm_kv<<<dim3(16, 32), 512, 0, stream>>>(mh, ml, kvwh, kvwl, kv_b, tab, Ksum, Mm);
    // Q GEMM (+elu/den/rope + fused Y = Qrot·Mt^T/den) -> Yh/Yl. 512 x 256.
    gemm_q<<<dim3(16, 32), 256, 0, stream>>>(xh, xl, qwh, qwl, q_b, tab, Ksum, Mm, Yh, Yl);
    // out = Y @ proj_w + proj_b. 512 x 256.
    gemm_out<<<dim3(16, 32), 256, 0, stream>>>(Yh, Yl, pwh, pwl, proj_b, (float*)d_out);
}

// Round 6
// 226.162 us; speedup vs baseline: 1.0738x; 1.0351x over previous
//
#include <hip/hip_runtime.h>
#include <cstddef>
#include <cstdint>

// Problem constants
#define B_SZ  2
#define T_SEQ 2048
#define S_SEQ 2048
#define C_EMB 1024
#define NH    16
#define HD    64
#define KDIM  1024   // inner dim of the three big GEMMs

typedef __attribute__((ext_vector_type(8))) short bf16x8;
typedef __attribute__((ext_vector_type(4))) float f32x4;

// ---------------------------------------------------------------------------
// Workspace layout (float units).
// ---------------------------------------------------------------------------
#define OFF_XH    ((size_t)0)           // [4096,1024] ushort
#define OFF_XL    ((size_t)2097152)
#define OFF_MEMH  ((size_t)4194304)     // [4096,1024] ushort
#define OFF_MEML  ((size_t)6291456)
#define OFF_QWH   ((size_t)8388608)     // [1024,1024] ushort (transposed [N,K])
#define OFF_QWL   ((size_t)8912896)
#define OFF_KVWH  ((size_t)9437184)     // [2048,1024] ushort
#define OFF_KVWL  ((size_t)10485760)
#define OFF_PWH   ((size_t)11534336)    // [1024,1024] ushort
#define OFF_PWL   ((size_t)12058624)
#define OFF_KSUM  ((size_t)12582912)    // [2,1024]      (zeroed by prep)
#define OFF_MT    ((size_t)12584960)    // [32,64,64]    (zeroed by prep)
#define OFF_TAB   ((size_t)12716032)    // [2048,32] float2
#define OFF_YH    ((size_t)12847104)    // [4096,1024] ushort
#define OFF_YL    ((size_t)14944256)
#define WS_FLOATS ((size_t)17041408)    // ~68.2 MB

__device__ __forceinline__ float elu1(float v) {
    return v > 0.0f ? v + 1.0f : __expf(v);
}
__device__ __forceinline__ unsigned short bf16_rne(float x) {
    union { float f; unsigned int u; } v; v.f = x;
    unsigned int u = v.u;
    return (unsigned short)((u + 0x7FFFu + ((u >> 16) & 1u)) >> 16);
}
__device__ __forceinline__ float bf16_to_f(unsigned short h) {
    union { unsigned int u; float f; } v; v.u = ((unsigned int)h) << 16;
    return v.f;
}

// ---------------------------------------------------------------------------
// Unified prep kernel (block-range dispatch), unchanged.
// ---------------------------------------------------------------------------
#define PREP_BLOCKS 13064

__device__ __forceinline__ void split4_body(
    const float4* __restrict__ in, ushort4* __restrict__ hi,
    ushort4* __restrict__ lo, int i)
{
    float4 v = in[i];
    ushort4 h, l;
    h.x = bf16_rne(v.x); l.x = bf16_rne(v.x - bf16_to_f(h.x));
    h.y = bf16_rne(v.y); l.y = bf16_rne(v.y - bf16_to_f(h.y));
    h.z = bf16_rne(v.z); l.z = bf16_rne(v.z - bf16_to_f(h.z));
    h.w = bf16_rne(v.w); l.w = bf16_rne(v.w - bf16_to_f(h.w));
    hi[i] = h; lo[i] = l;
}

__device__ __forceinline__ void transpose_body(
    const float* __restrict__ W, unsigned short* __restrict__ Wth,
    unsigned short* __restrict__ Wtl, int K, int N, int bx, int by,
    float (*tile)[33])
{
    const int k0 = by * 32, n0 = bx * 32;
    const int tx = threadIdx.x & 31, ty = threadIdx.x >> 5;
    #pragma unroll
    for (int j = 0; j < 4; ++j)
        tile[ty + j * 8][tx] = W[(size_t)(k0 + ty + j * 8) * N + n0 + tx];
    __syncthreads();
    #pragma unroll
    for (int j = 0; j < 4; ++j) {
        float x = tile[tx][ty + j * 8];
        unsigned short h = bf16_rne(x);
        unsigned short l = bf16_rne(x - bf16_to_f(h));
        size_t o = (size_t)(n0 + ty + j * 8) * K + k0 + tx;
        Wth[o] = h; Wtl[o] = l;
    }
}

__global__ __launch_bounds__(256) void prep_kernel(
    const float* __restrict__ x, const float* __restrict__ memory,
    const float* __restrict__ q_w, const float* __restrict__ kv_w,
    const float* __restrict__ proj_w,
    unsigned short* __restrict__ xh, unsigned short* __restrict__ xl,
    unsigned short* __restrict__ mh, unsigned short* __restrict__ ml,
    unsigned short* __restrict__ qwh, unsigned short* __restrict__ qwl,
    unsigned short* __restrict__ kvwh, unsigned short* __restrict__ kvwl,
    unsigned short* __restrict__ pwh, unsigned short* __restrict__ pwl,
    float2* __restrict__ tab, float* __restrict__ zero_base)
{
    __shared__ float tile[32][33];
    const int bid = blockIdx.x;
    const int tid = threadIdx.x;
    if (bid < 4096) {
        split4_body((const float4*)x, (ushort4*)xh, (ushort4*)xl, bid * 256 + tid);
    } else if (bid < 8192) {
        split4_body((const float4*)memory, (ushort4*)mh, (ushort4*)ml, (bid - 4096) * 256 + tid);
    } else if (bid < 9216) {
        int i = bid - 8192;
        transpose_body(q_w, qwh, qwl, 1024, 1024, i & 31, i >> 5, tile);
    } else if (bid < 11264) {
        int i = bid - 9216;
        transpose_body(kv_w, kvwh, kvwl, 1024, 2048, i & 63, i >> 6, tile);
    } else if (bid < 12288) {
        int i = bid - 11264;
        transpose_body(proj_w, pwh, pwl, 1024, 1024, i & 31, i >> 5, tile);
    } else if (bid < 12544) {
        int idx = (bid - 12288) * 256 + tid;    // pos*32 + i
        int pos = idx >> 5, i = idx & 31;
        double invf = exp(-(double)i * (9.210340371976184 / 32.0));  // 10000^(-i/32)
        float arg = (float)((double)pos * invf);
        float sn, cs;
        sincosf(arg, &sn, &cs);
        tab[idx] = make_float2(cs, sn);
    } else {
        int idx = (bid - 12544) * 256 + tid;
        if (idx < 2048 + 131072) zero_base[idx] = 0.0f;   // Ksum + Mt
    }
}

#define WAITCNT_VM(N)   asm volatile("s_waitcnt vmcnt(" #N ")" ::: "memory")
#define WAITCNT_LGKM(N) asm volatile("s_waitcnt lgkmcnt(" #N ")" ::: "memory")
#define CBAR()          asm volatile("" ::: "memory")

// ---------------------------------------------------------------------------
// Bijective XCD swizzles (id%8 assumed = XCD).
// 16x16 grid: XCD x owns by in {2x,2x+1}, all 16 bx.
// 16x32 grid: XCD x owns by in {4x..4x+3}, all 16 bx.
// ---------------------------------------------------------------------------
__device__ __forceinline__ void xcd_swz16(int& bx, int& by) {
    int id = (int)(blockIdx.x + (blockIdx.y << 4));
    int x = id & 7, k = id >> 3;
    bx = k >> 1;
    by = x * 2 + (k & 1);
}
__device__ __forceinline__ void xcd_swz32(int& bx, int& by) {
    int id = (int)(blockIdx.x + (blockIdx.y << 4));   // 0..511
    int x = id & 7, k = id >> 3;                      // k 0..63
    bx = k >> 2;                                      // 0..15
    by = x * 4 + (k & 3);                             // 0..31
}

// ---------------------------------------------------------------------------
// KV main loop (measured 54.2 us / MfmaUtil 39%): 256(M)x128(N) head-paired
// tile, 512 threads (8 waves, wr4 x wc2, per-wave 64x64, acc[4][4]).
// ONE barrier per 32-K tile: vmcnt(6) -> s_barrier -> 16 ds_read_b128 ->
// STAGE(t+2) -> lgkm(4) -> 24 MFMA (product-major) -> lgkm(0) -> 24 MFMA.
// 3-deep LDS ring (BUFSZ 24576 ush), T2 swizzle both sides, counted vmcnt.
// ---------------------------------------------------------------------------
__device__ __forceinline__ void gemm_pipe_kv(
    const unsigned short* __restrict__ Ah, const unsigned short* __restrict__ Al,
    const unsigned short* __restrict__ Bth, const unsigned short* __restrict__ Btl,
    unsigned short* lds, int m0, int n0, f32x4 (&acc)[4][4])
{
    constexpr int BUFSZ = 24576;                 // ushorts per K-tile buffer
    constexpr int NT = KDIM / 32;                // 32 K-tiles
    const int tid = threadIdx.x;
    const int w = tid >> 6, lane = tid & 63;
    const int quad = lane >> 4, lrow = lane & 15;
    const int sr = tid >> 2;                          // staging row 0..127
    const int g  = (tid & 3) ^ ((tid >> 3) & 3);      // pre-swizzled granule
    const int wr = w >> 1, wc = w & 1;
    const int rowbase = wr * 64;
    const int colbase = wc * 64;
    const int sw = ((quad ^ ((lrow >> 1) & 3)) << 3); // swizzled read granule (ushorts)

    // Global staging sources (k0 added per tile).
    const unsigned short* gA0 = Ah + (size_t)(m0 + sr) * KDIM + g * 8;
    const unsigned short* gA1 = Ah + (size_t)(m0 + 128 + sr) * KDIM + g * 8;
    const unsigned short* gA2 = Al + (size_t)(m0 + sr) * KDIM + g * 8;
    const unsigned short* gA3 = Al + (size_t)(m0 + 128 + sr) * KDIM + g * 8;
    // rows 0..63 = K head, 64..127 = V head (paired via +960 skip)
    size_t brow = (size_t)(n0 + sr) + (sr >= 64 ? (size_t)960 : 0);
    const unsigned short* gB0 = Bth + brow * KDIM + g * 8;
    const unsigned short* gB1 = Btl + brow * KDIM + g * 8;
    // Wave-uniform LDS destinations (ushort offsets within buffer).
    const int lA0 = w * 512;                 // A hi rows 0-127
    const int lA1 = 4096 + w * 512;          // A hi rows 128-255
    const int lA2 = 8192 + w * 512;          // A lo rows 0-127
    const int lA3 = 12288 + w * 512;         // A lo rows 128-255
    const int lB0 = 16384 + w * 512;         // B hi [128][32]
    const int lB1 = 20480 + w * 512;         // B lo

    auto STAGE = [&](unsigned short* buf, int k0) {
        __builtin_amdgcn_global_load_lds(
            (const __attribute__((address_space(1))) unsigned int*)(gA0 + k0),
            (__attribute__((address_space(3))) unsigned int*)(buf + lA0), 16, 0, 0);
        __builtin_amdgcn_global_load_lds(
            (const __attribute__((address_space(1))) unsigned int*)(gA1 + k0),
            (__attribute__((address_space(3))) unsigned int*)(buf + lA1), 16, 0, 0);
        __builtin_amdgcn_global_load_lds(
            (const __attribute__((address_space(1))) unsigned int*)(gA2 + k0),
            (__attribute__((address_space(3))) unsigned int*)(buf + lA2), 16, 0, 0);
        __builtin_amdgcn_global_load_lds(
            (const __attribute__((address_space(1))) unsigned int*)(gA3 + k0),
            (__attribute__((address_space(3))) unsigned int*)(buf + lA3), 16, 0, 0);
        __builtin_amdgcn_global_load_lds(
            (const __attribute__((address_space(1))) unsigned int*)(gB0 + k0),
            (__attribute__((address_space(3))) unsigned int*)(buf + lB0), 16, 0, 0);
        __builtin_amdgcn_global_load_lds(
            (const __attribute__((address_space(1))) unsigned int*)(gB1 + k0),
            (__attribute__((address_space(3))) unsigned int*)(buf + lB1), 16, 0, 0);
    };

    unsigned short* cur = lds;
    unsigned short* nxt = lds + BUFSZ;
    unsigned short* thr = lds + 2 * BUFSZ;
    STAGE(cur, 0);
    STAGE(nxt, 32);

    #pragma unroll 1
    for (int t = 0; t < NT; ++t) {
        // Own tile-t loads complete; tile t+1 (and t+2) stay in flight.
        if (t == NT - 1) {
            WAITCNT_VM(0);
        } else {
            WAITCNT_VM(6);
        }
        __builtin_amdgcn_s_barrier();   // all waves' t-loads visible; t-1 reads drained

        // group 1: A frags + B jt0/1 (12 ds_read_b128)
        bf16x8 ah[4], al[4], bh[4], bl[4];
        #pragma unroll
        for (int it = 0; it < 4; ++it) {
            int off = (rowbase + it * 16 + lrow) * 32 + sw;
            ah[it] = *(const bf16x8*)&cur[off];
            al[it] = *(const bf16x8*)&cur[8192 + off];
        }
        #pragma unroll
        for (int jt = 0; jt < 2; ++jt) {
            int boff = (colbase + jt * 16 + lrow) * 32 + sw;
            bh[jt] = *(const bf16x8*)&cur[16384 + boff];
            bl[jt] = *(const bf16x8*)&cur[20480 + boff];
        }
        CBAR();   // pin group order so lgkmcnt(4) counts exactly group 2
        // group 2: B jt2/3 (4 ds_read_b128)
        #pragma unroll
        for (int jt = 2; jt < 4; ++jt) {
            int boff = (colbase + jt * 16 + lrow) * 32 + sw;
            bh[jt] = *(const bf16x8*)&cur[16384 + boff];
            bl[jt] = *(const bf16x8*)&cur[20480 + boff];
        }
        if (t + 2 < NT) STAGE(thr, (t + 2) * 32);

        WAITCNT_LGKM(4);                       // group 1 resident
        __builtin_amdgcn_sched_barrier(0);
        __builtin_amdgcn_s_setprio(1);
        // jt01 cluster, product-major (same-acc MFMAs 8 apart)
        #pragma unroll
        for (int it = 0; it < 4; ++it)
            #pragma unroll
            for (int jt = 0; jt < 2; ++jt)
                acc[it][jt] = __builtin_amdgcn_mfma_f32_16x16x32_bf16(ah[it], bh[jt], acc[it][jt], 0, 0, 0);
        #pragma unroll
        for (int it = 0; it < 4; ++it)
            #pragma unroll
            for (int jt = 0; jt < 2; ++jt)
                acc[it][jt] = __builtin_amdgcn_mfma_f32_16x16x32_bf16(ah[it], bl[jt], acc[it][jt], 0, 0, 0);
        #pragma unroll
        for (int it = 0; it < 4; ++it)
            #pragma unroll
            for (int jt = 0; jt < 2; ++jt)
                acc[it][jt] = __builtin_amdgcn_mfma_f32_16x16x32_bf16(al[it], bh[jt], acc[it][jt], 0, 0, 0);

        WAITCNT_LGKM(0);                       // group 2 resident
        __builtin_amdgcn_sched_barrier(0);
        // jt23 cluster, product-major
        #pragma unroll
        for (int it = 0; it < 4; ++it)
            #pragma unroll
            for (int jt = 2; jt < 4; ++jt)
                acc[it][jt] = __builtin_amdgcn_mfma_f32_16x16x32_bf16(ah[it], bh[jt], acc[it][jt], 0, 0, 0);
        #pragma unroll
        for (int it = 0; it < 4; ++it)
            #pragma unroll
            for (int jt = 2; jt < 4; ++jt)
                acc[it][jt] = __builtin_amdgcn_mfma_f32_16x16x32_bf16(ah[it], bl[jt], acc[it][jt], 0, 0, 0);
        #pragma unroll
        for (int it = 0; it < 4; ++it)
            #pragma unroll
            for (int jt = 2; jt < 4; ++jt)
                acc[it][jt] = __builtin_amdgcn_mfma_f32_16x16x32_bf16(al[it], bh[jt], acc[it][jt], 0, 0, 0);
        __builtin_amdgcn_s_setprio(0);

        unsigned short* tmp = cur; cur = nxt; nxt = thr; thr = tmp;
    }
    __syncthreads();   // drain before LDS reuse by epilogues
}

// ---------------------------------------------------------------------------
// KV GEMM: 256(M)x128(N) head-paired tile, pipelined loop, fused
// elu/Ksum/rope + Mt accumulate. grid (16 heads, 16 mtiles), 512 threads.
// Epilogue reuses LDS: K_hi[64][264] @0, K_lo @16896, V_hi @33792,
// V_lo @50688 (ushorts, 67584 total <= 73728).
// ---------------------------------------------------------------------------
__global__ __launch_bounds__(512) void gemm_kv(
    const unsigned short* __restrict__ Ah, const unsigned short* __restrict__ Al,
    const unsigned short* __restrict__ Bth, const unsigned short* __restrict__ Btl,
    const float* __restrict__ bias, const float2* __restrict__ tab,
    float* __restrict__ Ksum, float* __restrict__ Mt)
{
    __shared__ alignas(16) unsigned short smem[73728];   // 144 KiB
    const int tid = threadIdx.x;
    const int w = tid >> 6, lane = tid & 63;
    const int wr = w >> 1, wc = w & 1;
    const int quad = lane >> 4, lrow = lane & 15;
    int h, mt;
    xcd_swz16(h, mt);
    const int m0 = mt * 256;
    const int b  = m0 >> 11;
    const int tbase = (m0 & 2047) + wr * 64;
    const int bh_idx = b * NH + h;

    f32x4 acc[4][4] = {};
    gemm_pipe_kv(Ah, Al, Bth, Btl, smem, m0, h * 64, acc);

    const bool isK = (wc == 0);
    const int colg = (isK ? 0 : C_EMB) + h * 64;
    float bb[4];
    #pragma unroll
    for (int jt = 0; jt < 4; ++jt) bb[jt] = bias[colg + jt * 16 + lrow];
    #pragma unroll
    for (int it = 0; it < 4; ++it)
        #pragma unroll
        for (int jt = 0; jt < 4; ++jt)
            #pragma unroll
            for (int r = 0; r < 4; ++r) {
                float v = acc[it][jt][r] + bb[jt];
                acc[it][jt][r] = isK ? elu1(v) : v;
            }

    if (isK) {
        #pragma unroll
        for (int jt = 0; jt < 4; ++jt) {
            float p = 0.0f;
            #pragma unroll
            for (int it = 0; it < 4; ++it)
                #pragma unroll
                for (int r = 0; r < 4; ++r) p += acc[it][jt][r];
            p += __shfl_xor(p, 16);
            p += __shfl_xor(p, 32);
            if (quad == 0)
                atomicAdd(&Ksum[b * C_EMB + h * 64 + jt * 16 + lrow], p);
        }
        #pragma unroll
        for (int it = 0; it < 4; ++it)
            #pragma unroll
            for (int r = 0; r < 4; ++r) {
                int s = tbase + it * 16 + quad * 4 + r;
                float2 c0 = tab[s * 32 + lrow];
                float2 c1 = tab[s * 32 + 16 + lrow];
                float a0 = acc[it][0][r], a1 = acc[it][1][r];
                float a2 = acc[it][2][r], a3 = acc[it][3][r];
                acc[it][0][r] = a0 * c0.x - a2 * c0.y;
                acc[it][2][r] = a2 * c0.x + a0 * c0.y;
                acc[it][1][r] = a1 * c1.x - a3 * c1.y;
                acc[it][3][r] = a3 * c1.x + a1 * c1.y;
            }
    }

    // transposed LDS: [64 d][264 t] hi/lo per K and V
    unsigned short* Hd = smem + (isK ? 0 : 33792);
    unsigned short* Ld = Hd + 16896;
    #pragma unroll
    for (int jt = 0; jt < 4; ++jt) {
        int d = jt * 16 + lrow;
        #pragma unroll
        for (int it = 0; it < 4; ++it) {
            int t0loc = wr * 64 + it * 16 + quad * 4;
            ushort4 h4, l4;
            float v0 = acc[it][jt][0], v1 = acc[it][jt][1];
            float v2 = acc[it][jt][2], v3 = acc[it][jt][3];
            h4.x = bf16_rne(v0); l4.x = bf16_rne(v0 - bf16_to_f(h4.x));
            h4.y = bf16_rne(v1); l4.y = bf16_rne(v1 - bf16_to_f(h4.y));
            h4.z = bf16_rne(v2); l4.z = bf16_rne(v2 - bf16_to_f(h4.z));
            h4.w = bf16_rne(v3); l4.w = bf16_rne(v3 - bf16_to_f(h4.w));
            *(ushort4*)&Hd[d * 264 + t0loc] = h4;
            *(ushort4*)&Ld[d * 264 + t0loc] = l4;
        }
    }
    __syncthreads();

    {
        const unsigned short* KH = smem;
        const unsigned short* KL = smem + 16896;
        const unsigned short* VH = smem + 33792;
        const unsigned short* VL = smem + 50688;
        const int mrow = (w & 3) * 16 + lrow;   // V feature row
        const int thalf = w >> 2;               // t-half 0/1 (128 each)
        f32x4 macc[4] = {};
        #pragma unroll
        for (int ks = 0; ks < 4; ++ks) {
            int kof = thalf * 128 + ks * 32 + quad * 8;
            bf16x8 vah = *(const bf16x8*)&VH[mrow * 264 + kof];
            bf16x8 val = *(const bf16x8*)&VL[mrow * 264 + kof];
            #pragma unroll
            for (int jt = 0; jt < 4; ++jt) {
                int nrow = jt * 16 + lrow;
                bf16x8 kbh = *(const bf16x8*)&KH[nrow * 264 + kof];
                bf16x8 kbl = *(const bf16x8*)&KL[nrow * 264 + kof];
                macc[jt] = __builtin_amdgcn_mfma_f32_16x16x32_bf16(vah, kbh, macc[jt], 0, 0, 0);
                macc[jt] = __builtin_amdgcn_mfma_f32_16x16x32_bf16(vah, kbl, macc[jt], 0, 0, 0);
                macc[jt] = __builtin_amdgcn_mfma_f32_16x16x32_bf16(val, kbh, macc[jt], 0, 0, 0);
            }
        }
        #pragma unroll
        for (int jt = 0; jt < 4; ++jt)
            #pragma unroll
            for (int r = 0; r < 4; ++r)
                atomicAdd(&Mt[((size_t)bh_idx * 64 + (w & 3) * 16 + quad * 4 + r) * 64 + jt * 16 + lrow],
                          macc[jt][r]);
    }
}

// ---------------------------------------------------------------------------
// 128(M)x64(N) main loop for Q / out. 256 threads (4 waves, per-wave 32x64).
// 2-buffer LDS ring (48 KiB total -> 3 blocks/CU), distance-1 staging,
// 1 barrier/tile, counted lgkm split, product-major MFMA.
// ---------------------------------------------------------------------------
__device__ __forceinline__ void gemm_main_128(
    const unsigned short* __restrict__ Ah, const unsigned short* __restrict__ Al,
    const unsigned short* __restrict__ Bth, const unsigned short* __restrict__ Btl,
    unsigned short* lds, int m0, int n0, f32x4 (&acc)[2][4])
{
    const int tid = threadIdx.x;
    const int w = tid >> 6, lane = tid & 63;
    const int quad = lane >> 4, lrow = lane & 15;
    const int srow = lane >> 2;                       // 0..15
    const int g  = (lane & 3) ^ ((lane >> 3) & 3);    // pre-swizzled granule
    const int sw = ((quad ^ ((lrow >> 1) & 3)) << 3); // swizzled read granule

    const unsigned short* gA0 = Ah + (size_t)(m0 + w * 16 + srow) * KDIM + g * 8;
    const unsigned short* gA1 = Ah + (size_t)(m0 + 64 + w * 16 + srow) * KDIM + g * 8;
    const unsigned short* gA2 = Al + (size_t)(m0 + w * 16 + srow) * KDIM + g * 8;
    const unsigned short* gA3 = Al + (size_t)(m0 + 64 + w * 16 + srow) * KDIM + g * 8;
    const unsigned short* gB0 = Bth + (size_t)(n0 + w * 16 + srow) * KDIM + g * 8;
    const unsigned short* gB1 = Btl + (size_t)(n0 + w * 16 + srow) * KDIM + g * 8;
    const int lA0 = w * 512, lA1 = 2048 + w * 512;
    const int lA2 = 4096 + w * 512, lA3 = 6144 + w * 512;
    const int lB0 = 8192 + w * 512, lB1 = 10240 + w * 512;

    auto STAGE = [&](unsigned short* buf, int k0) {
        __builtin_amdgcn_global_load_lds(
            (const __attribute__((address_space(1))) unsigned int*)(gA0 + k0),
            (__attribute__((address_space(3))) unsigned int*)(buf + lA0), 16, 0, 0);
        __builtin_amdgcn_global_load_lds(
            (const __attribute__((address_space(1))) unsigned int*)(gA1 + k0),
            (__attribute__((address_space(3))) unsigned int*)(buf + lA1), 16, 0, 0);
        __builtin_amdgcn_global_load_lds(
            (const __attribute__((address_space(1))) unsigned int*)(gA2 + k0),
            (__attribute__((address_space(3))) unsigned int*)(buf + lA2), 16, 0, 0);
        __builtin_amdgcn_global_load_lds(
            (const __attribute__((address_space(1))) unsigned int*)(gA3 + k0),
            (__attribute__((address_space(3))) unsigned int*)(buf + lA3), 16, 0, 0);
        __builtin_amdgcn_global_load_lds(
            (const __attribute__((address_space(1))) unsigned int*)(gB0 + k0),
            (__attribute__((address_space(3))) unsigned int*)(buf + lB0), 16, 0, 0);
        __builtin_amdgcn_global_load_lds(
            (const __attribute__((address_space(1))) unsigned int*)(gB1 + k0),
            (__attribute__((address_space(3))) unsigned int*)(buf + lB1), 16, 0, 0);
    };

    STAGE(lds, 0);

    #pragma unroll 1
    for (int t = 0; t < 32; ++t) {
        unsigned short* cur = lds + (t & 1) * 12288;
        unsigned short* nxt = lds + ((t + 1) & 1) * 12288;
        WAITCNT_VM(0);                    // own STAGE(t) complete
        __builtin_amdgcn_sched_barrier(0);
        __builtin_amdgcn_s_barrier();     // all waves: t resident; t-1 reads done
        __builtin_amdgcn_sched_barrier(0);

        bf16x8 ah[2], al[2], bh[4], bl[4];
        #pragma unroll
        for (int it = 0; it < 2; ++it) {
            int off = (w * 32 + it * 16 + lrow) * 32 + sw;
            ah[it] = *(const bf16x8*)&cur[off];
            al[it] = *(const bf16x8*)&cur[4096 + off];
        }
        #pragma unroll
        for (int jt = 0; jt < 2; ++jt) {
            int boff = (jt * 16 + lrow) * 32 + sw;
            bh[jt] = *(const bf16x8*)&cur[8192 + boff];
            bl[jt] = *(const bf16x8*)&cur[10240 + boff];
        }
        CBAR();   // pin group order: lgkm(4) counts exactly the 4 reads below
        #pragma unroll
        for (int jt = 2; jt < 4; ++jt) {
            int boff = (jt * 16 + lrow) * 32 + sw;
            bh[jt] = *(const bf16x8*)&cur[8192 + boff];
            bl[jt] = *(const bf16x8*)&cur[10240 + boff];
        }
        if (t + 1 < 32) STAGE(nxt, (t + 1) * 32);

        WAITCNT_LGKM(4);                  // group 1 (A + B jt01) resident
        __builtin_amdgcn_sched_barrier(0);
        __builtin_amdgcn_s_setprio(1);
        #pragma unroll
        for (int it = 0; it < 2; ++it)
            #pragma unroll
            for (int jt = 0; jt < 2; ++jt)
                acc[it][jt] = __builtin_amdgcn_mfma_f32_16x16x32_bf16(ah[it], bh[jt], acc[it][jt], 0, 0, 0);
        #pragma unroll
        for (int it = 0; it < 2; ++it)
            #pragma unroll
            for (int jt = 0; jt < 2; ++jt)
                acc[it][jt] = __builtin_amdgcn_mfma_f32_16x16x32_bf16(ah[it], bl[jt], acc[it][jt], 0, 0, 0);
        #pragma unroll
        for (int it = 0; it < 2; ++it)
            #pragma unroll
            for (int jt = 0; jt < 2; ++jt)
                acc[it][jt] = __builtin_amdgcn_mfma_f32_16x16x32_bf16(al[it], bh[jt], acc[it][jt], 0, 0, 0);

        WAITCNT_LGKM(0);                  // group 2 (B jt23) resident
        __builtin_amdgcn_sched_barrier(0);
        #pragma unroll
        for (int it = 0; it < 2; ++it)
            #pragma unroll
            for (int jt = 2; jt < 4; ++jt)
                acc[it][jt] = __builtin_amdgcn_mfma_f32_16x16x32_bf16(ah[it], bh[jt], acc[it][jt], 0, 0, 0);
        #pragma unroll
        for (int it = 0; it < 2; ++it)
            #pragma unroll
            for (int jt = 2; jt < 4; ++jt)
                acc[it][jt] = __builtin_amdgcn_mfma_f32_16x16x32_bf16(ah[it], bl[jt], acc[it][jt], 0, 0, 0);
        #pragma unroll
        for (int it = 0; it < 2; ++it)
            #pragma unroll
            for (int jt = 2; jt < 4; ++jt)
                acc[it][jt] = __builtin_amdgcn_mfma_f32_16x16x32_bf16(al[it], bh[jt], acc[it][jt], 0, 0, 0);
        __builtin_amdgcn_s_setprio(0);
    }
    __syncthreads();   // drain before LDS reuse by epilogues
}

// ---------------------------------------------------------------------------
// Q GEMM, 128x64 tile (one head per block), grid (16,32) x 256 thr.
// Epilogue: bias, elu+1, den in regs, RoPE, per-wave Qrot LDS,
// Y = (Qrot @ Mt^T)/den, bf16 hi/lo stores.
// ---------------------------------------------------------------------------
__global__ __launch_bounds__(256, 3) void gemm_q(
    const unsigned short* __restrict__ Ah, const unsigned short* __restrict__ Al,
    const unsigned short* __restrict__ Bth, const unsigned short* __restrict__ Btl,
    const float* __restrict__ bias, const float2* __restrict__ tab,
    const float* __restrict__ Ksum, const float* __restrict__ Mt,
    unsigned short* __restrict__ Yh, unsigned short* __restrict__ Yl)
{
    // main loop uses [0,24576); epilogue reuses [0,18432) as per-wave Qrot
    __shared__ alignas(16) unsigned short smem[24576];   // 48 KiB
    int h, mt;
    xcd_swz32(h, mt);
    const int m0 = mt * 128;
    f32x4 acc[2][4] = {};
    gemm_main_128(Ah, Al, Bth, Btl, smem, m0, h * 64, acc);

    const int tid = threadIdx.x;
    const int w = tid >> 6, lane = tid & 63;
    const int quad = lane >> 4, lrow = lane & 15;
    const int b = m0 >> 11;
    const int tbase = (m0 & 2047) + w * 32;
    const int bh = b * NH + h;

    float bb[4];
    #pragma unroll
    for (int jt = 0; jt < 4; ++jt) bb[jt] = bias[h * 64 + jt * 16 + lrow];
    #pragma unroll
    for (int it = 0; it < 2; ++it)
        #pragma unroll
        for (int jt = 0; jt < 4; ++jt)
            #pragma unroll
            for (int r = 0; r < 4; ++r)
                acc[it][jt][r] = elu1(acc[it][jt][r] + bb[jt]);

    // den (pre-rope), kept in registers
    float ks[4], den_reg[2][4];
    #pragma unroll
    for (int jt = 0; jt < 4; ++jt) ks[jt] = Ksum[b * C_EMB + h * 64 + jt * 16 + lrow];
    #pragma unroll
    for (int it = 0; it < 2; ++it)
        #pragma unroll
        for (int r = 0; r < 4; ++r) {
            float p = acc[it][0][r] * ks[0] + acc[it][1][r] * ks[1]
                    + acc[it][2][r] * ks[2] + acc[it][3][r] * ks[3];
            p += __shfl_xor(p, 1);
            p += __shfl_xor(p, 2);
            p += __shfl_xor(p, 4);
            p += __shfl_xor(p, 8);
            den_reg[it][r] = p;
        }

    // RoPE in registers (pairs jt, jt^2)
    #pragma unroll
    for (int it = 0; it < 2; ++it)
        #pragma unroll
        for (int r = 0; r < 4; ++r) {
            int s = tbase + it * 16 + quad * 4 + r;
            float2 c0 = tab[s * 32 + lrow];
            float2 c1 = tab[s * 32 + 16 + lrow];
            float a0 = acc[it][0][r], a1 = acc[it][1][r];
            float a2 = acc[it][2][r], a3 = acc[it][3][r];
            acc[it][0][r] = a0 * c0.x - a2 * c0.y;
            acc[it][2][r] = a2 * c0.x + a0 * c0.y;
            acc[it][1][r] = a1 * c1.x - a3 * c1.y;
            acc[it][3][r] = a3 * c1.x + a1 * c1.y;
        }

    // Qrot -> per-wave LDS ([32 rows][72], hi then lo). Wave-private region;
    // main loop's final __syncthreads drained cross-wave LDS reads.
    unsigned short* QH = smem + w * 4608;
    unsigned short* QL = QH + 2304;
    #pragma unroll
    for (int it = 0; it < 2; ++it)
        #pragma unroll
        for (int jt = 0; jt < 4; ++jt)
            #pragma unroll
            for (int r = 0; r < 4; ++r) {
                int tloc = it * 16 + quad * 4 + r;
                int d = jt * 16 + lrow;
                float v = acc[it][jt][r];
                unsigned short hh = bf16_rne(v);
                QH[tloc * 72 + d] = hh;
                QL[tloc * 72 + d] = bf16_rne(v - bf16_to_f(hh));
            }

    // Y = (Qrot @ Mt^T) / den
    f32x4 acc2[2][4] = {};
    #pragma unroll
    for (int kc = 0; kc < 2; ++kc) {
        bf16x8 mbh[4], mbl[4];
        #pragma unroll
        for (int jt2 = 0; jt2 < 4; ++jt2) {
            const float* mp = &Mt[((size_t)bh * 64 + jt2 * 16 + lrow) * 64 + kc * 32 + quad * 8];
            #pragma unroll
            for (int e = 0; e < 8; ++e) {
                float x = mp[e];
                unsigned short hh = bf16_rne(x);
                mbh[jt2][e] = (short)hh;
                mbl[jt2][e] = (short)bf16_rne(x - bf16_to_f(hh));
            }
        }
        #pragma unroll
        for (int it2 = 0; it2 < 2; ++it2) {
            int ro = (it2 * 16 + lrow) * 72 + kc * 32 + quad * 8;
            bf16x8 qh = *(const bf16x8*)&QH[ro];
            bf16x8 ql = *(const bf16x8*)&QL[ro];
            #pragma unroll
            for (int jt2 = 0; jt2 < 4; ++jt2) {
                acc2[it2][jt2] = __builtin_amdgcn_mfma_f32_16x16x32_bf16(qh, mbh[jt2], acc2[it2][jt2], 0, 0, 0);
                acc2[it2][jt2] = __builtin_amdgcn_mfma_f32_16x16x32_bf16(qh, mbl[jt2], acc2[it2][jt2], 0, 0, 0);
                acc2[it2][jt2] = __builtin_amdgcn_mfma_f32_16x16x32_bf16(ql, mbh[jt2], acc2[it2][jt2], 0, 0, 0);
            }
        }
    }

    // divide + bf16 hi/lo store
    #pragma unroll
    for (int it2 = 0; it2 < 2; ++it2)
        #pragma unroll
        for (int jt2 = 0; jt2 < 4; ++jt2)
            #pragma unroll
            for (int r = 0; r < 4; ++r) {
                float v = acc2[it2][jt2][r] / den_reg[it2][r];
                size_t o = ((size_t)(m0 + w * 32 + it2 * 16 + quad * 4 + r)) * C_EMB
                         + h * 64 + jt2 * 16 + lrow;
                unsigned short hh = bf16_rne(v);
                Yh[o] = hh;
                Yl[o] = bf16_rne(v - bf16_to_f(hh));
            }
}

// ---------------------------------------------------------------------------
// Output projection GEMM, 128x64 tile: out = Y @ proj_w + proj_b.
// grid (16 n-tiles, 32 m-tiles) x 256 thr.
// ---------------------------------------------------------------------------
__global__ __launch_bounds__(256, 3) void gemm_out(
    const unsigned short* __restrict__ Ah, const unsigned short* __restrict__ Al,
    const unsigned short* __restrict__ Bth, const unsigned short* __restrict__ Btl,
    const float* __restrict__ bias, float* __restrict__ out)
{
    __shared__ alignas(16) unsigned short smem[24576];
    int nt, mt;
    xcd_swz32(nt, mt);
    const int m0 = mt * 128, n0 = nt * 64;
    f32x4 acc[2][4] = {};
    gemm_main_128(Ah, Al, Bth, Btl, smem, m0, n0, acc);

    const int tid = threadIdx.x;
    const int w = tid >> 6, lane = tid & 63;
    const int quad = lane >> 4, lrow = lane & 15;

    #pragma unroll
    for (int jt = 0; jt < 4; ++jt) {
        int gc = n0 + jt * 16 + lrow;
        float bb = bias[gc];
        #pragma unroll
        for (int it = 0; it < 2; ++it) {
            int grb = m0 + w * 32 + it * 16 + quad * 4;
            #pragma unroll
            for (int r = 0; r < 4; ++r)
                out[(size_t)(grb + r) * C_EMB + gc] = acc[it][jt][r] + bb;
        }
    }
}

// ---------------------------------------------------------------------------
extern "C" void kernel_launch(void* const* d_in, const int* in_sizes, int n_in,
                              void* d_out, int out_size, void* d_ws, size_t ws_size,
                              hipStream_t stream)
{
    const float* x      = (const float*)d_in[0];
    const float* memory = (const float*)d_in[1];
    const float* q_w    = (const float*)d_in[2];
    const float* q_b    = (const float*)d_in[3];
    const float* kv_w   = (const float*)d_in[4];
    const float* kv_b   = (const float*)d_in[5];
    const float* proj_w = (const float*)d_in[6];
    const float* proj_b = (const float*)d_in[7];

    if (ws_size < WS_FLOATS * sizeof(float)) return;

    float* ws = (float*)d_ws;
    unsigned short* xh   = (unsigned short*)(ws + OFF_XH);
    unsigned short* xl   = (unsigned short*)(ws + OFF_XL);
    unsigned short* mh   = (unsigned short*)(ws + OFF_MEMH);
    unsigned short* ml   = (unsigned short*)(ws + OFF_MEML);
    unsigned short* qwh  = (unsigned short*)(ws + OFF_QWH);
    unsigned short* qwl  = (unsigned short*)(ws + OFF_QWL);
    unsigned short* kvwh = (unsigned short*)(ws + OFF_KVWH);
    unsigned short* kvwl = (unsigned short*)(ws + OFF_KVWL);
    unsigned short* pwh  = (unsigned short*)(ws + OFF_PWH);
    unsigned short* pwl  = (unsigned short*)(ws + OFF_PWL);
    unsigned short* Yh   = (unsigned short*)(ws + OFF_YH);
    unsigned short* Yl   = (unsigned short*)(ws + OFF_YL);
    float*  Ksum = ws + OFF_KSUM;
    float*  Mm   = ws + OFF_MT;
    float2* tab  = (float2*)(ws + OFF_TAB);

    // One prep dispatch: splits + weight transposes + rope table + zero Ksum/Mt
    prep_kernel<<<PREP_BLOCKS, 256, 0, stream>>>(
        x, memory, q_w, kv_w, proj_w,
        xh, xl, mh, ml, qwh, qwl, kvwh, kvwl, pwh, pwl,
        tab, Ksum /* zero_base: Ksum+Mt contiguous */);

    // KV GEMM (+elu/Ksum/rope + fused Mt accumulate). 256 blocks x 512 thr.
    gemm_kv<<<dim3(16, 16), 512, 0, stream>>>(mh, ml, kvwh, kvwl, kv_b, tab, Ksum, Mm);
    // Q GEMM (+elu/den/rope + fused Y = Qrot·Mt^T/den) -> Yh/Yl. 512 x 256.
    gemm_q<<<dim3(16, 32), 256, 0, stream>>>(xh, xl, qwh, qwl, q_b, tab, Ksum, Mm, Yh, Yl);
    // out = Y @ proj_w + proj_b. 512 x 256.
    gemm_out<<<dim3(16, 32), 256, 0, stream>>>(Yh, Yl, pwh, pwl, proj_b, (float*)d_out);
}

// Round 7
// 224.058 us; speedup vs baseline: 1.0839x; 1.0094x over previous
//
#include <hip/hip_runtime.h>
#include <cstddef>
#include <cstdint>

// Problem constants
#define B_SZ  2
#define T_SEQ 2048
#define S_SEQ 2048
#define C_EMB 1024
#define NH    16
#define HD    64
#define KDIM  1024   // inner dim of the three big GEMMs

typedef __attribute__((ext_vector_type(8))) short bf16x8;
typedef __attribute__((ext_vector_type(4))) float f32x4;

// ---------------------------------------------------------------------------
// Workspace layout (float units).
// ---------------------------------------------------------------------------
#define OFF_XH    ((size_t)0)           // [4096,1024] ushort
#define OFF_XL    ((size_t)2097152)
#define OFF_MEMH  ((size_t)4194304)     // [4096,1024] ushort
#define OFF_MEML  ((size_t)6291456)
#define OFF_QWH   ((size_t)8388608)     // [1024,1024] ushort (transposed [N,K])
#define OFF_QWL   ((size_t)8912896)
#define OFF_KVWH  ((size_t)9437184)     // [2048,1024] ushort
#define OFF_KVWL  ((size_t)10485760)
#define OFF_PWH   ((size_t)11534336)    // [1024,1024] ushort
#define OFF_PWL   ((size_t)12058624)
#define OFF_KSUM  ((size_t)12582912)    // [2,1024]      (zeroed by prep)
#define OFF_MT    ((size_t)12584960)    // [32,64,64]    (zeroed by prep)
#define OFF_TAB   ((size_t)12716032)    // [2048,32] float2
#define OFF_YH    ((size_t)12847104)    // [4096,1024] ushort
#define OFF_YL    ((size_t)14944256)
#define WS_FLOATS ((size_t)17041408)    // ~68.2 MB

__device__ __forceinline__ float elu1(float v) {
    return v > 0.0f ? v + 1.0f : __expf(v);
}
__device__ __forceinline__ unsigned short bf16_rne(float x) {
    union { float f; unsigned int u; } v; v.f = x;
    unsigned int u = v.u;
    return (unsigned short)((u + 0x7FFFu + ((u >> 16) & 1u)) >> 16);
}
__device__ __forceinline__ float bf16_to_f(unsigned short h) {
    union { unsigned int u; float f; } v; v.u = ((unsigned int)h) << 16;
    return v.f;
}

// ---------------------------------------------------------------------------
// Unified prep kernel (block-range dispatch), unchanged.
// ---------------------------------------------------------------------------
#define PREP_BLOCKS 13064

__device__ __forceinline__ void split4_body(
    const float4* __restrict__ in, ushort4* __restrict__ hi,
    ushort4* __restrict__ lo, int i)
{
    float4 v = in[i];
    ushort4 h, l;
    h.x = bf16_rne(v.x); l.x = bf16_rne(v.x - bf16_to_f(h.x));
    h.y = bf16_rne(v.y); l.y = bf16_rne(v.y - bf16_to_f(h.y));
    h.z = bf16_rne(v.z); l.z = bf16_rne(v.z - bf16_to_f(h.z));
    h.w = bf16_rne(v.w); l.w = bf16_rne(v.w - bf16_to_f(h.w));
    hi[i] = h; lo[i] = l;
}

__device__ __forceinline__ void transpose_body(
    const float* __restrict__ W, unsigned short* __restrict__ Wth,
    unsigned short* __restrict__ Wtl, int K, int N, int bx, int by,
    float (*tile)[33])
{
    const int k0 = by * 32, n0 = bx * 32;
    const int tx = threadIdx.x & 31, ty = threadIdx.x >> 5;
    #pragma unroll
    for (int j = 0; j < 4; ++j)
        tile[ty + j * 8][tx] = W[(size_t)(k0 + ty + j * 8) * N + n0 + tx];
    __syncthreads();
    #pragma unroll
    for (int j = 0; j < 4; ++j) {
        float x = tile[tx][ty + j * 8];
        unsigned short h = bf16_rne(x);
        unsigned short l = bf16_rne(x - bf16_to_f(h));
        size_t o = (size_t)(n0 + ty + j * 8) * K + k0 + tx;
        Wth[o] = h; Wtl[o] = l;
    }
}

__global__ __launch_bounds__(256) void prep_kernel(
    const float* __restrict__ x, const float* __restrict__ memory,
    const float* __restrict__ q_w, const float* __restrict__ kv_w,
    const float* __restrict__ proj_w,
    unsigned short* __restrict__ xh, unsigned short* __restrict__ xl,
    unsigned short* __restrict__ mh, unsigned short* __restrict__ ml,
    unsigned short* __restrict__ qwh, unsigned short* __restrict__ qwl,
    unsigned short* __restrict__ kvwh, unsigned short* __restrict__ kvwl,
    unsigned short* __restrict__ pwh, unsigned short* __restrict__ pwl,
    float2* __restrict__ tab, float* __restrict__ zero_base)
{
    __shared__ float tile[32][33];
    const int bid = blockIdx.x;
    const int tid = threadIdx.x;
    if (bid < 4096) {
        split4_body((const float4*)x, (ushort4*)xh, (ushort4*)xl, bid * 256 + tid);
    } else if (bid < 8192) {
        split4_body((const float4*)memory, (ushort4*)mh, (ushort4*)ml, (bid - 4096) * 256 + tid);
    } else if (bid < 9216) {
        int i = bid - 8192;
        transpose_body(q_w, qwh, qwl, 1024, 1024, i & 31, i >> 5, tile);
    } else if (bid < 11264) {
        int i = bid - 9216;
        transpose_body(kv_w, kvwh, kvwl, 1024, 2048, i & 63, i >> 6, tile);
    } else if (bid < 12288) {
        int i = bid - 11264;
        transpose_body(proj_w, pwh, pwl, 1024, 1024, i & 31, i >> 5, tile);
    } else if (bid < 12544) {
        int idx = (bid - 12288) * 256 + tid;    // pos*32 + i
        int pos = idx >> 5, i = idx & 31;
        double invf = exp(-(double)i * (9.210340371976184 / 32.0));  // 10000^(-i/32)
        float arg = (float)((double)pos * invf);
        float sn, cs;
        sincosf(arg, &sn, &cs);
        tab[idx] = make_float2(cs, sn);
    } else {
        int idx = (bid - 12544) * 256 + tid;
        if (idx < 2048 + 131072) zero_base[idx] = 0.0f;   // Ksum + Mt
    }
}

#define WAITCNT_VM(N)   asm volatile("s_waitcnt vmcnt(" #N ")" ::: "memory")
#define WAITCNT_LGKM(N) asm volatile("s_waitcnt lgkmcnt(" #N ")" ::: "memory")
#define CBAR()          asm volatile("" ::: "memory")

// ---------------------------------------------------------------------------
// Bijective XCD swizzles (id%8 assumed = XCD).
// 16x16 grid: XCD x owns by in {2x,2x+1}, all 16 bx.
// 16x32 grid: XCD x owns by in {4x..4x+3}, all 16 bx.
// ---------------------------------------------------------------------------
__device__ __forceinline__ void xcd_swz16(int& bx, int& by) {
    int id = (int)(blockIdx.x + (blockIdx.y << 4));
    int x = id & 7, k = id >> 3;
    bx = k >> 1;
    by = x * 2 + (k & 1);
}
__device__ __forceinline__ void xcd_swz32(int& bx, int& by) {
    int id = (int)(blockIdx.x + (blockIdx.y << 4));   // 0..511
    int x = id & 7, k = id >> 3;                      // k 0..63
    bx = k >> 2;                                      // 0..15
    by = x * 4 + (k & 3);                             // 0..31
}

// ---------------------------------------------------------------------------
// KV main loop (unchanged from round 6): 256(M)x128(N) head-paired tile,
// 512 threads (8 waves, wr4 x wc2, per-wave 64x64, acc[4][4]).
// ONE barrier per 32-K tile: vmcnt(6) -> s_barrier -> 16 ds_read_b128 ->
// STAGE(t+2) -> lgkm(4) -> 24 MFMA (product-major) -> lgkm(0) -> 24 MFMA.
// 3-deep LDS ring (BUFSZ 24576 ush), T2 swizzle both sides, counted vmcnt.
// ---------------------------------------------------------------------------
__device__ __forceinline__ void gemm_pipe_kv(
    const unsigned short* __restrict__ Ah, const unsigned short* __restrict__ Al,
    const unsigned short* __restrict__ Bth, const unsigned short* __restrict__ Btl,
    unsigned short* lds, int m0, int n0, f32x4 (&acc)[4][4])
{
    constexpr int BUFSZ = 24576;                 // ushorts per K-tile buffer
    constexpr int NT = KDIM / 32;                // 32 K-tiles
    const int tid = threadIdx.x;
    const int w = tid >> 6, lane = tid & 63;
    const int quad = lane >> 4, lrow = lane & 15;
    const int sr = tid >> 2;                          // staging row 0..127
    const int g  = (tid & 3) ^ ((tid >> 3) & 3);      // pre-swizzled granule
    const int wr = w >> 1, wc = w & 1;
    const int rowbase = wr * 64;
    const int colbase = wc * 64;
    const int sw = ((quad ^ ((lrow >> 1) & 3)) << 3); // swizzled read granule (ushorts)

    // Global staging sources (k0 added per tile).
    const unsigned short* gA0 = Ah + (size_t)(m0 + sr) * KDIM + g * 8;
    const unsigned short* gA1 = Ah + (size_t)(m0 + 128 + sr) * KDIM + g * 8;
    const unsigned short* gA2 = Al + (size_t)(m0 + sr) * KDIM + g * 8;
    const unsigned short* gA3 = Al + (size_t)(m0 + 128 + sr) * KDIM + g * 8;
    // rows 0..63 = K head, 64..127 = V head (paired via +960 skip)
    size_t brow = (size_t)(n0 + sr) + (sr >= 64 ? (size_t)960 : 0);
    const unsigned short* gB0 = Bth + brow * KDIM + g * 8;
    const unsigned short* gB1 = Btl + brow * KDIM + g * 8;
    // Wave-uniform LDS destinations (ushort offsets within buffer).
    const int lA0 = w * 512;                 // A hi rows 0-127
    const int lA1 = 4096 + w * 512;          // A hi rows 128-255
    const int lA2 = 8192 + w * 512;          // A lo rows 0-127
    const int lA3 = 12288 + w * 512;         // A lo rows 128-255
    const int lB0 = 16384 + w * 512;         // B hi [128][32]
    const int lB1 = 20480 + w * 512;         // B lo

    auto STAGE = [&](unsigned short* buf, int k0) {
        __builtin_amdgcn_global_load_lds(
            (const __attribute__((address_space(1))) unsigned int*)(gA0 + k0),
            (__attribute__((address_space(3))) unsigned int*)(buf + lA0), 16, 0, 0);
        __builtin_amdgcn_global_load_lds(
            (const __attribute__((address_space(1))) unsigned int*)(gA1 + k0),
            (__attribute__((address_space(3))) unsigned int*)(buf + lA1), 16, 0, 0);
        __builtin_amdgcn_global_load_lds(
            (const __attribute__((address_space(1))) unsigned int*)(gA2 + k0),
            (__attribute__((address_space(3))) unsigned int*)(buf + lA2), 16, 0, 0);
        __builtin_amdgcn_global_load_lds(
            (const __attribute__((address_space(1))) unsigned int*)(gA3 + k0),
            (__attribute__((address_space(3))) unsigned int*)(buf + lA3), 16, 0, 0);
        __builtin_amdgcn_global_load_lds(
            (const __attribute__((address_space(1))) unsigned int*)(gB0 + k0),
            (__attribute__((address_space(3))) unsigned int*)(buf + lB0), 16, 0, 0);
        __builtin_amdgcn_global_load_lds(
            (const __attribute__((address_space(1))) unsigned int*)(gB1 + k0),
            (__attribute__((address_space(3))) unsigned int*)(buf + lB1), 16, 0, 0);
    };

    unsigned short* cur = lds;
    unsigned short* nxt = lds + BUFSZ;
    unsigned short* thr = lds + 2 * BUFSZ;
    STAGE(cur, 0);
    STAGE(nxt, 32);

    #pragma unroll 1
    for (int t = 0; t < NT; ++t) {
        // Own tile-t loads complete; tile t+1 (and t+2) stay in flight.
        if (t == NT - 1) {
            WAITCNT_VM(0);
        } else {
            WAITCNT_VM(6);
        }
        __builtin_amdgcn_s_barrier();   // all waves' t-loads visible; t-1 reads drained

        // group 1: A frags + B jt0/1 (12 ds_read_b128)
        bf16x8 ah[4], al[4], bh[4], bl[4];
        #pragma unroll
        for (int it = 0; it < 4; ++it) {
            int off = (rowbase + it * 16 + lrow) * 32 + sw;
            ah[it] = *(const bf16x8*)&cur[off];
            al[it] = *(const bf16x8*)&cur[8192 + off];
        }
        #pragma unroll
        for (int jt = 0; jt < 2; ++jt) {
            int boff = (colbase + jt * 16 + lrow) * 32 + sw;
            bh[jt] = *(const bf16x8*)&cur[16384 + boff];
            bl[jt] = *(const bf16x8*)&cur[20480 + boff];
        }
        CBAR();   // pin group order so lgkmcnt(4) counts exactly group 2
        // group 2: B jt2/3 (4 ds_read_b128)
        #pragma unroll
        for (int jt = 2; jt < 4; ++jt) {
            int boff = (colbase + jt * 16 + lrow) * 32 + sw;
            bh[jt] = *(const bf16x8*)&cur[16384 + boff];
            bl[jt] = *(const bf16x8*)&cur[20480 + boff];
        }
        if (t + 2 < NT) STAGE(thr, (t + 2) * 32);

        WAITCNT_LGKM(4);                       // group 1 resident
        __builtin_amdgcn_sched_barrier(0);
        __builtin_amdgcn_s_setprio(1);
        // jt01 cluster, product-major (same-acc MFMAs 8 apart)
        #pragma unroll
        for (int it = 0; it < 4; ++it)
            #pragma unroll
            for (int jt = 0; jt < 2; ++jt)
                acc[it][jt] = __builtin_amdgcn_mfma_f32_16x16x32_bf16(ah[it], bh[jt], acc[it][jt], 0, 0, 0);
        #pragma unroll
        for (int it = 0; it < 4; ++it)
            #pragma unroll
            for (int jt = 0; jt < 2; ++jt)
                acc[it][jt] = __builtin_amdgcn_mfma_f32_16x16x32_bf16(ah[it], bl[jt], acc[it][jt], 0, 0, 0);
        #pragma unroll
        for (int it = 0; it < 4; ++it)
            #pragma unroll
            for (int jt = 0; jt < 2; ++jt)
                acc[it][jt] = __builtin_amdgcn_mfma_f32_16x16x32_bf16(al[it], bh[jt], acc[it][jt], 0, 0, 0);

        WAITCNT_LGKM(0);                       // group 2 resident
        __builtin_amdgcn_sched_barrier(0);
        // jt23 cluster, product-major
        #pragma unroll
        for (int it = 0; it < 4; ++it)
            #pragma unroll
            for (int jt = 2; jt < 4; ++jt)
                acc[it][jt] = __builtin_amdgcn_mfma_f32_16x16x32_bf16(ah[it], bh[jt], acc[it][jt], 0, 0, 0);
        #pragma unroll
        for (int it = 0; it < 4; ++it)
            #pragma unroll
            for (int jt = 2; jt < 4; ++jt)
                acc[it][jt] = __builtin_amdgcn_mfma_f32_16x16x32_bf16(ah[it], bl[jt], acc[it][jt], 0, 0, 0);
        #pragma unroll
        for (int it = 0; it < 4; ++it)
            #pragma unroll
            for (int jt = 2; jt < 4; ++jt)
                acc[it][jt] = __builtin_amdgcn_mfma_f32_16x16x32_bf16(al[it], bh[jt], acc[it][jt], 0, 0, 0);
        __builtin_amdgcn_s_setprio(0);

        unsigned short* tmp = cur; cur = nxt; nxt = thr; thr = tmp;
    }
    __syncthreads();   // drain before LDS reuse by epilogues
}

// ---------------------------------------------------------------------------
// KV GEMM: 256(M)x128(N) head-paired tile, pipelined loop, fused
// elu/Ksum/rope + Mt accumulate. grid (16 heads, 16 mtiles), 512 threads.
// Epilogue reuses LDS: K_hi[64][264] @0, K_lo @16896, V_hi @33792,
// V_lo @50688 (ushorts, 67584 total <= 73728).
// ---------------------------------------------------------------------------
__global__ __launch_bounds__(512) void gemm_kv(
    const unsigned short* __restrict__ Ah, const unsigned short* __restrict__ Al,
    const unsigned short* __restrict__ Bth, const unsigned short* __restrict__ Btl,
    const float* __restrict__ bias, const float2* __restrict__ tab,
    float* __restrict__ Ksum, float* __restrict__ Mt)
{
    __shared__ alignas(16) unsigned short smem[73728];   // 144 KiB
    const int tid = threadIdx.x;
    const int w = tid >> 6, lane = tid & 63;
    const int wr = w >> 1, wc = w & 1;
    const int quad = lane >> 4, lrow = lane & 15;
    int h, mt;
    xcd_swz16(h, mt);
    const int m0 = mt * 256;
    const int b  = m0 >> 11;
    const int tbase = (m0 & 2047) + wr * 64;
    const int bh_idx = b * NH + h;

    f32x4 acc[4][4] = {};
    gemm_pipe_kv(Ah, Al, Bth, Btl, smem, m0, h * 64, acc);

    const bool isK = (wc == 0);
    const int colg = (isK ? 0 : C_EMB) + h * 64;
    float bb[4];
    #pragma unroll
    for (int jt = 0; jt < 4; ++jt) bb[jt] = bias[colg + jt * 16 + lrow];
    #pragma unroll
    for (int it = 0; it < 4; ++it)
        #pragma unroll
        for (int jt = 0; jt < 4; ++jt)
            #pragma unroll
            for (int r = 0; r < 4; ++r) {
                float v = acc[it][jt][r] + bb[jt];
                acc[it][jt][r] = isK ? elu1(v) : v;
            }

    if (isK) {
        #pragma unroll
        for (int jt = 0; jt < 4; ++jt) {
            float p = 0.0f;
            #pragma unroll
            for (int it = 0; it < 4; ++it)
                #pragma unroll
                for (int r = 0; r < 4; ++r) p += acc[it][jt][r];
            p += __shfl_xor(p, 16);
            p += __shfl_xor(p, 32);
            if (quad == 0)
                atomicAdd(&Ksum[b * C_EMB + h * 64 + jt * 16 + lrow], p);
        }
        #pragma unroll
        for (int it = 0; it < 4; ++it)
            #pragma unroll
            for (int r = 0; r < 4; ++r) {
                int s = tbase + it * 16 + quad * 4 + r;
                float2 c0 = tab[s * 32 + lrow];
                float2 c1 = tab[s * 32 + 16 + lrow];
                float a0 = acc[it][0][r], a1 = acc[it][1][r];
                float a2 = acc[it][2][r], a3 = acc[it][3][r];
                acc[it][0][r] = a0 * c0.x - a2 * c0.y;
                acc[it][2][r] = a2 * c0.x + a0 * c0.y;
                acc[it][1][r] = a1 * c1.x - a3 * c1.y;
                acc[it][3][r] = a3 * c1.x + a1 * c1.y;
            }
    }

    // transposed LDS: [64 d][264 t] hi/lo per K and V
    unsigned short* Hd = smem + (isK ? 0 : 33792);
    unsigned short* Ld = Hd + 16896;
    #pragma unroll
    for (int jt = 0; jt < 4; ++jt) {
        int d = jt * 16 + lrow;
        #pragma unroll
        for (int it = 0; it < 4; ++it) {
            int t0loc = wr * 64 + it * 16 + quad * 4;
            ushort4 h4, l4;
            float v0 = acc[it][jt][0], v1 = acc[it][jt][1];
            float v2 = acc[it][jt][2], v3 = acc[it][jt][3];
            h4.x = bf16_rne(v0); l4.x = bf16_rne(v0 - bf16_to_f(h4.x));
            h4.y = bf16_rne(v1); l4.y = bf16_rne(v1 - bf16_to_f(h4.y));
            h4.z = bf16_rne(v2); l4.z = bf16_rne(v2 - bf16_to_f(h4.z));
            h4.w = bf16_rne(v3); l4.w = bf16_rne(v3 - bf16_to_f(h4.w));
            *(ushort4*)&Hd[d * 264 + t0loc] = h4;
            *(ushort4*)&Ld[d * 264 + t0loc] = l4;
        }
    }
    __syncthreads();

    {
        const unsigned short* KH = smem;
        const unsigned short* KL = smem + 16896;
        const unsigned short* VH = smem + 33792;
        const unsigned short* VL = smem + 50688;
        const int mrow = (w & 3) * 16 + lrow;   // V feature row
        const int thalf = w >> 2;               // t-half 0/1 (128 each)
        f32x4 macc[4] = {};
        #pragma unroll
        for (int ks = 0; ks < 4; ++ks) {
            int kof = thalf * 128 + ks * 32 + quad * 8;
            bf16x8 vah = *(const bf16x8*)&VH[mrow * 264 + kof];
            bf16x8 val = *(const bf16x8*)&VL[mrow * 264 + kof];
            #pragma unroll
            for (int jt = 0; jt < 4; ++jt) {
                int nrow = jt * 16 + lrow;
                bf16x8 kbh = *(const bf16x8*)&KH[nrow * 264 + kof];
                bf16x8 kbl = *(const bf16x8*)&KL[nrow * 264 + kof];
                macc[jt] = __builtin_amdgcn_mfma_f32_16x16x32_bf16(vah, kbh, macc[jt], 0, 0, 0);
                macc[jt] = __builtin_amdgcn_mfma_f32_16x16x32_bf16(vah, kbl, macc[jt], 0, 0, 0);
                macc[jt] = __builtin_amdgcn_mfma_f32_16x16x32_bf16(val, kbh, macc[jt], 0, 0, 0);
            }
        }
        #pragma unroll
        for (int jt = 0; jt < 4; ++jt)
            #pragma unroll
            for (int r = 0; r < 4; ++r)
                atomicAdd(&Mt[((size_t)bh_idx * 64 + (w & 3) * 16 + quad * 4 + r) * 64 + jt * 16 + lrow],
                          macc[jt][r]);
    }
}

// ---------------------------------------------------------------------------
// 128(M)x64(N) main loop for Q / out. 256 threads (4 waves, per-wave 32x64).
// NEW: distance-2 staging with 3-buffer ring (BUFSZ 12288 ush, 72 KiB LDS ->
// 2 blocks/CU) and counted vmcnt(6) (never 0 until last tile) -- the KV
// pipe's latency-cover schedule, ported. 1 barrier/tile, counted lgkm split,
// product-major MFMA.
// ---------------------------------------------------------------------------
__device__ __forceinline__ void gemm_main_128(
    const unsigned short* __restrict__ Ah, const unsigned short* __restrict__ Al,
    const unsigned short* __restrict__ Bth, const unsigned short* __restrict__ Btl,
    unsigned short* lds, int m0, int n0, f32x4 (&acc)[2][4])
{
    constexpr int BUFSZ = 12288;                 // ushorts per K-tile buffer
    constexpr int NT = 32;
    const int tid = threadIdx.x;
    const int w = tid >> 6, lane = tid & 63;
    const int quad = lane >> 4, lrow = lane & 15;
    const int srow = lane >> 2;                       // 0..15
    const int g  = (lane & 3) ^ ((lane >> 3) & 3);    // pre-swizzled granule
    const int sw = ((quad ^ ((lrow >> 1) & 3)) << 3); // swizzled read granule

    const unsigned short* gA0 = Ah + (size_t)(m0 + w * 16 + srow) * KDIM + g * 8;
    const unsigned short* gA1 = Ah + (size_t)(m0 + 64 + w * 16 + srow) * KDIM + g * 8;
    const unsigned short* gA2 = Al + (size_t)(m0 + w * 16 + srow) * KDIM + g * 8;
    const unsigned short* gA3 = Al + (size_t)(m0 + 64 + w * 16 + srow) * KDIM + g * 8;
    const unsigned short* gB0 = Bth + (size_t)(n0 + w * 16 + srow) * KDIM + g * 8;
    const unsigned short* gB1 = Btl + (size_t)(n0 + w * 16 + srow) * KDIM + g * 8;
    const int lA0 = w * 512, lA1 = 2048 + w * 512;
    const int lA2 = 4096 + w * 512, lA3 = 6144 + w * 512;
    const int lB0 = 8192 + w * 512, lB1 = 10240 + w * 512;

    auto STAGE = [&](unsigned short* buf, int k0) {
        __builtin_amdgcn_global_load_lds(
            (const __attribute__((address_space(1))) unsigned int*)(gA0 + k0),
            (__attribute__((address_space(3))) unsigned int*)(buf + lA0), 16, 0, 0);
        __builtin_amdgcn_global_load_lds(
            (const __attribute__((address_space(1))) unsigned int*)(gA1 + k0),
            (__attribute__((address_space(3))) unsigned int*)(buf + lA1), 16, 0, 0);
        __builtin_amdgcn_global_load_lds(
            (const __attribute__((address_space(1))) unsigned int*)(gA2 + k0),
            (__attribute__((address_space(3))) unsigned int*)(buf + lA2), 16, 0, 0);
        __builtin_amdgcn_global_load_lds(
            (const __attribute__((address_space(1))) unsigned int*)(gA3 + k0),
            (__attribute__((address_space(3))) unsigned int*)(buf + lA3), 16, 0, 0);
        __builtin_amdgcn_global_load_lds(
            (const __attribute__((address_space(1))) unsigned int*)(gB0 + k0),
            (__attribute__((address_space(3))) unsigned int*)(buf + lB0), 16, 0, 0);
        __builtin_amdgcn_global_load_lds(
            (const __attribute__((address_space(1))) unsigned int*)(gB1 + k0),
            (__attribute__((address_space(3))) unsigned int*)(buf + lB1), 16, 0, 0);
    };

    unsigned short* cur = lds;
    unsigned short* nxt = lds + BUFSZ;
    unsigned short* thr = lds + 2 * BUFSZ;
    STAGE(cur, 0);
    STAGE(nxt, 32);

    #pragma unroll 1
    for (int t = 0; t < NT; ++t) {
        // Own tile-t loads complete; tile t+1 (and t+2) stay in flight.
        if (t == NT - 1) {
            WAITCNT_VM(0);
        } else {
            WAITCNT_VM(6);
        }
        __builtin_amdgcn_sched_barrier(0);
        __builtin_amdgcn_s_barrier();     // all waves: t resident; t-1 reads done
        __builtin_amdgcn_sched_barrier(0);

        bf16x8 ah[2], al[2], bh[4], bl[4];
        #pragma unroll
        for (int it = 0; it < 2; ++it) {
            int off = (w * 32 + it * 16 + lrow) * 32 + sw;
            ah[it] = *(const bf16x8*)&cur[off];
            al[it] = *(const bf16x8*)&cur[4096 + off];
        }
        #pragma unroll
        for (int jt = 0; jt < 2; ++jt) {
            int boff = (jt * 16 + lrow) * 32 + sw;
            bh[jt] = *(const bf16x8*)&cur[8192 + boff];
            bl[jt] = *(const bf16x8*)&cur[10240 + boff];
        }
        CBAR();   // pin group order: lgkm(4) counts exactly the 4 reads below
        #pragma unroll
        for (int jt = 2; jt < 4; ++jt) {
            int boff = (jt * 16 + lrow) * 32 + sw;
            bh[jt] = *(const bf16x8*)&cur[8192 + boff];
            bl[jt] = *(const bf16x8*)&cur[10240 + boff];
        }
        if (t + 2 < NT) STAGE(thr, (t + 2) * 32);

        WAITCNT_LGKM(4);                  // group 1 (A + B jt01) resident
        __builtin_amdgcn_sched_barrier(0);
        __builtin_amdgcn_s_setprio(1);
        #pragma unroll
        for (int it = 0; it < 2; ++it)
            #pragma unroll
            for (int jt = 0; jt < 2; ++jt)
                acc[it][jt] = __builtin_amdgcn_mfma_f32_16x16x32_bf16(ah[it], bh[jt], acc[it][jt], 0, 0, 0);
        #pragma unroll
        for (int it = 0; it < 2; ++it)
            #pragma unroll
            for (int jt = 0; jt < 2; ++jt)
                acc[it][jt] = __builtin_amdgcn_mfma_f32_16x16x32_bf16(ah[it], bl[jt], acc[it][jt], 0, 0, 0);
        #pragma unroll
        for (int it = 0; it < 2; ++it)
            #pragma unroll
            for (int jt = 0; jt < 2; ++jt)
                acc[it][jt] = __builtin_amdgcn_mfma_f32_16x16x32_bf16(al[it], bh[jt], acc[it][jt], 0, 0, 0);

        WAITCNT_LGKM(0);                  // group 2 (B jt23) resident
        __builtin_amdgcn_sched_barrier(0);
        #pragma unroll
        for (int it = 0; it < 2; ++it)
            #pragma unroll
            for (int jt = 2; jt < 4; ++jt)
                acc[it][jt] = __builtin_amdgcn_mfma_f32_16x16x32_bf16(ah[it], bh[jt], acc[it][jt], 0, 0, 0);
        #pragma unroll
        for (int it = 0; it < 2; ++it)
            #pragma unroll
            for (int jt = 2; jt < 4; ++jt)
                acc[it][jt] = __builtin_amdgcn_mfma_f32_16x16x32_bf16(ah[it], bl[jt], acc[it][jt], 0, 0, 0);
        #pragma unroll
        for (int it = 0; it < 2; ++it)
            #pragma unroll
            for (int jt = 2; jt < 4; ++jt)
                acc[it][jt] = __builtin_amdgcn_mfma_f32_16x16x32_bf16(al[it], bh[jt], acc[it][jt], 0, 0, 0);
        __builtin_amdgcn_s_setprio(0);

        unsigned short* tmp = cur; cur = nxt; nxt = thr; thr = tmp;
    }
    __syncthreads();   // drain before LDS reuse by epilogues
}

// ---------------------------------------------------------------------------
// Q GEMM, 128x64 tile (one head per block), grid (16,32) x 256 thr.
// Epilogue: bias, elu+1, den in regs, RoPE, per-wave Qrot LDS,
// Y = (Qrot @ Mt^T)/den, bf16 hi/lo stores.
// ---------------------------------------------------------------------------
__global__ __launch_bounds__(256, 2) void gemm_q(
    const unsigned short* __restrict__ Ah, const unsigned short* __restrict__ Al,
    const unsigned short* __restrict__ Bth, const unsigned short* __restrict__ Btl,
    const float* __restrict__ bias, const float2* __restrict__ tab,
    const float* __restrict__ Ksum, const float* __restrict__ Mt,
    unsigned short* __restrict__ Yh, unsigned short* __restrict__ Yl)
{
    // main loop uses [0,36864); epilogue reuses [0,18432) as per-wave Qrot
    __shared__ alignas(16) unsigned short smem[36864];   // 72 KiB
    int h, mt;
    xcd_swz32(h, mt);
    const int m0 = mt * 128;
    f32x4 acc[2][4] = {};
    gemm_main_128(Ah, Al, Bth, Btl, smem, m0, h * 64, acc);

    const int tid = threadIdx.x;
    const int w = tid >> 6, lane = tid & 63;
    const int quad = lane >> 4, lrow = lane & 15;
    const int b = m0 >> 11;
    const int tbase = (m0 & 2047) + w * 32;
    const int bh = b * NH + h;

    float bb[4];
    #pragma unroll
    for (int jt = 0; jt < 4; ++jt) bb[jt] = bias[h * 64 + jt * 16 + lrow];
    #pragma unroll
    for (int it = 0; it < 2; ++it)
        #pragma unroll
        for (int jt = 0; jt < 4; ++jt)
            #pragma unroll
            for (int r = 0; r < 4; ++r)
                acc[it][jt][r] = elu1(acc[it][jt][r] + bb[jt]);

    // den (pre-rope), kept in registers
    float ks[4], den_reg[2][4];
    #pragma unroll
    for (int jt = 0; jt < 4; ++jt) ks[jt] = Ksum[b * C_EMB + h * 64 + jt * 16 + lrow];
    #pragma unroll
    for (int it = 0; it < 2; ++it)
        #pragma unroll
        for (int r = 0; r < 4; ++r) {
            float p = acc[it][0][r] * ks[0] + acc[it][1][r] * ks[1]
                    + acc[it][2][r] * ks[2] + acc[it][3][r] * ks[3];
            p += __shfl_xor(p, 1);
            p += __shfl_xor(p, 2);
            p += __shfl_xor(p, 4);
            p += __shfl_xor(p, 8);
            den_reg[it][r] = p;
        }

    // RoPE in registers (pairs jt, jt^2)
    #pragma unroll
    for (int it = 0; it < 2; ++it)
        #pragma unroll
        for (int r = 0; r < 4; ++r) {
            int s = tbase + it * 16 + quad * 4 + r;
            float2 c0 = tab[s * 32 + lrow];
            float2 c1 = tab[s * 32 + 16 + lrow];
            float a0 = acc[it][0][r], a1 = acc[it][1][r];
            float a2 = acc[it][2][r], a3 = acc[it][3][r];
            acc[it][0][r] = a0 * c0.x - a2 * c0.y;
            acc[it][2][r] = a2 * c0.x + a0 * c0.y;
            acc[it][1][r] = a1 * c1.x - a3 * c1.y;
            acc[it][3][r] = a3 * c1.x + a1 * c1.y;
        }

    // Qrot -> per-wave LDS ([32 rows][72], hi then lo). Wave-private region;
    // main loop's final __syncthreads drained cross-wave LDS reads.
    unsigned short* QH = smem + w * 4608;
    unsigned short* QL = QH + 2304;
    #pragma unroll
    for (int it = 0; it < 2; ++it)
        #pragma unroll
        for (int jt = 0; jt < 4; ++jt)
            #pragma unroll
            for (int r = 0; r < 4; ++r) {
                int tloc = it * 16 + quad * 4 + r;
                int d = jt * 16 + lrow;
                float v = acc[it][jt][r];
                unsigned short hh = bf16_rne(v);
                QH[tloc * 72 + d] = hh;
                QL[tloc * 72 + d] = bf16_rne(v - bf16_to_f(hh));
            }

    // Y = (Qrot @ Mt^T) / den
    f32x4 acc2[2][4] = {};
    #pragma unroll
    for (int kc = 0; kc < 2; ++kc) {
        bf16x8 mbh[4], mbl[4];
        #pragma unroll
        for (int jt2 = 0; jt2 < 4; ++jt2) {
            const float* mp = &Mt[((size_t)bh * 64 + jt2 * 16 + lrow) * 64 + kc * 32 + quad * 8];
            #pragma unroll
            for (int e = 0; e < 8; ++e) {
                float x = mp[e];
                unsigned short hh = bf16_rne(x);
                mbh[jt2][e] = (short)hh;
                mbl[jt2][e] = (short)bf16_rne(x - bf16_to_f(hh));
            }
        }
        #pragma unroll
        for (int it2 = 0; it2 < 2; ++it2) {
            int ro = (it2 * 16 + lrow) * 72 + kc * 32 + quad * 8;
            bf16x8 qh = *(const bf16x8*)&QH[ro];
            bf16x8 ql = *(const bf16x8*)&QL[ro];
            #pragma unroll
            for (int jt2 = 0; jt2 < 4; ++jt2) {
                acc2[it2][jt2] = __builtin_amdgcn_mfma_f32_16x16x32_bf16(qh, mbh[jt2], acc2[it2][jt2], 0, 0, 0);
                acc2[it2][jt2] = __builtin_amdgcn_mfma_f32_16x16x32_bf16(qh, mbl[jt2], acc2[it2][jt2], 0, 0, 0);
                acc2[it2][jt2] = __builtin_amdgcn_mfma_f32_16x16x32_bf16(ql, mbh[jt2], acc2[it2][jt2], 0, 0, 0);
            }
        }
    }

    // divide + bf16 hi/lo store
    #pragma unroll
    for (int it2 = 0; it2 < 2; ++it2)
        #pragma unroll
        for (int jt2 = 0; jt2 < 4; ++jt2)
            #pragma unroll
            for (int r = 0; r < 4; ++r) {
                float v = acc2[it2][jt2][r] / den_reg[it2][r];
                size_t o = ((size_t)(m0 + w * 32 + it2 * 16 + quad * 4 + r)) * C_EMB
                         + h * 64 + jt2 * 16 + lrow;
                unsigned short hh = bf16_rne(v);
                Yh[o] = hh;
                Yl[o] = bf16_rne(v - bf16_to_f(hh));
            }
}

// ---------------------------------------------------------------------------
// Output projection GEMM, 128x64 tile: out = Y @ proj_w + proj_b.
// grid (16 n-tiles, 32 m-tiles) x 256 thr.
// ---------------------------------------------------------------------------
__global__ __launch_bounds__(256, 2) void gemm_out(
    const unsigned short* __restrict__ Ah, const unsigned short* __restrict__ Al,
    const unsigned short* __restrict__ Bth, const unsigned short* __restrict__ Btl,
    const float* __restrict__ bias, float* __restrict__ out)
{
    __shared__ alignas(16) unsigned short smem[36864];   // 72 KiB
    int nt, mt;
    xcd_swz32(nt, mt);
    const int m0 = mt * 128, n0 = nt * 64;
    f32x4 acc[2][4] = {};
    gemm_main_128(Ah, Al, Bth, Btl, smem, m0, n0, acc);

    const int tid = threadIdx.x;
    const int w = tid >> 6, lane = tid & 63;
    const int quad = lane >> 4, lrow = lane & 15;

    #pragma unroll
    for (int jt = 0; jt < 4; ++jt) {
        int gc = n0 + jt * 16 + lrow;
        float bb = bias[gc];
        #pragma unroll
        for (int it = 0; it < 2; ++it) {
            int grb = m0 + w * 32 + it * 16 + quad * 4;
            #pragma unroll
            for (int r = 0; r < 4; ++r)
                out[(size_t)(grb + r) * C_EMB + gc] = acc[it][jt][r] + bb;
        }
    }
}

// ---------------------------------------------------------------------------
extern "C" void kernel_launch(void* const* d_in, const int* in_sizes, int n_in,
                              void* d_out, int out_size, void* d_ws, size_t ws_size,
                              hipStream_t stream)
{
    const float* x      = (const float*)d_in[0];
    const float* memory = (const float*)d_in[1];
    const float* q_w    = (const float*)d_in[2];
    const float* q_b    = (const float*)d_in[3];
    const float* kv_w   = (const float*)d_in[4];
    const float* kv_b   = (const float*)d_in[5];
    const float* proj_w = (const float*)d_in[6];
    const float* proj_b = (const float*)d_in[7];

    if (ws_size < WS_FLOATS * sizeof(float)) return;

    float* ws = (float*)d_ws;
    unsigned short* xh   = (unsigned short*)(ws + OFF_XH);
    unsigned short* xl   = (unsigned short*)(ws + OFF_XL);
    unsigned short* mh   = (unsigned short*)(ws + OFF_MEMH);
    unsigned short* ml   = (unsigned short*)(ws + OFF_MEML);
    unsigned short* qwh  = (unsigned short*)(ws + OFF_QWH);
    unsigned short* qwl  = (unsigned short*)(ws + OFF_QWL);
    unsigned short* kvwh = (unsigned short*)(ws + OFF_KVWH);
    unsigned short* kvwl = (unsigned short*)(ws + OFF_KVWL);
    unsigned short* pwh  = (unsigned short*)(ws + OFF_PWH);
    unsigned short* pwl  = (unsigned short*)(ws + OFF_PWL);
    unsigned short* Yh   = (unsigned short*)(ws + OFF_YH);
    unsigned short* Yl   = (unsigned short*)(ws + OFF_YL);
    float*  Ksum = ws + OFF_KSUM;
    float*  Mm   = ws + OFF_MT;
    float2* tab  = (float2*)(ws + OFF_TAB);

    // One prep dispatch: splits + weight transposes + rope table + zero Ksum/Mt
    prep_kernel<<<PREP_BLOCKS, 256, 0, stream>>>(
        x, memory, q_w, kv_w, proj_w,
        xh, xl, mh, ml, qwh, qwl, kvwh, kvwl, pwh, pwl,
        tab, Ksum /* zero_base: Ksum+Mt contiguous */);

    // KV GEMM (+elu/Ksum/rope + fused Mt accumulate). 256 blocks x 512 thr.
    gemm_kv<<<dim3(16, 16), 512, 0, stream>>>(mh, ml, kvwh, kvwl, kv_b, tab, Ksum, Mm);
    // Q GEMM (+elu/den/rope + fused Y = Qrot·Mt^T/den) -> Yh/Yl. 512 x 256.
    gemm_q<<<dim3(16, 32), 256, 0, stream>>>(xh, xl, qwh, qwl, q_b, tab, Ksum, Mm, Yh, Yl);
    // out = Y @ proj_w + proj_b. 512 x 256.
    gemm_out<<<dim3(16, 32), 256, 0, stream>>>(Yh, Yl, pwh, pwl, proj_b, (float*)d_out);
}

// Round 10
// 221.205 us; speedup vs baseline: 1.0979x; 1.0129x over previous
//
#include <hip/hip_runtime.h>
#include <cstddef>
#include <cstdint>

// Problem constants
#define B_SZ  2
#define T_SEQ 2048
#define S_SEQ 2048
#define C_EMB 1024
#define NH    16
#define HD    64
#define KDIM  1024   // inner dim of the three big GEMMs

typedef __attribute__((ext_vector_type(8))) short bf16x8;
typedef __attribute__((ext_vector_type(4))) float f32x4;

// ---------------------------------------------------------------------------
// Workspace layout (float units).
// ---------------------------------------------------------------------------
#define OFF_XH    ((size_t)0)           // [4096,1024] ushort
#define OFF_XL    ((size_t)2097152)
#define OFF_MEMH  ((size_t)4194304)     // [4096,1024] ushort
#define OFF_MEML  ((size_t)6291456)
#define OFF_QWH   ((size_t)8388608)     // [1024,1024] ushort (transposed [N,K])
#define OFF_QWL   ((size_t)8912896)
#define OFF_KVWH  ((size_t)9437184)     // [2048,1024] ushort
#define OFF_KVWL  ((size_t)10485760)
#define OFF_PWH   ((size_t)11534336)    // [1024,1024] ushort
#define OFF_PWL   ((size_t)12058624)
#define OFF_KSUM  ((size_t)12582912)    // [2,1024]      (zeroed by prep)
#define OFF_MT    ((size_t)12584960)    // [32,64,64]    (zeroed by prep)
#define OFF_TAB   ((size_t)12716032)    // [2048,32] float2
#define OFF_YH    ((size_t)12847104)    // [4096,1024] ushort
#define OFF_YL    ((size_t)14944256)
#define WS_FLOATS ((size_t)17041408)    // ~68.2 MB

__device__ __forceinline__ float elu1(float v) {
    return v > 0.0f ? v + 1.0f : __expf(v);
}
__device__ __forceinline__ unsigned short bf16_rne(float x) {
    union { float f; unsigned int u; } v; v.f = x;
    unsigned int u = v.u;
    return (unsigned short)((u + 0x7FFFu + ((u >> 16) & 1u)) >> 16);
}
__device__ __forceinline__ float bf16_to_f(unsigned short h) {
    union { unsigned int u; float f; } v; v.u = ((unsigned int)h) << 16;
    return v.f;
}

// ---------------------------------------------------------------------------
// Unified prep kernel (block-range dispatch), unchanged.
// ---------------------------------------------------------------------------
#define PREP_BLOCKS 13064

__device__ __forceinline__ void split4_body(
    const float4* __restrict__ in, ushort4* __restrict__ hi,
    ushort4* __restrict__ lo, int i)
{
    float4 v = in[i];
    ushort4 h, l;
    h.x = bf16_rne(v.x); l.x = bf16_rne(v.x - bf16_to_f(h.x));
    h.y = bf16_rne(v.y); l.y = bf16_rne(v.y - bf16_to_f(h.y));
    h.z = bf16_rne(v.z); l.z = bf16_rne(v.z - bf16_to_f(h.z));
    h.w = bf16_rne(v.w); l.w = bf16_rne(v.w - bf16_to_f(h.w));
    hi[i] = h; lo[i] = l;
}

__device__ __forceinline__ void transpose_body(
    const float* __restrict__ W, unsigned short* __restrict__ Wth,
    unsigned short* __restrict__ Wtl, int K, int N, int bx, int by,
    float (*tile)[33])
{
    const int k0 = by * 32, n0 = bx * 32;
    const int tx = threadIdx.x & 31, ty = threadIdx.x >> 5;
    #pragma unroll
    for (int j = 0; j < 4; ++j)
        tile[ty + j * 8][tx] = W[(size_t)(k0 + ty + j * 8) * N + n0 + tx];
    __syncthreads();
    #pragma unroll
    for (int j = 0; j < 4; ++j) {
        float x = tile[tx][ty + j * 8];
        unsigned short h = bf16_rne(x);
        unsigned short l = bf16_rne(x - bf16_to_f(h));
        size_t o = (size_t)(n0 + ty + j * 8) * K + k0 + tx;
        Wth[o] = h; Wtl[o] = l;
    }
}

__global__ __launch_bounds__(256) void prep_kernel(
    const float* __restrict__ x, const float* __restrict__ memory,
    const float* __restrict__ q_w, const float* __restrict__ kv_w,
    const float* __restrict__ proj_w,
    unsigned short* __restrict__ xh, unsigned short* __restrict__ xl,
    unsigned short* __restrict__ mh, unsigned short* __restrict__ ml,
    unsigned short* __restrict__ qwh, unsigned short* __restrict__ qwl,
    unsigned short* __restrict__ kvwh, unsigned short* __restrict__ kvwl,
    unsigned short* __restrict__ pwh, unsigned short* __restrict__ pwl,
    float2* __restrict__ tab, float* __restrict__ zero_base)
{
    __shared__ float tile[32][33];
    const int bid = blockIdx.x;
    const int tid = threadIdx.x;
    if (bid < 4096) {
        split4_body((const float4*)x, (ushort4*)xh, (ushort4*)xl, bid * 256 + tid);
    } else if (bid < 8192) {
        split4_body((const float4*)memory, (ushort4*)mh, (ushort4*)ml, (bid - 4096) * 256 + tid);
    } else if (bid < 9216) {
        int i = bid - 8192;
        transpose_body(q_w, qwh, qwl, 1024, 1024, i & 31, i >> 5, tile);
    } else if (bid < 11264) {
        int i = bid - 9216;
        transpose_body(kv_w, kvwh, kvwl, 1024, 2048, i & 63, i >> 6, tile);
    } else if (bid < 12288) {
        int i = bid - 11264;
        transpose_body(proj_w, pwh, pwl, 1024, 1024, i & 31, i >> 5, tile);
    } else if (bid < 12544) {
        int idx = (bid - 12288) * 256 + tid;    // pos*32 + i
        int pos = idx >> 5, i = idx & 31;
        double invf = exp(-(double)i * (9.210340371976184 / 32.0));  // 10000^(-i/32)
        float arg = (float)((double)pos * invf);
        float sn, cs;
        sincosf(arg, &sn, &cs);
        tab[idx] = make_float2(cs, sn);
    } else {
        int idx = (bid - 12544) * 256 + tid;
        if (idx < 2048 + 131072) zero_base[idx] = 0.0f;   // Ksum + Mt
    }
}

#define WAITCNT_VM(N)   asm volatile("s_waitcnt vmcnt(" #N ")" ::: "memory")
#define WAITCNT_LGKM(N) asm volatile("s_waitcnt lgkmcnt(" #N ")" ::: "memory")
#define CBAR()          asm volatile("" ::: "memory")
#define SB0()           __builtin_amdgcn_sched_barrier(0)

// ---------------------------------------------------------------------------
// Bijective XCD swizzles (id%8 assumed = XCD).
// 16x16 grid: XCD x owns by in {2x,2x+1}, all 16 bx.
// 16x32 grid: XCD x owns by in {4x..4x+3}, all 16 bx.
// ---------------------------------------------------------------------------
__device__ __forceinline__ void xcd_swz16(int& bx, int& by) {
    int id = (int)(blockIdx.x + (blockIdx.y << 4));
    int x = id & 7, k = id >> 3;
    bx = k >> 1;
    by = x * 2 + (k & 1);
}
__device__ __forceinline__ void xcd_swz32(int& bx, int& by) {
    int id = (int)(blockIdx.x + (blockIdx.y << 4));   // 0..511
    int x = id & 7, k = id >> 3;                      // k 0..63
    bx = k >> 2;                                      // 0..15
    by = x * 4 + (k & 3);                             // 0..31
}

// ---------------------------------------------------------------------------
// KV main loop (verified round-7 form, 53.7 us / MfmaUtil 39%):
// 256(M)x128(N) head-paired tile, 512 threads (8 waves, wr4 x wc2, per-wave
// 64x64, acc[4][4]). ONE barrier per 32-K tile: vmcnt(6) -> s_barrier ->
// 16 ds_read_b128 -> STAGE(t+2) -> lgkm(4) -> 24 MFMA (product-major) ->
// lgkm(0) -> 24 MFMA. 3-deep LDS ring (BUFSZ 24576 ush), T2 swizzle both
// sides, counted vmcnt.
// ---------------------------------------------------------------------------
__device__ __forceinline__ void gemm_pipe_kv(
    const unsigned short* __restrict__ Ah, const unsigned short* __restrict__ Al,
    const unsigned short* __restrict__ Bth, const unsigned short* __restrict__ Btl,
    unsigned short* lds, int m0, int n0, f32x4 (&acc)[4][4])
{
    constexpr int BUFSZ = 24576;                 // ushorts per K-tile buffer
    constexpr int NT = KDIM / 32;                // 32 K-tiles
    const int tid = threadIdx.x;
    const int w = tid >> 6, lane = tid & 63;
    const int quad = lane >> 4, lrow = lane & 15;
    const int sr = tid >> 2;                          // staging row 0..127
    const int g  = (tid & 3) ^ ((tid >> 3) & 3);      // pre-swizzled granule
    const int wr = w >> 1, wc = w & 1;
    const int rowbase = wr * 64;
    const int colbase = wc * 64;
    const int sw = ((quad ^ ((lrow >> 1) & 3)) << 3); // swizzled read granule (ushorts)

    // Global staging sources (k0 added per tile).
    const unsigned short* gA0 = Ah + (size_t)(m0 + sr) * KDIM + g * 8;
    const unsigned short* gA1 = Ah + (size_t)(m0 + 128 + sr) * KDIM + g * 8;
    const unsigned short* gA2 = Al + (size_t)(m0 + sr) * KDIM + g * 8;
    const unsigned short* gA3 = Al + (size_t)(m0 + 128 + sr) * KDIM + g * 8;
    // rows 0..63 = K head, 64..127 = V head (paired via +960 skip)
    size_t brow = (size_t)(n0 + sr) + (sr >= 64 ? (size_t)960 : 0);
    const unsigned short* gB0 = Bth + brow * KDIM + g * 8;
    const unsigned short* gB1 = Btl + brow * KDIM + g * 8;
    // Wave-uniform LDS destinations (ushort offsets within buffer).
    const int lA0 = w * 512;                 // A hi rows 0-127
    const int lA1 = 4096 + w * 512;          // A hi rows 128-255
    const int lA2 = 8192 + w * 512;          // A lo rows 0-127
    const int lA3 = 12288 + w * 512;         // A lo rows 128-255
    const int lB0 = 16384 + w * 512;         // B hi [128][32]
    const int lB1 = 20480 + w * 512;         // B lo

    auto STAGE = [&](unsigned short* buf, int k0) {
        __builtin_amdgcn_global_load_lds(
            (const __attribute__((address_space(1))) unsigned int*)(gA0 + k0),
            (__attribute__((address_space(3))) unsigned int*)(buf + lA0), 16, 0, 0);
        __builtin_amdgcn_global_load_lds(
            (const __attribute__((address_space(1))) unsigned int*)(gA1 + k0),
            (__attribute__((address_space(3))) unsigned int*)(buf + lA1), 16, 0, 0);
        __builtin_amdgcn_global_load_lds(
            (const __attribute__((address_space(1))) unsigned int*)(gA2 + k0),
            (__attribute__((address_space(3))) unsigned int*)(buf + lA2), 16, 0, 0);
        __builtin_amdgcn_global_load_lds(
            (const __attribute__((address_space(1))) unsigned int*)(gA3 + k0),
            (__attribute__((address_space(3))) unsigned int*)(buf + lA3), 16, 0, 0);
        __builtin_amdgcn_global_load_lds(
            (const __attribute__((address_space(1))) unsigned int*)(gB0 + k0),
            (__attribute__((address_space(3))) unsigned int*)(buf + lB0), 16, 0, 0);
        __builtin_amdgcn_global_load_lds(
            (const __attribute__((address_space(1))) unsigned int*)(gB1 + k0),
            (__attribute__((address_space(3))) unsigned int*)(buf + lB1), 16, 0, 0);
    };

    unsigned short* cur = lds;
    unsigned short* nxt = lds + BUFSZ;
    unsigned short* thr = lds + 2 * BUFSZ;
    STAGE(cur, 0);
    STAGE(nxt, 32);

    #pragma unroll 1
    for (int t = 0; t < NT; ++t) {
        // Own tile-t loads complete; tile t+1 (and t+2) stay in flight.
        if (t == NT - 1) {
            WAITCNT_VM(0);
        } else {
            WAITCNT_VM(6);
        }
        __builtin_amdgcn_s_barrier();   // all waves' t-loads visible; t-1 reads drained

        // group 1: A frags + B jt0/1 (12 ds_read_b128)
        bf16x8 ah[4], al[4], bh[4], bl[4];
        #pragma unroll
        for (int it = 0; it < 4; ++it) {
            int off = (rowbase + it * 16 + lrow) * 32 + sw;
            ah[it] = *(const bf16x8*)&cur[off];
            al[it] = *(const bf16x8*)&cur[8192 + off];
        }
        #pragma unroll
        for (int jt = 0; jt < 2; ++jt) {
            int boff = (colbase + jt * 16 + lrow) * 32 + sw;
            bh[jt] = *(const bf16x8*)&cur[16384 + boff];
            bl[jt] = *(const bf16x8*)&cur[20480 + boff];
        }
        CBAR();   // pin group order so lgkmcnt(4) counts exactly group 2
        // group 2: B jt2/3 (4 ds_read_b128)
        #pragma unroll
        for (int jt = 2; jt < 4; ++jt) {
            int boff = (colbase + jt * 16 + lrow) * 32 + sw;
            bh[jt] = *(const bf16x8*)&cur[16384 + boff];
            bl[jt] = *(const bf16x8*)&cur[20480 + boff];
        }
        if (t + 2 < NT) STAGE(thr, (t + 2) * 32);

        WAITCNT_LGKM(4);                       // group 1 resident
        __builtin_amdgcn_sched_barrier(0);
        __builtin_amdgcn_s_setprio(1);
        // jt01 cluster, product-major (same-acc MFMAs 8 apart)
        #pragma unroll
        for (int it = 0; it < 4; ++it)
            #pragma unroll
            for (int jt = 0; jt < 2; ++jt)
                acc[it][jt] = __builtin_amdgcn_mfma_f32_16x16x32_bf16(ah[it], bh[jt], acc[it][jt], 0, 0, 0);
        #pragma unroll
        for (int it = 0; it < 4; ++it)
            #pragma unroll
            for (int jt = 0; jt < 2; ++jt)
                acc[it][jt] = __builtin_amdgcn_mfma_f32_16x16x32_bf16(ah[it], bl[jt], acc[it][jt], 0, 0, 0);
        #pragma unroll
        for (int it = 0; it < 4; ++it)
            #pragma unroll
            for (int jt = 0; jt < 2; ++jt)
                acc[it][jt] = __builtin_amdgcn_mfma_f32_16x16x32_bf16(al[it], bh[jt], acc[it][jt], 0, 0, 0);

        WAITCNT_LGKM(0);                       // group 2 resident
        __builtin_amdgcn_sched_barrier(0);
        // jt23 cluster, product-major
        #pragma unroll
        for (int it = 0; it < 4; ++it)
            #pragma unroll
            for (int jt = 2; jt < 4; ++jt)
                acc[it][jt] = __builtin_amdgcn_mfma_f32_16x16x32_bf16(ah[it], bh[jt], acc[it][jt], 0, 0, 0);
        #pragma unroll
        for (int it = 0; it < 4; ++it)
            #pragma unroll
            for (int jt = 2; jt < 4; ++jt)
                acc[it][jt] = __builtin_amdgcn_mfma_f32_16x16x32_bf16(ah[it], bl[jt], acc[it][jt], 0, 0, 0);
        #pragma unroll
        for (int it = 0; it < 4; ++it)
            #pragma unroll
            for (int jt = 2; jt < 4; ++jt)
                acc[it][jt] = __builtin_amdgcn_mfma_f32_16x16x32_bf16(al[it], bh[jt], acc[it][jt], 0, 0, 0);
        __builtin_amdgcn_s_setprio(0);

        unsigned short* tmp = cur; cur = nxt; nxt = thr; thr = tmp;
    }
    __syncthreads();   // drain before LDS reuse by epilogues
}

// ---------------------------------------------------------------------------
// KV GEMM: 256(M)x128(N) head-paired tile, pipelined loop, fused
// elu/Ksum/rope + Mt accumulate. grid (16 heads, 16 mtiles), 512 threads.
// Epilogue reuses LDS: K_hi[64][264] @0, K_lo @16896, V_hi @33792,
// V_lo @50688 (ushorts, 67584 total <= 73728).
// ---------------------------------------------------------------------------
__global__ __launch_bounds__(512) void gemm_kv(
    const unsigned short* __restrict__ Ah, const unsigned short* __restrict__ Al,
    const unsigned short* __restrict__ Bth, const unsigned short* __restrict__ Btl,
    const float* __restrict__ bias, const float2* __restrict__ tab,
    float* __restrict__ Ksum, float* __restrict__ Mt)
{
    __shared__ alignas(16) unsigned short smem[73728];   // 144 KiB
    const int tid = threadIdx.x;
    const int w = tid >> 6, lane = tid & 63;
    const int wr = w >> 1, wc = w & 1;
    const int quad = lane >> 4, lrow = lane & 15;
    int h, mt;
    xcd_swz16(h, mt);
    const int m0 = mt * 256;
    const int b  = m0 >> 11;
    const int tbase = (m0 & 2047) + wr * 64;
    const int bh_idx = b * NH + h;

    f32x4 acc[4][4] = {};
    gemm_pipe_kv(Ah, Al, Bth, Btl, smem, m0, h * 64, acc);

    const bool isK = (wc == 0);
    const int colg = (isK ? 0 : C_EMB) + h * 64;
    float bb[4];
    #pragma unroll
    for (int jt = 0; jt < 4; ++jt) bb[jt] = bias[colg + jt * 16 + lrow];
    #pragma unroll
    for (int it = 0; it < 4; ++it)
        #pragma unroll
        for (int jt = 0; jt < 4; ++jt)
            #pragma unroll
            for (int r = 0; r < 4; ++r) {
                float v = acc[it][jt][r] + bb[jt];
                acc[it][jt][r] = isK ? elu1(v) : v;
            }

    if (isK) {
        #pragma unroll
        for (int jt = 0; jt < 4; ++jt) {
            float p = 0.0f;
            #pragma unroll
            for (int it = 0; it < 4; ++it)
                #pragma unroll
                for (int r = 0; r < 4; ++r) p += acc[it][jt][r];
            p += __shfl_xor(p, 16);
            p += __shfl_xor(p, 32);
            if (quad == 0)
                atomicAdd(&Ksum[b * C_EMB + h * 64 + jt * 16 + lrow], p);
        }
        #pragma unroll
        for (int it = 0; it < 4; ++it)
            #pragma unroll
            for (int r = 0; r < 4; ++r) {
                int s = tbase + it * 16 + quad * 4 + r;
                float2 c0 = tab[s * 32 + lrow];
                float2 c1 = tab[s * 32 + 16 + lrow];
                float a0 = acc[it][0][r], a1 = acc[it][1][r];
                float a2 = acc[it][2][r], a3 = acc[it][3][r];
                acc[it][0][r] = a0 * c0.x - a2 * c0.y;
                acc[it][2][r] = a2 * c0.x + a0 * c0.y;
                acc[it][1][r] = a1 * c1.x - a3 * c1.y;
                acc[it][3][r] = a3 * c1.x + a1 * c1.y;
            }
    }

    // transposed LDS: [64 d][264 t] hi/lo per K and V
    unsigned short* Hd = smem + (isK ? 0 : 33792);
    unsigned short* Ld = Hd + 16896;
    #pragma unroll
    for (int jt = 0; jt < 4; ++jt) {
        int d = jt * 16 + lrow;
        #pragma unroll
        for (int it = 0; it < 4; ++it) {
            int t0loc = wr * 64 + it * 16 + quad * 4;
            ushort4 h4, l4;
            float v0 = acc[it][jt][0], v1 = acc[it][jt][1];
            float v2 = acc[it][jt][2], v3 = acc[it][jt][3];
            h4.x = bf16_rne(v0); l4.x = bf16_rne(v0 - bf16_to_f(h4.x));
            h4.y = bf16_rne(v1); l4.y = bf16_rne(v1 - bf16_to_f(h4.y));
            h4.z = bf16_rne(v2); l4.z = bf16_rne(v2 - bf16_to_f(h4.z));
            h4.w = bf16_rne(v3); l4.w = bf16_rne(v3 - bf16_to_f(h4.w));
            *(ushort4*)&Hd[d * 264 + t0loc] = h4;
            *(ushort4*)&Ld[d * 264 + t0loc] = l4;
        }
    }
    __syncthreads();

    {
        const unsigned short* KH = smem;
        const unsigned short* KL = smem + 16896;
        const unsigned short* VH = smem + 33792;
        const unsigned short* VL = smem + 50688;
        const int mrow = (w & 3) * 16 + lrow;   // V feature row
        const int thalf = w >> 2;               // t-half 0/1 (128 each)
        f32x4 macc[4] = {};
        #pragma unroll
        for (int ks = 0; ks < 4; ++ks) {
            int kof = thalf * 128 + ks * 32 + quad * 8;
            bf16x8 vah = *(const bf16x8*)&VH[mrow * 264 + kof];
            bf16x8 val = *(const bf16x8*)&VL[mrow * 264 + kof];
            #pragma unroll
            for (int jt = 0; jt < 4; ++jt) {
                int nrow = jt * 16 + lrow;
                bf16x8 kbh = *(const bf16x8*)&KH[nrow * 264 + kof];
                bf16x8 kbl = *(const bf16x8*)&KL[nrow * 264 + kof];
                macc[jt] = __builtin_amdgcn_mfma_f32_16x16x32_bf16(vah, kbh, macc[jt], 0, 0, 0);
                macc[jt] = __builtin_amdgcn_mfma_f32_16x16x32_bf16(vah, kbl, macc[jt], 0, 0, 0);
                macc[jt] = __builtin_amdgcn_mfma_f32_16x16x32_bf16(val, kbh, macc[jt], 0, 0, 0);
            }
        }
        #pragma unroll
        for (int jt = 0; jt < 4; ++jt)
            #pragma unroll
            for (int r = 0; r < 4; ++r)
                atomicAdd(&Mt[((size_t)bh_idx * 64 + (w & 3) * 16 + quad * 4 + r) * 64 + jt * 16 + lrow],
                          macc[jt][r]);
    }
}

// ---------------------------------------------------------------------------
// 128(M)x64(N) main loop for Q / out: 256 threads (4 waves, per-wave 32x64).
// Distance-2 staging, 3-buffer ring (72 KiB LDS -> 2 blocks/CU), counted
// vmcnt(6), 1 barrier/tile, counted lgkm split, product-major MFMA.
// ---------------------------------------------------------------------------
__device__ __forceinline__ void gemm_main_128(
    const unsigned short* __restrict__ Ah, const unsigned short* __restrict__ Al,
    const unsigned short* __restrict__ Bth, const unsigned short* __restrict__ Btl,
    unsigned short* lds, int m0, int n0, f32x4 (&acc)[2][4])
{
    constexpr int BUFSZ = 12288;                 // ushorts per K-tile buffer
    constexpr int NT = 32;
    const int tid = threadIdx.x;
    const int w = tid >> 6, lane = tid & 63;
    const int quad = lane >> 4, lrow = lane & 15;
    const int srow = lane >> 2;                       // 0..15
    const int g  = (lane & 3) ^ ((lane >> 3) & 3);    // pre-swizzled granule
    const int sw = ((quad ^ ((lrow >> 1) & 3)) << 3); // swizzled read granule

    const unsigned short* gA0 = Ah + (size_t)(m0 + w * 16 + srow) * KDIM + g * 8;
    const unsigned short* gA1 = Ah + (size_t)(m0 + 64 + w * 16 + srow) * KDIM + g * 8;
    const unsigned short* gA2 = Al + (size_t)(m0 + w * 16 + srow) * KDIM + g * 8;
    const unsigned short* gA3 = Al + (size_t)(m0 + 64 + w * 16 + srow) * KDIM + g * 8;
    const unsigned short* gB0 = Bth + (size_t)(n0 + w * 16 + srow) * KDIM + g * 8;
    const unsigned short* gB1 = Btl + (size_t)(n0 + w * 16 + srow) * KDIM + g * 8;
    const int lA0 = w * 512, lA1 = 2048 + w * 512;
    const int lA2 = 4096 + w * 512, lA3 = 6144 + w * 512;
    const int lB0 = 8192 + w * 512, lB1 = 10240 + w * 512;

    auto STAGE = [&](unsigned short* buf, int k0) {
        __builtin_amdgcn_global_load_lds(
            (const __attribute__((address_space(1))) unsigned int*)(gA0 + k0),
            (__attribute__((address_space(3))) unsigned int*)(buf + lA0), 16, 0, 0);
        __builtin_amdgcn_global_load_lds(
            (const __attribute__((address_space(1))) unsigned int*)(gA1 + k0),
            (__attribute__((address_space(3))) unsigned int*)(buf + lA1), 16, 0, 0);
        __builtin_amdgcn_global_load_lds(
            (const __attribute__((address_space(1))) unsigned int*)(gA2 + k0),
            (__attribute__((address_space(3))) unsigned int*)(buf + lA2), 16, 0, 0);
        __builtin_amdgcn_global_load_lds(
            (const __attribute__((address_space(1))) unsigned int*)(gA3 + k0),
            (__attribute__((address_space(3))) unsigned int*)(buf + lA3), 16, 0, 0);
        __builtin_amdgcn_global_load_lds(
            (const __attribute__((address_space(1))) unsigned int*)(gB0 + k0),
            (__attribute__((address_space(3))) unsigned int*)(buf + lB0), 16, 0, 0);
        __builtin_amdgcn_global_load_lds(
            (const __attribute__((address_space(1))) unsigned int*)(gB1 + k0),
            (__attribute__((address_space(3))) unsigned int*)(buf + lB1), 16, 0, 0);
    };

    unsigned short* cur = lds;
    unsigned short* nxt = lds + BUFSZ;
    unsigned short* thr = lds + 2 * BUFSZ;
    STAGE(cur, 0);
    STAGE(nxt, 32);

    #pragma unroll 1
    for (int t = 0; t < NT; ++t) {
        // Own tile-t loads complete; tile t+1 (and t+2) stay in flight.
        if (t == NT - 1) {
            WAITCNT_VM(0);
        } else {
            WAITCNT_VM(6);
        }
        SB0();
        __builtin_amdgcn_s_barrier();     // all waves: t resident; t-1 reads done
        SB0();

        bf16x8 ah[2], al[2], bh[4], bl[4];
        #pragma unroll
        for (int it = 0; it < 2; ++it) {
            int off = (w * 32 + it * 16 + lrow) * 32 + sw;
            ah[it] = *(const bf16x8*)&cur[off];
            al[it] = *(const bf16x8*)&cur[4096 + off];
        }
        #pragma unroll
        for (int jt = 0; jt < 2; ++jt) {
            int boff = (jt * 16 + lrow) * 32 + sw;
            bh[jt] = *(const bf16x8*)&cur[8192 + boff];
            bl[jt] = *(const bf16x8*)&cur[10240 + boff];
        }
        CBAR();   // pin group order: lgkm(4) counts exactly the 4 reads below
        #pragma unroll
        for (int jt = 2; jt < 4; ++jt) {
            int boff = (jt * 16 + lrow) * 32 + sw;
            bh[jt] = *(const bf16x8*)&cur[8192 + boff];
            bl[jt] = *(const bf16x8*)&cur[10240 + boff];
        }
        if (t + 2 < NT) STAGE(thr, (t + 2) * 32);

        WAITCNT_LGKM(4);                  // group 1 (A + B jt01) resident
        SB0();
        __builtin_amdgcn_s_setprio(1);
        #pragma unroll
        for (int it = 0; it < 2; ++it)
            #pragma unroll
            for (int jt = 0; jt < 2; ++jt)
                acc[it][jt] = __builtin_amdgcn_mfma_f32_16x16x32_bf16(ah[it], bh[jt], acc[it][jt], 0, 0, 0);
        #pragma unroll
        for (int it = 0; it < 2; ++it)
            #pragma unroll
            for (int jt = 0; jt < 2; ++jt)
                acc[it][jt] = __builtin_amdgcn_mfma_f32_16x16x32_bf16(ah[it], bl[jt], acc[it][jt], 0, 0, 0);
        #pragma unroll
        for (int it = 0; it < 2; ++it)
            #pragma unroll
            for (int jt = 0; jt < 2; ++jt)
                acc[it][jt] = __builtin_amdgcn_mfma_f32_16x16x32_bf16(al[it], bh[jt], acc[it][jt], 0, 0, 0);

        WAITCNT_LGKM(0);                  // group 2 (B jt23) resident
        SB0();
        #pragma unroll
        for (int it = 0; it < 2; ++it)
            #pragma unroll
            for (int jt = 2; jt < 4; ++jt)
                acc[it][jt] = __builtin_amdgcn_mfma_f32_16x16x32_bf16(ah[it], bh[jt], acc[it][jt], 0, 0, 0);
        #pragma unroll
        for (int it = 0; it < 2; ++it)
            #pragma unroll
            for (int jt = 2; jt < 4; ++jt)
                acc[it][jt] = __builtin_amdgcn_mfma_f32_16x16x32_bf16(ah[it], bl[jt], acc[it][jt], 0, 0, 0);
        #pragma unroll
        for (int it = 0; it < 2; ++it)
            #pragma unroll
            for (int jt = 2; jt < 4; ++jt)
                acc[it][jt] = __builtin_amdgcn_mfma_f32_16x16x32_bf16(al[it], bh[jt], acc[it][jt], 0, 0, 0);
        __builtin_amdgcn_s_setprio(0);

        unsigned short* tmp = cur; cur = nxt; nxt = thr; thr = tmp;
    }
    __syncthreads();   // drain before LDS reuse by epilogues
}

// ---------------------------------------------------------------------------
// Q GEMM, 128x64 tile (one head per block), grid (16,32) x 256 thr.
// Epilogue: bias, elu+1, den in regs, RoPE, per-wave Qrot LDS,
// Y = (Qrot @ Mt^T)/den, bf16 hi/lo stores.
// ---------------------------------------------------------------------------
__global__ __launch_bounds__(256, 2) void gemm_q(
    const unsigned short* __restrict__ Ah, const unsigned short* __restrict__ Al,
    const unsigned short* __restrict__ Bth, const unsigned short* __restrict__ Btl,
    const float* __restrict__ bias, const float2* __restrict__ tab,
    const float* __restrict__ Ksum, const float* __restrict__ Mt,
    unsigned short* __restrict__ Yh, unsigned short* __restrict__ Yl)
{
    // main loop uses [0,36864); epilogue reuses [0,18432) as per-wave Qrot
    __shared__ alignas(16) unsigned short smem[36864];   // 72 KiB
    int h, mt;
    xcd_swz32(h, mt);
    const int m0 = mt * 128;
    f32x4 acc[2][4] = {};
    gemm_main_128(Ah, Al, Bth, Btl, smem, m0, h * 64, acc);

    const int tid = threadIdx.x;
    const int w = tid >> 6, lane = tid & 63;
    const int quad = lane >> 4, lrow = lane & 15;
    const int b = m0 >> 11;
    const int tbase = (m0 & 2047) + w * 32;
    const int bh = b * NH + h;

    float bb[4];
    #pragma unroll
    for (int jt = 0; jt < 4; ++jt) bb[jt] = bias[h * 64 + jt * 16 + lrow];
    #pragma unroll
    for (int it = 0; it < 2; ++it)
        #pragma unroll
        for (int jt = 0; jt < 4; ++jt)
            #pragma unroll
            for (int r = 0; r < 4; ++r)
                acc[it][jt][r] = elu1(acc[it][jt][r] + bb[jt]);

    // den (pre-rope), kept in registers
    float ks[4], den_reg[2][4];
    #pragma unroll
    for (int jt = 0; jt < 4; ++jt) ks[jt] = Ksum[b * C_EMB + h * 64 + jt * 16 + lrow];
    #pragma unroll
    for (int it = 0; it < 2; ++it)
        #pragma unroll
        for (int r = 0; r < 4; ++r) {
            float p = acc[it][0][r] * ks[0] + acc[it][1][r] * ks[1]
                    + acc[it][2][r] * ks[2] + acc[it][3][r] * ks[3];
            p += __shfl_xor(p, 1);
            p += __shfl_xor(p, 2);
            p += __shfl_xor(p, 4);
            p += __shfl_xor(p, 8);
            den_reg[it][r] = p;
        }

    // RoPE in registers (pairs jt, jt^2)
    #pragma unroll
    for (int it = 0; it < 2; ++it)
        #pragma unroll
        for (int r = 0; r < 4; ++r) {
            int s = tbase + it * 16 + quad * 4 + r;
            float2 c0 = tab[s * 32 + lrow];
            float2 c1 = tab[s * 32 + 16 + lrow];
            float a0 = acc[it][0][r], a1 = acc[it][1][r];
            float a2 = acc[it][2][r], a3 = acc[it][3][r];
            acc[it][0][r] = a0 * c0.x - a2 * c0.y;
            acc[it][2][r] = a2 * c0.x + a0 * c0.y;
            acc[it][1][r] = a1 * c1.x - a3 * c1.y;
            acc[it][3][r] = a3 * c1.x + a1 * c1.y;
        }

    // Qrot -> per-wave LDS ([32 rows][72], hi then lo). Wave-private region;
    // main loop's final __syncthreads drained cross-wave LDS reads.
    unsigned short* QH = smem + w * 4608;
    unsigned short* QL = QH + 2304;
    #pragma unroll
    for (int it = 0; it < 2; ++it)
        #pragma unroll
        for (int jt = 0; jt < 4; ++jt)
            #pragma unroll
            for (int r = 0; r < 4; ++r) {
                int tloc = it * 16 + quad * 4 + r;
                int d = jt * 16 + lrow;
                float v = acc[it][jt][r];
                unsigned short hh = bf16_rne(v);
                QH[tloc * 72 + d] = hh;
                QL[tloc * 72 + d] = bf16_rne(v - bf16_to_f(hh));
            }

    // Y = (Qrot @ Mt^T) / den
    f32x4 acc2[2][4] = {};
    #pragma unroll
    for (int kc = 0; kc < 2; ++kc) {
        bf16x8 mbh[4], mbl[4];
        #pragma unroll
        for (int jt2 = 0; jt2 < 4; ++jt2) {
            const float* mp = &Mt[((size_t)bh * 64 + jt2 * 16 + lrow) * 64 + kc * 32 + quad * 8];
            #pragma unroll
            for (int e = 0; e < 8; ++e) {
                float x = mp[e];
                unsigned short hh = bf16_rne(x);
                mbh[jt2][e] = (short)hh;
                mbl[jt2][e] = (short)bf16_rne(x - bf16_to_f(hh));
            }
        }
        #pragma unroll
        for (int it2 = 0; it2 < 2; ++it2) {
            int ro = (it2 * 16 + lrow) * 72 + kc * 32 + quad * 8;
            bf16x8 qh = *(const bf16x8*)&QH[ro];
            bf16x8 ql = *(const bf16x8*)&QL[ro];
            #pragma unroll
            for (int jt2 = 0; jt2 < 4; ++jt2) {
                acc2[it2][jt2] = __builtin_amdgcn_mfma_f32_16x16x32_bf16(qh, mbh[jt2], acc2[it2][jt2], 0, 0, 0);
                acc2[it2][jt2] = __builtin_amdgcn_mfma_f32_16x16x32_bf16(qh, mbl[jt2], acc2[it2][jt2], 0, 0, 0);
                acc2[it2][jt2] = __builtin_amdgcn_mfma_f32_16x16x32_bf16(ql, mbh[jt2], acc2[it2][jt2], 0, 0, 0);
            }
        }
    }

    // divide + bf16 hi/lo store
    #pragma unroll
    for (int it2 = 0; it2 < 2; ++it2)
        #pragma unroll
        for (int jt2 = 0; jt2 < 4; ++jt2)
            #pragma unroll
            for (int r = 0; r < 4; ++r) {
                float v = acc2[it2][jt2][r] / den_reg[it2][r];
                size_t o = ((size_t)(m0 + w * 32 + it2 * 16 + quad * 4 + r)) * C_EMB
                         + h * 64 + jt2 * 16 + lrow;
                unsigned short hh = bf16_rne(v);
                Yh[o] = hh;
                Yl[o] = bf16_rne(v - bf16_to_f(hh));
            }
}

// ---------------------------------------------------------------------------
// Output projection GEMM, 128x64 tile: out = Y @ proj_w + proj_b.
// grid (16 n-tiles, 32 m-tiles) x 256 thr.
// ---------------------------------------------------------------------------
__global__ __launch_bounds__(256, 2) void gemm_out(
    const unsigned short* __restrict__ Ah, const unsigned short* __restrict__ Al,
    const unsigned short* __restrict__ Bth, const unsigned short* __restrict__ Btl,
    const float* __restrict__ bias, float* __restrict__ out)
{
    __shared__ alignas(16) unsigned short smem[36864];   // 72 KiB
    int nt, mt;
    xcd_swz32(nt, mt);
    const int m0 = mt * 128, n0 = nt * 64;
    f32x4 acc[2][4] = {};
    gemm_main_128(Ah, Al, Bth, Btl, smem, m0, n0, acc);

    const int tid = threadIdx.x;
    const int w = tid >> 6, lane = tid & 63;
    const int quad = lane >> 4, lrow = lane & 15;

    #pragma unroll
    for (int jt = 0; jt < 4; ++jt) {
        int gc = n0 + jt * 16 + lrow;
        float bb = bias[gc];
        #pragma unroll
        for (int it = 0; it < 2; ++it) {
            int grb = m0 + w * 32 + it * 16 + quad * 4;
            #pragma unroll
            for (int r = 0; r < 4; ++r)
                out[(size_t)(grb + r) * C_EMB + gc] = acc[it][jt][r] + bb;
        }
    }
}

// ---------------------------------------------------------------------------
extern "C" void kernel_launch(void* const* d_in, const int* in_sizes, int n_in,
                              void* d_out, int out_size, void* d_ws, size_t ws_size,
                              hipStream_t stream)
{
    const float* x      = (const float*)d_in[0];
    const float* memory = (const float*)d_in[1];
    const float* q_w    = (const float*)d_in[2];
    const float* q_b    = (const float*)d_in[3];
    const float* kv_w   = (const float*)d_in[4];
    const float* kv_b   = (const float*)d_in[5];
    const float* proj_w = (const float*)d_in[6];
    const float* proj_b = (const float*)d_in[7];

    if (ws_size < WS_FLOATS * sizeof(float)) return;

    float* ws = (float*)d_ws;
    unsigned short* xh   = (unsigned short*)(ws + OFF_XH);
    unsigned short* xl   = (unsigned short*)(ws + OFF_XL);
    unsigned short* mh   = (unsigned short*)(ws + OFF_MEMH);
    unsigned short* ml   = (unsigned short*)(ws + OFF_MEML);
    unsigned short* qwh  = (unsigned short*)(ws + OFF_QWH);
    unsigned short* qwl  = (unsigned short*)(ws + OFF_QWL);
    unsigned short* kvwh = (unsigned short*)(ws + OFF_KVWH);
    unsigned short* kvwl = (unsigned short*)(ws + OFF_KVWL);
    unsigned short* pwh  = (unsigned short*)(ws + OFF_PWH);
    unsigned short* pwl  = (unsigned short*)(ws + OFF_PWL);
    unsigned short* Yh   = (unsigned short*)(ws + OFF_YH);
    unsigned short* Yl   = (unsigned short*)(ws + OFF_YL);
    float*  Ksum = ws + OFF_KSUM;
    float*  Mm   = ws + OFF_MT;
    float2* tab  = (float2*)(ws + OFF_TAB);

    // One prep dispatch: splits + weight transposes + rope table + zero Ksum/Mt
    prep_kernel<<<PREP_BLOCKS, 256, 0, stream>>>(
        x, memory, q_w, kv_w, proj_w,
        xh, xl, mh, ml, qwh, qwl, kvwh, kvwl, pwh, pwl,
        tab, Ksum /* zero_base: Ksum+Mt contiguous */);

    // KV GEMM (+elu/Ksum/rope + fused Mt accumulate). 256 blocks x 512 thr.
    gemm_kv<<<dim3(16, 16), 512, 0, stream>>>(mh, ml, kvwh, kvwl, kv_b, tab, Ksum, Mm);
    // Q GEMM (+elu/den/rope + fused Y = Qrot·Mt^T/den) -> Yh/Yl. 512 x 256.
    gemm_q<<<dim3(16, 32), 256, 0, stream>>>(xh, xl, qwh, qwl, q_b, tab, Ksum, Mm, Yh, Yl);
    // out = Y @ proj_w + proj_b. 512 x 256.
    gemm_out<<<dim3(16, 32), 256, 0, stream>>>(Yh, Yl, pwh, pwl, proj_b, (float*)d_out);
}